// Round 1
// baseline (25474.632 us; speedup 1.0000x reference)
//
#include <hip/hip_runtime.h>
#include <math.h>

#define BB 8
#define SS 512
#define MMDIM 64
#define HHEAD 8
#define LLAY 4
#define FFDIM 256
#define KCB 1024
#define BSN 4096          // B*S
#define ROWS 49152        // BS*12
#define NEL 49152         // B*S*12

__constant__ int d_REP[12] = {0,1,2,2,3,3,4,4,5,5,6,6};

// ---------------- QF init (144 entries) + row sums (12) ----------------
__global__ void k_init_qf(float* qf) {
    int t = threadIdx.x;
    if (t < 144) {
        int r = t / 12, j = t % 12;
        double v;
        if (r == 0)      v = 1.0 / sqrt(12.0);
        else if (r == 1) v = ((j & 1) ? -1.0 : 1.0) / sqrt(12.0);
        else {
            int m = r >> 1;                     // r=2,3 -> 1 ... r=10,11 -> 5
            double ang = 2.0 * 3.14159265358979323846 * (double)m * (double)j / 12.0;
            v = (((r & 1) == 0) ? cos(ang) : sin(ang)) / sqrt(6.0);
        }
        qf[t] = (float)v;
    }
    __syncthreads();
    if (t < 12) {
        float s = 0.f;
        for (int j = 0; j < 12; ++j) s += qf[t * 12 + j];
        qf[144 + t] = s;
    }
}

// ---------------- embed head entry: h[bs,d,o] = (QF @ (x+fb))[d] * fw * w1[rep[d],o,0]
__global__ __launch_bounds__(256) void k_embed(const float* __restrict__ x,
                                               const float* __restrict__ fb,
                                               const float* __restrict__ fw,
                                               const float* __restrict__ w1,
                                               const float* __restrict__ qf,
                                               float* __restrict__ out) {
    int bs = blockIdx.x;
    __shared__ float xs[12], h1[12];
    int t = threadIdx.x;
    if (t < 12) xs[t] = x[bs * 12 + t] + fb[0];
    __syncthreads();
    if (t < 12) {
        float a = 0.f;
        for (int p = 0; p < 12; ++p) a += qf[t * 12 + p] * xs[p];
        h1[t] = a * fw[0];
    }
    __syncthreads();
    for (int e = t; e < 12 * 64; e += 256) {
        int d = e >> 6, o = e & 63;
        out[((size_t)bs * 12 + d) * 64 + o] = h1[d] * w1[d_REP[d] * 64 + o];
    }
}

// ---------------- act: per (bs, m) column, all 7 groups, exact gelu -----
__global__ __launch_bounds__(256) void k_act(float* __restrict__ h,
                                             const float* __restrict__ qf,
                                             int mdim) {
    const int starts[7] = {0, 1, 2, 4, 6, 8, 10};
    const int dks[7]    = {1, 1, 2, 2, 2, 2, 2};
    int idx = blockIdx.x * 256 + threadIdx.x;
    int total = BSN * mdim;
    if (idx >= total) return;
    int bs = idx / mdim, m = idx - bs * mdim;
    float* base = h + (size_t)bs * 12 * mdim + m;
    float v[12], o[12];
    for (int d = 0; d < 12; ++d) v[d] = base[d * mdim];
    for (int k = 0; k < 7; ++k) {
        int s = starts[k], dk = dks[k];
        float g[12];
        for (int pp = 0; pp < 12; ++pp) {
            float a = 0.f;
            for (int d = 0; d < dk; ++d) a += qf[(s + d) * 12 + pp] * v[s + d];
            g[pp] = 0.5f * a * (1.0f + erff(a * 0.7071067811865475f));
        }
        for (int d = 0; d < dk; ++d) {
            float a = 0.f;
            for (int pp = 0; pp < 12; ++pp) a += qf[(s + d) * 12 + pp] * g[pp];
            o[s + d] = a;
        }
    }
    for (int d = 0; d < 12; ++d) base[d * mdim] = o[d];
}

// ---------------- generic lin: out[row,o] = sum_i in[row,i]*W[rep[row%12],o,i] (+res)
template <int O, int I>
__global__ __launch_bounds__(256) void k_lin(const float* __restrict__ in,
                                             const float* __restrict__ W,
                                             const float* __restrict__ res,
                                             float* __restrict__ out) {
    constexpr int R = 256 / O;
    __shared__ float sIn[R][I];
    int t = threadIdx.x;
    int row0 = blockIdx.x * R;
    for (int e = t; e < R * I; e += 256) {
        int r = e / I, i = e - r * I;
        sIn[r][i] = in[(size_t)(row0 + r) * I + i];
    }
    __syncthreads();
    int r = t / O, o = t - r * O;
    int row = row0 + r;
    int d = row % 12;
    const float* w = W + ((size_t)d_REP[d] * O + o) * I;
    float acc = 0.f;
#pragma unroll
    for (int i = 0; i < I; ++i) acc += sIn[r][i] * w[i];
    size_t oi = (size_t)row * O + o;
    if (res) acc += res[oi];
    out[oi] = acc;
}

// ---------------- attention: one block per (b,h,q-row), naive two-pass --
__global__ __launch_bounds__(256) void k_attn(const float* __restrict__ q,
                                              const float* __restrict__ k,
                                              const float* __restrict__ v,
                                              float* __restrict__ out) {
    int bid = blockIdx.x;
    int qs = bid % SS;
    int bh = bid / SS;
    int hh = bh % HHEAD;
    int b  = bh / HHEAD;
    __shared__ float qv[96];
    __shared__ float sc[SS];
    __shared__ float red[256];
    int t = threadIdx.x;
    if (t < 96) {
        int d = t >> 3, mk = t & 7;
        qv[t] = q[(((size_t)b * SS + qs) * 12 + d) * 64 + hh * 8 + mk];
    }
    __syncthreads();
    for (int ks = t; ks < SS; ks += 256) {
        const float* krow = k + ((size_t)b * SS + ks) * 12 * 64 + hh * 8;
        float a = 0.f;
#pragma unroll
        for (int dd = 0; dd < 96; ++dd) {
            int d = dd >> 3, mk = dd & 7;
            a += qv[dd] * krow[d * 64 + mk];
        }
        sc[ks] = a / 9.797958971132712f;   // sqrt(96)
    }
    __syncthreads();
    float mx = -3.4e38f;
    for (int ks = t; ks < SS; ks += 256) mx = fmaxf(mx, sc[ks]);
    red[t] = mx; __syncthreads();
    for (int st = 128; st > 0; st >>= 1) { if (t < st) red[t] = fmaxf(red[t], red[t + st]); __syncthreads(); }
    mx = red[0]; __syncthreads();
    float sm = 0.f;
    for (int ks = t; ks < SS; ks += 256) { float e = expf(sc[ks] - mx); sc[ks] = e; sm += e; }
    red[t] = sm; __syncthreads();
    for (int st = 128; st > 0; st >>= 1) { if (t < st) red[t] += red[t + st]; __syncthreads(); }
    float inv = 1.0f / red[0];
    for (int dd = t; dd < 96; dd += 256) {
        int d = dd >> 3, mk = dd & 7;
        const float* vcol = v + (size_t)b * SS * 12 * 64 + d * 64 + hh * 8 + mk;
        float a = 0.f;
        for (int ks = 0; ks < SS; ++ks) a += sc[ks] * vcol[(size_t)ks * 768];
        out[(((size_t)b * SS + qs) * 12 + d) * 64 + hh * 8 + mk] = a * inv;
    }
}

// ---------------- fc_out: t[d]=h[d,:]·w[rep[d]]; z[p]=sum_d QF[d,p]t[d]/7
__global__ void k_fcout(const float* __restrict__ h, const float* __restrict__ w,
                        const float* __restrict__ qf, float* __restrict__ z) {
    int bs = blockIdx.x;
    __shared__ float td[12];
    int t = threadIdx.x;
    if (t < 12) {
        const float* row = h + ((size_t)bs * 12 + t) * 64;
        const float* wr  = w + d_REP[t] * 64;
        float a = 0.f;
        for (int i = 0; i < 64; ++i) a += row[i] * wr[i];
        td[t] = a;
    }
    __syncthreads();
    if (t < 12) {
        float a = 0.f;
        for (int d = 0; d < 12; ++d) a += qf[d * 12 + t] * td[d];
        z[bs * 12 + t] = a / 7.0f;
    }
}

// ---------------- VQ: argmin_c ||z||^2+||c||^2-2 z·c, first-index ties --
__global__ __launch_bounds__(256) void k_vq(const float* __restrict__ z,
                                            const float* __restrict__ cb,
                                            float* __restrict__ zvq,
                                            float* __restrict__ zst) {
    int bs = blockIdx.x;
    int t = threadIdx.x;
    __shared__ float zv[12];
    __shared__ float sb[256];
    __shared__ int   si[256];
    if (t < 12) zv[t] = z[bs * 12 + t];
    __syncthreads();
    float zz = 0.f;
    for (int j = 0; j < 12; ++j) zz += zv[j] * zv[j];
    float best = 3.4e38f; int bi = 0x7fffffff;
    for (int c = t; c < KCB; c += 256) {
        const float* cr = cb + c * 12;
        float cc = 0.f, dot = 0.f;
        for (int j = 0; j < 12; ++j) { cc += cr[j] * cr[j]; dot += zv[j] * cr[j]; }
        float dist = zz + cc - 2.0f * dot;
        if (dist < best) { best = dist; bi = c; }
    }
    sb[t] = best; si[t] = bi; __syncthreads();
    for (int st = 128; st > 0; st >>= 1) {
        if (t < st) {
            if (sb[t + st] < sb[t] || (sb[t + st] == sb[t] && si[t + st] < si[t])) {
                sb[t] = sb[t + st]; si[t] = si[t + st];
            }
        }
        __syncthreads();
    }
    if (t < 12) {
        float c = cb[si[0] * 12 + t];
        zvq[bs * 12 + t] = c;
        float zi = zv[t];
        zst[bs * 12 + t] = (c - zi) + zi;
    }
}

// ---------------- positional encoding add ------------------------------
__global__ __launch_bounds__(256) void k_posenc(float* __restrict__ h,
                                                const float* __restrict__ qf) {
    int idx = blockIdx.x * 256 + threadIdx.x;
    if (idx >= ROWS * 64) return;
    int m = idx & 63;
    int r = idx >> 6;
    int d = r % 12;
    int bs = r / 12;
    int s = bs % SS;
    int i = m >> 1;
    float dv = expf((float)(2 * i) * (-0.14391156831212787f));
    float arg = (float)s * dv;
    float pe = (m & 1) ? cosf(arg) : sinf(arg);
    h[idx] += qf[144 + d] * pe;
}

// ---------------- recon loss partials + x_recon write ------------------
__global__ __launch_bounds__(256) void k_recon(const float* __restrict__ x,
                                               const float* __restrict__ logits,
                                               float* __restrict__ xr_out,
                                               float* __restrict__ partial) {
    __shared__ float red[256];
    int t = threadIdx.x;
    float acc = 0.f;
    for (int i = blockIdx.x * 256 + t; i < NEL; i += gridDim.x * 256) {
        float lg = logits[i];
        float xr = 1.0f / (1.0f + expf(-lg));
        xr_out[i] = xr;
        float xi = x[i];
        float l1 = fmaxf(logf(xr), -100.0f);
        float l2 = fmaxf(logf(1.0f - xr), -100.0f);
        acc += xi * l1 + (1.0f - xi) * l2;
    }
    red[t] = acc; __syncthreads();
    for (int st = 128; st > 0; st >>= 1) { if (t < st) red[t] += red[t + st]; __syncthreads(); }
    if (t == 0) partial[blockIdx.x] = red[0];
}

__global__ __launch_bounds__(256) void k_embloss(const float* __restrict__ z,
                                                 const float* __restrict__ zvq,
                                                 float* __restrict__ partial) {
    __shared__ float red[256];
    int t = threadIdx.x;
    float acc = 0.f;
    for (int i = blockIdx.x * 256 + t; i < NEL; i += gridDim.x * 256) {
        float d = zvq[i] - z[i];
        acc += d * d;
    }
    red[t] = acc; __syncthreads();
    for (int st = 128; st > 0; st >>= 1) { if (t < st) red[t] += red[t + st]; __syncthreads(); }
    if (t == 0) partial[blockIdx.x] = red[0];
}

__global__ void k_final(const float* __restrict__ p1, const float* __restrict__ p2,
                        float* __restrict__ out) {
    if (threadIdx.x == 0) {
        float s1 = 0.f, s2 = 0.f;
        for (int i = 0; i < 96; ++i) { s1 += p1[i]; s2 += p2[i]; }
        out[NEL]     = -s1 / (float)NEL;
        out[NEL + 1] =  s2 / (float)NEL;
        out[NEL + 2] =  s2 / (float)NEL;
    }
}

// ------------------------------------------------------------------------
extern "C" void kernel_launch(void* const* d_in, const int* in_sizes, int n_in,
                              void* d_out, int out_size, void* d_ws, size_t ws_size,
                              hipStream_t stream) {
    const float* x   = (const float*)d_in[0];
    const float* efb = (const float*)d_in[1];
    const float* efw = (const float*)d_in[2];
    const float* ew1 = (const float*)d_in[3];
    const float* ew2 = (const float*)d_in[4];
    const float* ew3 = (const float*)d_in[5];
    const float* ewq = (const float*)d_in[6];
    const float* ewk = (const float*)d_in[7];
    const float* ewv = (const float*)d_in[8];
    const float* ewo = (const float*)d_in[9];
    const float* ef1 = (const float*)d_in[10];
    const float* ef2 = (const float*)d_in[11];
    const float* eow = (const float*)d_in[12];
    const float* cb  = (const float*)d_in[13];
    const float* dfb = (const float*)d_in[14];
    const float* dfw = (const float*)d_in[15];
    const float* dw1 = (const float*)d_in[16];
    const float* dw2 = (const float*)d_in[17];
    const float* dw3 = (const float*)d_in[18];
    const float* dwq = (const float*)d_in[19];
    const float* dwk = (const float*)d_in[20];
    const float* dwv = (const float*)d_in[21];
    const float* dwo = (const float*)d_in[22];
    const float* df1 = (const float*)d_in[23];
    const float* df2 = (const float*)d_in[24];
    const float* dow = (const float*)d_in[25];
    float* out = (float*)d_out;

    float* ws = (float*)d_ws;
    float* qf   = ws;                       // 160 (padded 256)
    float* h    = ws + 256;                 // 3,145,728
    float* big  = h + 3145728;              // 4 x 3,145,728
    float* q    = big;
    float* kk   = big + 3145728;
    float* vv   = big + 2 * 3145728;
    float* t1   = big + 3 * (size_t)3145728;
    float* fmid = big;                      // aliases q/kk/vv/t1 (dead then)
    float* z    = big + 4 * (size_t)3145728;
    float* zvq  = z + NEL;
    float* zst  = zvq + NEL;
    float* z2   = zst + NEL;
    float* p1   = z2 + NEL;
    float* p2   = p1 + 128;

    auto run_half = [&](const float* xin, const float* fb, const float* fw,
                        const float* w1, const float* w2, const float* w3,
                        const float* wq, const float* wk, const float* wv,
                        const float* wo, const float* f1, const float* f2,
                        const float* owt, float* zout) {
        k_embed<<<BSN, 256, 0, stream>>>(xin, fb, fw, w1, qf, h);
        k_act<<<(BSN * 64 + 255) / 256, 256, 0, stream>>>(h, qf, 64);
        k_lin<64, 64><<<ROWS / 4, 256, 0, stream>>>(h, w2, nullptr, t1);
        k_act<<<(BSN * 64 + 255) / 256, 256, 0, stream>>>(t1, qf, 64);
        k_lin<64, 64><<<ROWS / 4, 256, 0, stream>>>(t1, w3, nullptr, h);
        k_posenc<<<(ROWS * 64 + 255) / 256, 256, 0, stream>>>(h, qf);
        for (int l = 0; l < LLAY; ++l) {
            size_t off  = (size_t)l * 7 * 64 * 64;
            size_t offf = (size_t)l * 7 * 256 * 64;
            k_lin<64, 64><<<ROWS / 4, 256, 0, stream>>>(h, wq + off, nullptr, q);
            k_lin<64, 64><<<ROWS / 4, 256, 0, stream>>>(h, wk + off, nullptr, kk);
            k_lin<64, 64><<<ROWS / 4, 256, 0, stream>>>(h, wv + off, nullptr, vv);
            k_attn<<<BB * HHEAD * SS, 256, 0, stream>>>(q, kk, vv, t1);
            k_lin<64, 64><<<ROWS / 4, 256, 0, stream>>>(t1, wo + off, h, h);
            k_lin<256, 64><<<ROWS, 256, 0, stream>>>(h, f1 + offf, nullptr, fmid);
            k_act<<<(BSN * 256 + 255) / 256, 256, 0, stream>>>(fmid, qf, 256);
            k_lin<64, 256><<<ROWS / 4, 256, 0, stream>>>(fmid, f2 + offf, h, h);
        }
        k_fcout<<<BSN, 64, 0, stream>>>(h, owt, qf, zout);
    };

    k_init_qf<<<1, 256, 0, stream>>>(qf);
    run_half(x, efb, efw, ew1, ew2, ew3, ewq, ewk, ewv, ewo, ef1, ef2, eow, z);
    k_vq<<<BSN, 256, 0, stream>>>(z, cb, zvq, zst);
    run_half(zst, dfb, dfw, dw1, dw2, dw3, dwq, dwk, dwv, dwo, df1, df2, dow, z2);
    k_recon<<<96, 256, 0, stream>>>(x, z2, out, p1);
    k_embloss<<<96, 256, 0, stream>>>(z, zvq, p2);
    k_final<<<1, 64, 0, stream>>>(p1, p2, out);
}

// Round 2
// 11359.960 us; speedup vs baseline: 2.2425x; 2.2425x over previous
//
#include <hip/hip_runtime.h>
#include <math.h>

#define BB 8
#define SS 512
#define MMDIM 64
#define HHEAD 8
#define LLAY 4
#define FFDIM 256
#define KCB 1024
#define BSN 4096          // B*S
#define ROWS 49152        // BS*12
#define NEL 49152         // B*S*12

__constant__ int d_REP[12] = {0,1,2,2,3,3,4,4,5,5,6,6};

// ---------------- QF init (144 entries) + row sums (12) ----------------
__global__ void k_init_qf(float* qf) {
    int t = threadIdx.x;
    if (t < 144) {
        int r = t / 12, j = t % 12;
        double v;
        if (r == 0)      v = 1.0 / sqrt(12.0);
        else if (r == 1) v = ((j & 1) ? -1.0 : 1.0) / sqrt(12.0);
        else {
            int m = r >> 1;
            double ang = 2.0 * 3.14159265358979323846 * (double)m * (double)j / 12.0;
            v = (((r & 1) == 0) ? cos(ang) : sin(ang)) / sqrt(6.0);
        }
        qf[t] = (float)v;
    }
    __syncthreads();
    if (t < 12) {
        float s = 0.f;
        for (int j = 0; j < 12; ++j) s += qf[t * 12 + j];
        qf[144 + t] = s;
    }
}

// ---------------- embed head entry ----------------
__global__ __launch_bounds__(256) void k_embed(const float* __restrict__ x,
                                               const float* __restrict__ fb,
                                               const float* __restrict__ fw,
                                               const float* __restrict__ w1,
                                               const float* __restrict__ qf,
                                               float* __restrict__ out) {
    int bs = blockIdx.x;
    __shared__ float xs[12], h1[12];
    int t = threadIdx.x;
    if (t < 12) xs[t] = x[bs * 12 + t] + fb[0];
    __syncthreads();
    if (t < 12) {
        float a = 0.f;
        for (int p = 0; p < 12; ++p) a += qf[t * 12 + p] * xs[p];
        h1[t] = a * fw[0];
    }
    __syncthreads();
    for (int e = t; e < 12 * 64; e += 256) {
        int d = e >> 6, o = e & 63;
        out[((size_t)bs * 12 + d) * 64 + o] = h1[d] * w1[d_REP[d] * 64 + o];
    }
}

// ---------------- act ----------------
__global__ __launch_bounds__(256) void k_act(float* __restrict__ h,
                                             const float* __restrict__ qf,
                                             int mdim) {
    const int starts[7] = {0, 1, 2, 4, 6, 8, 10};
    const int dks[7]    = {1, 1, 2, 2, 2, 2, 2};
    int idx = blockIdx.x * 256 + threadIdx.x;
    int total = BSN * mdim;
    if (idx >= total) return;
    int bs = idx / mdim, m = idx - bs * mdim;
    float* base = h + (size_t)bs * 12 * mdim + m;
    float v[12], o[12];
    for (int d = 0; d < 12; ++d) v[d] = base[d * mdim];
    for (int k = 0; k < 7; ++k) {
        int s = starts[k], dk = dks[k];
        float g[12];
        for (int pp = 0; pp < 12; ++pp) {
            float a = 0.f;
            for (int d = 0; d < dk; ++d) a += qf[(s + d) * 12 + pp] * v[s + d];
            g[pp] = 0.5f * a * (1.0f + erff(a * 0.7071067811865475f));
        }
        for (int d = 0; d < dk; ++d) {
            float a = 0.f;
            for (int pp = 0; pp < 12; ++pp) a += qf[(s + d) * 12 + pp] * g[pp];
            o[s + d] = a;
        }
    }
    for (int d = 0; d < 12; ++d) base[d * mdim] = o[d];
}

// ---------------- generic lin; PERM=1 writes head-major [b][h][s][96] ---
template <int O, int I, int PERM>
__global__ __launch_bounds__(256) void k_lin(const float* __restrict__ in,
                                             const float* __restrict__ W,
                                             const float* __restrict__ res,
                                             float* __restrict__ out) {
    constexpr int R = 256 / O;
    __shared__ float sIn[R][I];
    int t = threadIdx.x;
    int row0 = blockIdx.x * R;
    for (int e = t; e < R * I; e += 256) {
        int r = e / I, i = e - r * I;
        sIn[r][i] = in[(size_t)(row0 + r) * I + i];
    }
    __syncthreads();
    int r = t / O, o = t - r * O;
    int row = row0 + r;
    int d = row % 12;
    const float* w = W + ((size_t)d_REP[d] * O + o) * I;
    float acc = 0.f;
#pragma unroll
    for (int i = 0; i < I; ++i) acc += sIn[r][i] * w[i];
    if (PERM) {
        int bs = row / 12;
        int b = bs >> 9, s = bs & 511;
        int hh = o >> 3, mk = o & 7;
        out[(((size_t)(b * 8 + hh) * 512 + s) * 96) + d * 8 + mk] = acc;
    } else {
        size_t oi = (size_t)row * O + o;
        if (res) acc += res[oi];
        out[oi] = acc;
    }
}

// ---------------- attention v2: head-major, LDS two-pass ----------------
// grid: (bh * 32 + qt), 256 threads (4 waves). 16 q-rows per block.
// LDS: ps[512][16] swizzled (word k*16 + (r ^ (k&15))), qs[16][100], kvs[64][100]
__global__ __launch_bounds__(256) void k_attn2(const float* __restrict__ qh,
                                               const float* __restrict__ kh,
                                               const float* __restrict__ vh,
                                               float* __restrict__ out) {
    __shared__ float sm[16192];
    float* ps  = sm;            // 8192 floats
    float* qs  = sm + 8192;     // 1600 floats ([16][100]); later invs[16]
    float* kvs = sm + 9792;     // 6400 floats ([64][100]); later reduce buf

    int qt = blockIdx.x & 31;
    int bh = blockIdx.x >> 5;
    int t  = threadIdx.x;
    int w  = t >> 6;
    int r1 = t >> 4;            // pass1 row 0..15
    int ks = t & 15;            // pass1 k-sub

    const float4* qg = (const float4*)(qh + ((size_t)bh * 512 + qt * 16) * 96);
    const float4* kg = (const float4*)(kh + (size_t)bh * 512 * 96);
    const float4* vg = (const float4*)(vh + (size_t)bh * 512 * 96);

    // stage Q: 16x96 = 384 float4
    for (int e = t; e < 384; e += 256) {
        int row = e / 24, i4 = e % 24;
        float4 v = qg[e];
        *(float4*)&qs[row * 100 + i4 * 4] = v;
    }

    // ---- pass 1: scores -> ps (raw) ----
    for (int tile = 0; tile < 8; ++tile) {
        __syncthreads();
        for (int e = t; e < 1536; e += 256) {
            int row = e / 24, i4 = e % 24;
            *(float4*)&kvs[row * 100 + i4 * 4] = kg[tile * 384 + e];
        }
        __syncthreads();
        float s0 = 0.f, s1 = 0.f, s2 = 0.f, s3 = 0.f;
#pragma unroll
        for (int i4 = 0; i4 < 24; ++i4) {
            float4 q4 = *(const float4*)&qs[r1 * 100 + i4 * 4];
            float4 a = *(const float4*)&kvs[(ks     ) * 100 + i4 * 4];
            float4 b = *(const float4*)&kvs[(ks + 16) * 100 + i4 * 4];
            float4 c = *(const float4*)&kvs[(ks + 32) * 100 + i4 * 4];
            float4 d = *(const float4*)&kvs[(ks + 48) * 100 + i4 * 4];
            s0 += q4.x * a.x + q4.y * a.y + q4.z * a.z + q4.w * a.w;
            s1 += q4.x * b.x + q4.y * b.y + q4.z * b.z + q4.w * b.w;
            s2 += q4.x * c.x + q4.y * c.y + q4.z * c.z + q4.w * c.w;
            s3 += q4.x * d.x + q4.y * d.y + q4.z * d.z + q4.w * d.w;
        }
        int k0 = tile * 64 + ks;
        ps[(k0     ) * 16 + (r1 ^ ((k0     ) & 15))] = s0;
        ps[(k0 + 16) * 16 + (r1 ^ ((k0 + 16) & 15))] = s1;
        ps[(k0 + 32) * 16 + (r1 ^ ((k0 + 32) & 15))] = s2;
        ps[(k0 + 48) * 16 + (r1 ^ ((k0 + 48) & 15))] = s3;
    }
    __syncthreads();

    // ---- softmax per row (16 threads per row) ----
    const float scale = 0.10206207261596577f;   // 1/sqrt(96)
    float mx = -3.4e38f;
#pragma unroll
    for (int j = 0; j < 32; ++j) {
        int k = (j >> 2) * 64 + ks + (j & 3) * 16;
        mx = fmaxf(mx, ps[k * 16 + (r1 ^ (k & 15))]);
    }
    for (int m = 8; m; m >>= 1) mx = fmaxf(mx, __shfl_xor(mx, m));
    float sum = 0.f;
#pragma unroll
    for (int j = 0; j < 32; ++j) {
        int k = (j >> 2) * 64 + ks + (j & 3) * 16;
        int a = k * 16 + (r1 ^ (k & 15));
        float e = expf((ps[a] - mx) * scale);
        ps[a] = e;
        sum += e;
    }
    for (int m = 8; m; m >>= 1) sum += __shfl_xor(sum, m);
    if (ks == 0) qs[r1] = 1.0f / sum;   // qs dead as Q-buffer; reuse for inv

    // ---- pass 2: PV. wave w handles local k [w*16, w*16+16) of each tile.
    int r2 = t & 15;
    int dq = (t >> 4) & 3;
    float acc[24];
#pragma unroll
    for (int u = 0; u < 24; ++u) acc[u] = 0.f;
    for (int tile = 0; tile < 8; ++tile) {
        __syncthreads();
        for (int e = t; e < 1536; e += 256) {
            int row = e / 24, i4 = e % 24;
            *(float4*)&kvs[row * 100 + i4 * 4] = vg[tile * 384 + e];
        }
        __syncthreads();
        for (int kk = 0; kk < 16; ++kk) {
            int k = tile * 64 + w * 16 + kk;
            float pv = ps[k * 16 + (r2 ^ (k & 15))];
            const float* vr = &kvs[(w * 16 + kk) * 100 + dq * 24];
#pragma unroll
            for (int u4 = 0; u4 < 6; ++u4) {
                float4 v4 = *(const float4*)&vr[u4 * 4];
                acc[u4 * 4 + 0] += pv * v4.x;
                acc[u4 * 4 + 1] += pv * v4.y;
                acc[u4 * 4 + 2] += pv * v4.z;
                acc[u4 * 4 + 3] += pv * v4.w;
            }
        }
    }
    float inv = qs[r2];
#pragma unroll
    for (int u = 0; u < 24; ++u) acc[u] *= inv;
    __syncthreads();
    if (w) {
        float* red = &kvs[(w - 1) * 1600 + r2 * 100 + dq * 24];
#pragma unroll
        for (int u4 = 0; u4 < 6; ++u4)
            *(float4*)&red[u4 * 4] = make_float4(acc[u4*4], acc[u4*4+1], acc[u4*4+2], acc[u4*4+3]);
    }
    __syncthreads();
    if (w == 0) {
#pragma unroll
        for (int ww = 0; ww < 3; ++ww) {
            const float* red = &kvs[ww * 1600 + r2 * 100 + dq * 24];
#pragma unroll
            for (int u = 0; u < 24; ++u) acc[u] += red[u];
        }
        int b = bh >> 3, hh = bh & 7;
        int s = qt * 16 + r2;
        float* ob = out + (((size_t)(b * 512 + s)) * 12) * 64 + hh * 8;
#pragma unroll
        for (int u4 = 0; u4 < 6; ++u4) {
            int d = dq * 3 + (u4 >> 1);
            int mk = (u4 & 1) * 4;
            *(float4*)&ob[d * 64 + mk] = make_float4(acc[u4*4], acc[u4*4+1], acc[u4*4+2], acc[u4*4+3]);
        }
    }
}

// ---------------- fc_out ----------------
__global__ void k_fcout(const float* __restrict__ h, const float* __restrict__ w,
                        const float* __restrict__ qf, float* __restrict__ z) {
    int bs = blockIdx.x;
    __shared__ float td[12];
    int t = threadIdx.x;
    if (t < 12) {
        const float* row = h + ((size_t)bs * 12 + t) * 64;
        const float* wr  = w + d_REP[t] * 64;
        float a = 0.f;
        for (int i = 0; i < 64; ++i) a += row[i] * wr[i];
        td[t] = a;
    }
    __syncthreads();
    if (t < 12) {
        float a = 0.f;
        for (int d = 0; d < 12; ++d) a += qf[d * 12 + t] * td[d];
        z[bs * 12 + t] = a / 7.0f;
    }
}

// ---------------- VQ ----------------
__global__ __launch_bounds__(256) void k_vq(const float* __restrict__ z,
                                            const float* __restrict__ cb,
                                            float* __restrict__ zvq,
                                            float* __restrict__ zst) {
    int bs = blockIdx.x;
    int t = threadIdx.x;
    __shared__ float zv[12];
    __shared__ float sb[256];
    __shared__ int   si[256];
    if (t < 12) zv[t] = z[bs * 12 + t];
    __syncthreads();
    float zz = 0.f;
    for (int j = 0; j < 12; ++j) zz += zv[j] * zv[j];
    float best = 3.4e38f; int bi = 0x7fffffff;
    for (int c = t; c < KCB; c += 256) {
        const float* cr = cb + c * 12;
        float cc = 0.f, dot = 0.f;
        for (int j = 0; j < 12; ++j) { cc += cr[j] * cr[j]; dot += zv[j] * cr[j]; }
        float dist = zz + cc - 2.0f * dot;
        if (dist < best) { best = dist; bi = c; }
    }
    sb[t] = best; si[t] = bi; __syncthreads();
    for (int st = 128; st > 0; st >>= 1) {
        if (t < st) {
            if (sb[t + st] < sb[t] || (sb[t + st] == sb[t] && si[t + st] < si[t])) {
                sb[t] = sb[t + st]; si[t] = si[t + st];
            }
        }
        __syncthreads();
    }
    if (t < 12) {
        float c = cb[si[0] * 12 + t];
        zvq[bs * 12 + t] = c;
        float zi = zv[t];
        zst[bs * 12 + t] = (c - zi) + zi;
    }
}

// ---------------- positional encoding add ------------------------------
__global__ __launch_bounds__(256) void k_posenc(float* __restrict__ h,
                                                const float* __restrict__ qf) {
    int idx = blockIdx.x * 256 + threadIdx.x;
    if (idx >= ROWS * 64) return;
    int m = idx & 63;
    int r = idx >> 6;
    int d = r % 12;
    int bs = r / 12;
    int s = bs % SS;
    int i = m >> 1;
    float dv = expf((float)(2 * i) * (-0.14391156831212787f));
    float arg = (float)s * dv;
    float pe = (m & 1) ? cosf(arg) : sinf(arg);
    h[idx] += qf[144 + d] * pe;
}

// ---------------- losses ----------------
__global__ __launch_bounds__(256) void k_recon(const float* __restrict__ x,
                                               const float* __restrict__ logits,
                                               float* __restrict__ xr_out,
                                               float* __restrict__ partial) {
    __shared__ float red[256];
    int t = threadIdx.x;
    float acc = 0.f;
    for (int i = blockIdx.x * 256 + t; i < NEL; i += gridDim.x * 256) {
        float lg = logits[i];
        float xr = 1.0f / (1.0f + expf(-lg));
        xr_out[i] = xr;
        float xi = x[i];
        float l1 = fmaxf(logf(xr), -100.0f);
        float l2 = fmaxf(logf(1.0f - xr), -100.0f);
        acc += xi * l1 + (1.0f - xi) * l2;
    }
    red[t] = acc; __syncthreads();
    for (int st = 128; st > 0; st >>= 1) { if (t < st) red[t] += red[t + st]; __syncthreads(); }
    if (t == 0) partial[blockIdx.x] = red[0];
}

__global__ __launch_bounds__(256) void k_embloss(const float* __restrict__ z,
                                                 const float* __restrict__ zvq,
                                                 float* __restrict__ partial) {
    __shared__ float red[256];
    int t = threadIdx.x;
    float acc = 0.f;
    for (int i = blockIdx.x * 256 + t; i < NEL; i += gridDim.x * 256) {
        float d = zvq[i] - z[i];
        acc += d * d;
    }
    red[t] = acc; __syncthreads();
    for (int st = 128; st > 0; st >>= 1) { if (t < st) red[t] += red[t + st]; __syncthreads(); }
    if (t == 0) partial[blockIdx.x] = red[0];
}

__global__ void k_final(const float* __restrict__ p1, const float* __restrict__ p2,
                        float* __restrict__ out) {
    if (threadIdx.x == 0) {
        float s1 = 0.f, s2 = 0.f;
        for (int i = 0; i < 96; ++i) { s1 += p1[i]; s2 += p2[i]; }
        out[NEL]     = -s1 / (float)NEL;
        out[NEL + 1] =  s2 / (float)NEL;
        out[NEL + 2] =  s2 / (float)NEL;
    }
}

// ------------------------------------------------------------------------
extern "C" void kernel_launch(void* const* d_in, const int* in_sizes, int n_in,
                              void* d_out, int out_size, void* d_ws, size_t ws_size,
                              hipStream_t stream) {
    const float* x   = (const float*)d_in[0];
    const float* efb = (const float*)d_in[1];
    const float* efw = (const float*)d_in[2];
    const float* ew1 = (const float*)d_in[3];
    const float* ew2 = (const float*)d_in[4];
    const float* ew3 = (const float*)d_in[5];
    const float* ewq = (const float*)d_in[6];
    const float* ewk = (const float*)d_in[7];
    const float* ewv = (const float*)d_in[8];
    const float* ewo = (const float*)d_in[9];
    const float* ef1 = (const float*)d_in[10];
    const float* ef2 = (const float*)d_in[11];
    const float* eow = (const float*)d_in[12];
    const float* cb  = (const float*)d_in[13];
    const float* dfb = (const float*)d_in[14];
    const float* dfw = (const float*)d_in[15];
    const float* dw1 = (const float*)d_in[16];
    const float* dw2 = (const float*)d_in[17];
    const float* dw3 = (const float*)d_in[18];
    const float* dwq = (const float*)d_in[19];
    const float* dwk = (const float*)d_in[20];
    const float* dwv = (const float*)d_in[21];
    const float* dwo = (const float*)d_in[22];
    const float* df1 = (const float*)d_in[23];
    const float* df2 = (const float*)d_in[24];
    const float* dow = (const float*)d_in[25];
    float* out = (float*)d_out;

    float* ws = (float*)d_ws;
    float* qf   = ws;                       // 256
    float* h    = ws + 256;                 // 3,145,728
    float* big  = h + 3145728;              // 4 x 3,145,728
    float* q    = big;
    float* kk   = big + 3145728;
    float* vv   = big + 2 * 3145728;
    float* t1   = big + 3 * (size_t)3145728;
    float* fmid = big;                      // aliases q/kk/vv/t1 (dead then)
    float* z    = big + 4 * (size_t)3145728;
    float* zvq  = z + NEL;
    float* zst  = zvq + NEL;
    float* z2   = zst + NEL;
    float* p1   = z2 + NEL;
    float* p2   = p1 + 128;

    auto run_half = [&](const float* xin, const float* fb, const float* fw,
                        const float* w1, const float* w2, const float* w3,
                        const float* wq, const float* wk, const float* wv,
                        const float* wo, const float* f1, const float* f2,
                        const float* owt, float* zout) {
        k_embed<<<BSN, 256, 0, stream>>>(xin, fb, fw, w1, qf, h);
        k_act<<<(BSN * 64 + 255) / 256, 256, 0, stream>>>(h, qf, 64);
        k_lin<64, 64, 0><<<ROWS / 4, 256, 0, stream>>>(h, w2, nullptr, t1);
        k_act<<<(BSN * 64 + 255) / 256, 256, 0, stream>>>(t1, qf, 64);
        k_lin<64, 64, 0><<<ROWS / 4, 256, 0, stream>>>(t1, w3, nullptr, h);
        k_posenc<<<(ROWS * 64 + 255) / 256, 256, 0, stream>>>(h, qf);
        for (int l = 0; l < LLAY; ++l) {
            size_t off  = (size_t)l * 7 * 64 * 64;
            size_t offf = (size_t)l * 7 * 256 * 64;
            k_lin<64, 64, 1><<<ROWS / 4, 256, 0, stream>>>(h, wq + off, nullptr, q);
            k_lin<64, 64, 1><<<ROWS / 4, 256, 0, stream>>>(h, wk + off, nullptr, kk);
            k_lin<64, 64, 1><<<ROWS / 4, 256, 0, stream>>>(h, wv + off, nullptr, vv);
            k_attn2<<<BB * HHEAD * 32, 256, 0, stream>>>(q, kk, vv, t1);
            k_lin<64, 64, 0><<<ROWS / 4, 256, 0, stream>>>(t1, wo + off, h, h);
            k_lin<256, 64, 0><<<ROWS, 256, 0, stream>>>(h, f1 + offf, nullptr, fmid);
            k_act<<<(BSN * 256 + 255) / 256, 256, 0, stream>>>(fmid, qf, 256);
            k_lin<64, 256, 0><<<ROWS / 4, 256, 0, stream>>>(fmid, f2 + offf, h, h);
        }
        k_fcout<<<BSN, 64, 0, stream>>>(h, owt, qf, zout);
    };

    k_init_qf<<<1, 256, 0, stream>>>(qf);
    run_half(x, efb, efw, ew1, ew2, ew3, ewq, ewk, ewv, ewo, ef1, ef2, eow, z);
    k_vq<<<BSN, 256, 0, stream>>>(z, cb, zvq, zst);
    run_half(zst, dfb, dfw, dw1, dw2, dw3, dwq, dwk, dwv, dwo, df1, df2, dow, z2);
    k_recon<<<96, 256, 0, stream>>>(x, z2, out, p1);
    k_embloss<<<96, 256, 0, stream>>>(z, zvq, p2);
    k_final<<<1, 64, 0, stream>>>(p1, p2, out);
}

// Round 3
// 3730.265 us; speedup vs baseline: 6.8292x; 3.0453x over previous
//
#include <hip/hip_runtime.h>
#include <math.h>

#define BB 8
#define SS 512
#define MMDIM 64
#define HHEAD 8
#define LLAY 4
#define FFDIM 256
#define KCB 1024
#define BSN 4096          // B*S
#define ROWS 49152        // BS*12
#define NEL 49152         // B*S*12

__constant__ int d_REP[12] = {0,1,2,2,3,3,4,4,5,5,6,6};

// ---------------- QF init (144 entries) + row sums (12) ----------------
__global__ void k_init_qf(float* qf) {
    int t = threadIdx.x;
    if (t < 144) {
        int r = t / 12, j = t % 12;
        double v;
        if (r == 0)      v = 1.0 / sqrt(12.0);
        else if (r == 1) v = ((j & 1) ? -1.0 : 1.0) / sqrt(12.0);
        else {
            int m = r >> 1;
            double ang = 2.0 * 3.14159265358979323846 * (double)m * (double)j / 12.0;
            v = (((r & 1) == 0) ? cos(ang) : sin(ang)) / sqrt(6.0);
        }
        qf[t] = (float)v;
    }
    __syncthreads();
    if (t < 12) {
        float s = 0.f;
        for (int j = 0; j < 12; ++j) s += qf[t * 12 + j];
        qf[144 + t] = s;
    }
}

// ---------------- embed head entry ----------------
__global__ __launch_bounds__(256) void k_embed(const float* __restrict__ x,
                                               const float* __restrict__ fb,
                                               const float* __restrict__ fw,
                                               const float* __restrict__ w1,
                                               const float* __restrict__ qf,
                                               float* __restrict__ out) {
    int bs = blockIdx.x;
    __shared__ float xs[12], h1[12];
    int t = threadIdx.x;
    if (t < 12) xs[t] = x[bs * 12 + t] + fb[0];
    __syncthreads();
    if (t < 12) {
        float a = 0.f;
        for (int p = 0; p < 12; ++p) a += qf[t * 12 + p] * xs[p];
        h1[t] = a * fw[0];
    }
    __syncthreads();
    for (int e = t; e < 12 * 64; e += 256) {
        int d = e >> 6, o = e & 63;
        out[((size_t)bs * 12 + d) * 64 + o] = h1[d] * w1[d_REP[d] * 64 + o];
    }
}

// ---------------- act ----------------
__global__ __launch_bounds__(256) void k_act(float* __restrict__ h,
                                             const float* __restrict__ qf,
                                             int mdim) {
    const int starts[7] = {0, 1, 2, 4, 6, 8, 10};
    const int dks[7]    = {1, 1, 2, 2, 2, 2, 2};
    int idx = blockIdx.x * 256 + threadIdx.x;
    int total = BSN * mdim;
    if (idx >= total) return;
    int bs = idx / mdim, m = idx - bs * mdim;
    float* base = h + (size_t)bs * 12 * mdim + m;
    float v[12], o[12];
    for (int d = 0; d < 12; ++d) v[d] = base[d * mdim];
    for (int k = 0; k < 7; ++k) {
        int s = starts[k], dk = dks[k];
        float g[12];
        for (int pp = 0; pp < 12; ++pp) {
            float a = 0.f;
            for (int d = 0; d < dk; ++d) a += qf[(s + d) * 12 + pp] * v[s + d];
            g[pp] = 0.5f * a * (1.0f + erff(a * 0.7071067811865475f));
        }
        for (int d = 0; d < dk; ++d) {
            float a = 0.f;
            for (int pp = 0; pp < 12; ++pp) a += qf[(s + d) * 12 + pp] * g[pp];
            o[s + d] = a;
        }
    }
    for (int d = 0; d < 12; ++d) base[d * mdim] = o[d];
}

// ---------------- register-tiled lin v3 ---------------------------------
// grid (12, 4096/64, O/64). block 256. 64-row x 64-col tile per block.
// thread (tr,tc) owns rows bs0+tr+16i, cols c0+tc+16j (i,j in 0..3).
// LDS stride 66: staging writes 2-way max; inner reads conflict-free.
template <int O, int I, int PERM, int RES>
__global__ __launch_bounds__(256) void k_lin3(const float* __restrict__ in,
                                              const float* __restrict__ W,
                                              const float* __restrict__ res,
                                              float* __restrict__ out) {
    const int d   = blockIdx.x;
    const int bs0 = blockIdx.y * 64;
    const int c0  = blockIdx.z * 64;
    __shared__ float sIn[64 * 66];
    __shared__ float sW[64 * 66];
    const int t  = threadIdx.x;
    const int tr = t >> 4, tc = t & 15;
    float acc[4][4];
#pragma unroll
    for (int i = 0; i < 4; ++i)
#pragma unroll
        for (int j = 0; j < 4; ++j) acc[i][j] = 0.f;

    const float* wbase = W + ((size_t)d_REP[d] * O + c0) * I;

    for (int kc = 0; kc < I; kc += 64) {
        __syncthreads();
        for (int e = t; e < 1024; e += 256) {
            int r = e >> 4, q = e & 15;
            const float* g = in + ((size_t)(bs0 + r) * 12 + d) * I + kc + q * 4;
            float4 v = *(const float4*)g;
            float* s = &sIn[r * 66 + q * 4];
            s[0] = v.x; s[1] = v.y; s[2] = v.z; s[3] = v.w;
        }
        for (int e = t; e < 1024; e += 256) {
            int c = e >> 4, q = e & 15;
            const float* g = wbase + (size_t)c * I + kc + q * 4;
            float4 v = *(const float4*)g;
            float* s = &sW[c * 66 + q * 4];
            s[0] = v.x; s[1] = v.y; s[2] = v.z; s[3] = v.w;
        }
        __syncthreads();
#pragma unroll
        for (int k = 0; k < 64; k += 2) {
            float2 a[4], b[4];
#pragma unroll
            for (int i = 0; i < 4; ++i) a[i] = *(const float2*)&sIn[(tr + 16 * i) * 66 + k];
#pragma unroll
            for (int j = 0; j < 4; ++j) b[j] = *(const float2*)&sW[(tc + 16 * j) * 66 + k];
#pragma unroll
            for (int i = 0; i < 4; ++i)
#pragma unroll
                for (int j = 0; j < 4; ++j)
                    acc[i][j] += a[i].x * b[j].x + a[i].y * b[j].y;
        }
    }

#pragma unroll
    for (int i = 0; i < 4; ++i) {
        int bs = bs0 + tr + 16 * i;
        size_t row = (size_t)bs * 12 + d;
        if (PERM) {
            int b = bs >> 9, s = bs & 511;
#pragma unroll
            for (int j = 0; j < 4; ++j) {
                int o = c0 + tc + 16 * j;
                int hh = o >> 3, mk = o & 7;
                out[(((size_t)(b * 8 + hh) * 512 + s) * 96) + d * 8 + mk] = acc[i][j];
            }
        } else if (RES) {
            float* ob = out + row * O + c0;
            const float* rb = res + row * O + c0;
#pragma unroll
            for (int j = 0; j < 4; ++j) ob[tc + 16 * j] = acc[i][j] + rb[tc + 16 * j];
        } else {
            float* ob = out + row * O + c0;
#pragma unroll
            for (int j = 0; j < 4; ++j) ob[tc + 16 * j] = acc[i][j];
        }
    }
}

// ---------------- attention v2: head-major, LDS two-pass ----------------
__global__ __launch_bounds__(256) void k_attn2(const float* __restrict__ qh,
                                               const float* __restrict__ kh,
                                               const float* __restrict__ vh,
                                               float* __restrict__ out) {
    __shared__ float sm[16192];
    float* ps  = sm;            // 8192 floats
    float* qs  = sm + 8192;     // 1600 floats ([16][100]); later invs[16]
    float* kvs = sm + 9792;     // 6400 floats ([64][100]); later reduce buf

    int qt = blockIdx.x & 31;
    int bh = blockIdx.x >> 5;
    int t  = threadIdx.x;
    int w  = t >> 6;
    int r1 = t >> 4;
    int ks = t & 15;

    const float4* qg = (const float4*)(qh + ((size_t)bh * 512 + qt * 16) * 96);
    const float4* kg = (const float4*)(kh + (size_t)bh * 512 * 96);
    const float4* vg = (const float4*)(vh + (size_t)bh * 512 * 96);

    for (int e = t; e < 384; e += 256) {
        int row = e / 24, i4 = e % 24;
        float4 v = qg[e];
        *(float4*)&qs[row * 100 + i4 * 4] = v;
    }

    for (int tile = 0; tile < 8; ++tile) {
        __syncthreads();
        for (int e = t; e < 1536; e += 256) {
            int row = e / 24, i4 = e % 24;
            *(float4*)&kvs[row * 100 + i4 * 4] = kg[tile * 384 + e];
        }
        __syncthreads();
        float s0 = 0.f, s1 = 0.f, s2 = 0.f, s3 = 0.f;
#pragma unroll
        for (int i4 = 0; i4 < 24; ++i4) {
            float4 q4 = *(const float4*)&qs[r1 * 100 + i4 * 4];
            float4 a = *(const float4*)&kvs[(ks     ) * 100 + i4 * 4];
            float4 b = *(const float4*)&kvs[(ks + 16) * 100 + i4 * 4];
            float4 c = *(const float4*)&kvs[(ks + 32) * 100 + i4 * 4];
            float4 d = *(const float4*)&kvs[(ks + 48) * 100 + i4 * 4];
            s0 += q4.x * a.x + q4.y * a.y + q4.z * a.z + q4.w * a.w;
            s1 += q4.x * b.x + q4.y * b.y + q4.z * b.z + q4.w * b.w;
            s2 += q4.x * c.x + q4.y * c.y + q4.z * c.z + q4.w * c.w;
            s3 += q4.x * d.x + q4.y * d.y + q4.z * d.z + q4.w * d.w;
        }
        int k0 = tile * 64 + ks;
        ps[(k0     ) * 16 + (r1 ^ ((k0     ) & 15))] = s0;
        ps[(k0 + 16) * 16 + (r1 ^ ((k0 + 16) & 15))] = s1;
        ps[(k0 + 32) * 16 + (r1 ^ ((k0 + 32) & 15))] = s2;
        ps[(k0 + 48) * 16 + (r1 ^ ((k0 + 48) & 15))] = s3;
    }
    __syncthreads();

    const float scale = 0.10206207261596577f;   // 1/sqrt(96)
    float mx = -3.4e38f;
#pragma unroll
    for (int j = 0; j < 32; ++j) {
        int k = (j >> 2) * 64 + ks + (j & 3) * 16;
        mx = fmaxf(mx, ps[k * 16 + (r1 ^ (k & 15))]);
    }
    for (int m = 8; m; m >>= 1) mx = fmaxf(mx, __shfl_xor(mx, m));
    float sum = 0.f;
#pragma unroll
    for (int j = 0; j < 32; ++j) {
        int k = (j >> 2) * 64 + ks + (j & 3) * 16;
        int a = k * 16 + (r1 ^ (k & 15));
        float e = expf((ps[a] - mx) * scale);
        ps[a] = e;
        sum += e;
    }
    for (int m = 8; m; m >>= 1) sum += __shfl_xor(sum, m);
    if (ks == 0) qs[r1] = 1.0f / sum;

    int r2 = t & 15;
    int dq = (t >> 4) & 3;
    float acc[24];
#pragma unroll
    for (int u = 0; u < 24; ++u) acc[u] = 0.f;
    for (int tile = 0; tile < 8; ++tile) {
        __syncthreads();
        for (int e = t; e < 1536; e += 256) {
            int row = e / 24, i4 = e % 24;
            *(float4*)&kvs[row * 100 + i4 * 4] = vg[tile * 384 + e];
        }
        __syncthreads();
        for (int kk = 0; kk < 16; ++kk) {
            int k = tile * 64 + w * 16 + kk;
            float pv = ps[k * 16 + (r2 ^ (k & 15))];
            const float* vr = &kvs[(w * 16 + kk) * 100 + dq * 24];
#pragma unroll
            for (int u4 = 0; u4 < 6; ++u4) {
                float4 v4 = *(const float4*)&vr[u4 * 4];
                acc[u4 * 4 + 0] += pv * v4.x;
                acc[u4 * 4 + 1] += pv * v4.y;
                acc[u4 * 4 + 2] += pv * v4.z;
                acc[u4 * 4 + 3] += pv * v4.w;
            }
        }
    }
    float inv = qs[r2];
#pragma unroll
    for (int u = 0; u < 24; ++u) acc[u] *= inv;
    __syncthreads();
    if (w) {
        float* red = &kvs[(w - 1) * 1600 + r2 * 100 + dq * 24];
#pragma unroll
        for (int u4 = 0; u4 < 6; ++u4)
            *(float4*)&red[u4 * 4] = make_float4(acc[u4*4], acc[u4*4+1], acc[u4*4+2], acc[u4*4+3]);
    }
    __syncthreads();
    if (w == 0) {
#pragma unroll
        for (int ww = 0; ww < 3; ++ww) {
            const float* red = &kvs[ww * 1600 + r2 * 100 + dq * 24];
#pragma unroll
            for (int u = 0; u < 24; ++u) acc[u] += red[u];
        }
        int b = bh >> 3, hh = bh & 7;
        int s = qt * 16 + r2;
        float* ob = out + (((size_t)(b * 512 + s)) * 12) * 64 + hh * 8;
#pragma unroll
        for (int u4 = 0; u4 < 6; ++u4) {
            int d = dq * 3 + (u4 >> 1);
            int mk = (u4 & 1) * 4;
            *(float4*)&ob[d * 64 + mk] = make_float4(acc[u4*4], acc[u4*4+1], acc[u4*4+2], acc[u4*4+3]);
        }
    }
}

// ---------------- fc_out ----------------
__global__ void k_fcout(const float* __restrict__ h, const float* __restrict__ w,
                        const float* __restrict__ qf, float* __restrict__ z) {
    int bs = blockIdx.x;
    __shared__ float td[12];
    int t = threadIdx.x;
    if (t < 12) {
        const float* row = h + ((size_t)bs * 12 + t) * 64;
        const float* wr  = w + d_REP[t] * 64;
        float a = 0.f;
        for (int i = 0; i < 64; ++i) a += row[i] * wr[i];
        td[t] = a;
    }
    __syncthreads();
    if (t < 12) {
        float a = 0.f;
        for (int d = 0; d < 12; ++d) a += qf[d * 12 + t] * td[d];
        z[bs * 12 + t] = a / 7.0f;
    }
}

// ---------------- VQ ----------------
__global__ __launch_bounds__(256) void k_vq(const float* __restrict__ z,
                                            const float* __restrict__ cb,
                                            float* __restrict__ zvq,
                                            float* __restrict__ zst) {
    int bs = blockIdx.x;
    int t = threadIdx.x;
    __shared__ float zv[12];
    __shared__ float sb[256];
    __shared__ int   si[256];
    if (t < 12) zv[t] = z[bs * 12 + t];
    __syncthreads();
    float zz = 0.f;
    for (int j = 0; j < 12; ++j) zz += zv[j] * zv[j];
    float best = 3.4e38f; int bi = 0x7fffffff;
    for (int c = t; c < KCB; c += 256) {
        const float* cr = cb + c * 12;
        float cc = 0.f, dot = 0.f;
        for (int j = 0; j < 12; ++j) { cc += cr[j] * cr[j]; dot += zv[j] * cr[j]; }
        float dist = zz + cc - 2.0f * dot;
        if (dist < best) { best = dist; bi = c; }
    }
    sb[t] = best; si[t] = bi; __syncthreads();
    for (int st = 128; st > 0; st >>= 1) {
        if (t < st) {
            if (sb[t + st] < sb[t] || (sb[t + st] == sb[t] && si[t + st] < si[t])) {
                sb[t] = sb[t + st]; si[t] = si[t + st];
            }
        }
        __syncthreads();
    }
    if (t < 12) {
        float c = cb[si[0] * 12 + t];
        zvq[bs * 12 + t] = c;
        float zi = zv[t];
        zst[bs * 12 + t] = (c - zi) + zi;
    }
}

// ---------------- positional encoding add ------------------------------
__global__ __launch_bounds__(256) void k_posenc(float* __restrict__ h,
                                                const float* __restrict__ qf) {
    int idx = blockIdx.x * 256 + threadIdx.x;
    if (idx >= ROWS * 64) return;
    int m = idx & 63;
    int r = idx >> 6;
    int d = r % 12;
    int bs = r / 12;
    int s = bs % SS;
    int i = m >> 1;
    float dv = expf((float)(2 * i) * (-0.14391156831212787f));
    float arg = (float)s * dv;
    float pe = (m & 1) ? cosf(arg) : sinf(arg);
    h[idx] += qf[144 + d] * pe;
}

// ---------------- losses ----------------
__global__ __launch_bounds__(256) void k_recon(const float* __restrict__ x,
                                               const float* __restrict__ logits,
                                               float* __restrict__ xr_out,
                                               float* __restrict__ partial) {
    __shared__ float red[256];
    int t = threadIdx.x;
    float acc = 0.f;
    for (int i = blockIdx.x * 256 + t; i < NEL; i += gridDim.x * 256) {
        float lg = logits[i];
        float xr = 1.0f / (1.0f + expf(-lg));
        xr_out[i] = xr;
        float xi = x[i];
        float l1 = fmaxf(logf(xr), -100.0f);
        float l2 = fmaxf(logf(1.0f - xr), -100.0f);
        acc += xi * l1 + (1.0f - xi) * l2;
    }
    red[t] = acc; __syncthreads();
    for (int st = 128; st > 0; st >>= 1) { if (t < st) red[t] += red[t + st]; __syncthreads(); }
    if (t == 0) partial[blockIdx.x] = red[0];
}

__global__ __launch_bounds__(256) void k_embloss(const float* __restrict__ z,
                                                 const float* __restrict__ zvq,
                                                 float* __restrict__ partial) {
    __shared__ float red[256];
    int t = threadIdx.x;
    float acc = 0.f;
    for (int i = blockIdx.x * 256 + t; i < NEL; i += gridDim.x * 256) {
        float d = zvq[i] - z[i];
        acc += d * d;
    }
    red[t] = acc; __syncthreads();
    for (int st = 128; st > 0; st >>= 1) { if (t < st) red[t] += red[t + st]; __syncthreads(); }
    if (t == 0) partial[blockIdx.x] = red[0];
}

__global__ void k_final(const float* __restrict__ p1, const float* __restrict__ p2,
                        float* __restrict__ out) {
    if (threadIdx.x == 0) {
        float s1 = 0.f, s2 = 0.f;
        for (int i = 0; i < 96; ++i) { s1 += p1[i]; s2 += p2[i]; }
        out[NEL]     = -s1 / (float)NEL;
        out[NEL + 1] =  s2 / (float)NEL;
        out[NEL + 2] =  s2 / (float)NEL;
    }
}

// ------------------------------------------------------------------------
extern "C" void kernel_launch(void* const* d_in, const int* in_sizes, int n_in,
                              void* d_out, int out_size, void* d_ws, size_t ws_size,
                              hipStream_t stream) {
    const float* x   = (const float*)d_in[0];
    const float* efb = (const float*)d_in[1];
    const float* efw = (const float*)d_in[2];
    const float* ew1 = (const float*)d_in[3];
    const float* ew2 = (const float*)d_in[4];
    const float* ew3 = (const float*)d_in[5];
    const float* ewq = (const float*)d_in[6];
    const float* ewk = (const float*)d_in[7];
    const float* ewv = (const float*)d_in[8];
    const float* ewo = (const float*)d_in[9];
    const float* ef1 = (const float*)d_in[10];
    const float* ef2 = (const float*)d_in[11];
    const float* eow = (const float*)d_in[12];
    const float* cb  = (const float*)d_in[13];
    const float* dfb = (const float*)d_in[14];
    const float* dfw = (const float*)d_in[15];
    const float* dw1 = (const float*)d_in[16];
    const float* dw2 = (const float*)d_in[17];
    const float* dw3 = (const float*)d_in[18];
    const float* dwq = (const float*)d_in[19];
    const float* dwk = (const float*)d_in[20];
    const float* dwv = (const float*)d_in[21];
    const float* dwo = (const float*)d_in[22];
    const float* df1 = (const float*)d_in[23];
    const float* df2 = (const float*)d_in[24];
    const float* dow = (const float*)d_in[25];
    float* out = (float*)d_out;

    float* ws = (float*)d_ws;
    float* qf   = ws;                       // 256
    float* h    = ws + 256;                 // 3,145,728
    float* big  = h + 3145728;              // 4 x 3,145,728
    float* q    = big;
    float* kk   = big + 3145728;
    float* vv   = big + 2 * 3145728;
    float* t1   = big + 3 * (size_t)3145728;
    float* fmid = big;                      // aliases q/kk/vv/t1 (dead then)
    float* z    = big + 4 * (size_t)3145728;
    float* zvq  = z + NEL;
    float* zst  = zvq + NEL;
    float* z2   = zst + NEL;
    float* p1   = z2 + NEL;
    float* p2   = p1 + 128;

    auto run_half = [&](const float* xin, const float* fb, const float* fw,
                        const float* w1, const float* w2, const float* w3,
                        const float* wq, const float* wk, const float* wv,
                        const float* wo, const float* f1, const float* f2,
                        const float* owt, float* zout) {
        k_embed<<<BSN, 256, 0, stream>>>(xin, fb, fw, w1, qf, h);
        k_act<<<(BSN * 64 + 255) / 256, 256, 0, stream>>>(h, qf, 64);
        k_lin3<64, 64, 0, 0><<<dim3(12, 64, 1), 256, 0, stream>>>(h, w2, nullptr, t1);
        k_act<<<(BSN * 64 + 255) / 256, 256, 0, stream>>>(t1, qf, 64);
        k_lin3<64, 64, 0, 0><<<dim3(12, 64, 1), 256, 0, stream>>>(t1, w3, nullptr, h);
        k_posenc<<<(ROWS * 64 + 255) / 256, 256, 0, stream>>>(h, qf);
        for (int l = 0; l < LLAY; ++l) {
            size_t off  = (size_t)l * 7 * 64 * 64;
            size_t offf = (size_t)l * 7 * 256 * 64;
            k_lin3<64, 64, 1, 0><<<dim3(12, 64, 1), 256, 0, stream>>>(h, wq + off, nullptr, q);
            k_lin3<64, 64, 1, 0><<<dim3(12, 64, 1), 256, 0, stream>>>(h, wk + off, nullptr, kk);
            k_lin3<64, 64, 1, 0><<<dim3(12, 64, 1), 256, 0, stream>>>(h, wv + off, nullptr, vv);
            k_attn2<<<BB * HHEAD * 32, 256, 0, stream>>>(q, kk, vv, t1);
            k_lin3<64, 64, 0, 1><<<dim3(12, 64, 1), 256, 0, stream>>>(t1, wo + off, h, h);
            k_lin3<256, 64, 0, 0><<<dim3(12, 64, 4), 256, 0, stream>>>(h, f1 + offf, nullptr, fmid);
            k_act<<<(BSN * 256 + 255) / 256, 256, 0, stream>>>(fmid, qf, 256);
            k_lin3<64, 256, 0, 1><<<dim3(12, 64, 1), 256, 0, stream>>>(fmid, f2 + offf, h, h);
        }
        k_fcout<<<BSN, 64, 0, stream>>>(h, owt, qf, zout);
    };

    k_init_qf<<<1, 256, 0, stream>>>(qf);
    run_half(x, efb, efw, ew1, ew2, ew3, ewq, ewk, ewv, ewo, ef1, ef2, eow, z);
    k_vq<<<BSN, 256, 0, stream>>>(z, cb, zvq, zst);
    run_half(zst, dfb, dfw, dw1, dw2, dw3, dwq, dwk, dwv, dwo, df1, df2, dow, z2);
    k_recon<<<96, 256, 0, stream>>>(x, z2, out, p1);
    k_embloss<<<96, 256, 0, stream>>>(z, zvq, p2);
    k_final<<<1, 64, 0, stream>>>(p1, p2, out);
}

// Round 4
// 2424.845 us; speedup vs baseline: 10.5057x; 1.5384x over previous
//
#include <hip/hip_runtime.h>
#include <math.h>

#define BB 8
#define SS 512
#define HHEAD 8
#define LLAY 4
#define KCB 1024
#define BSN 4096          // B*S
#define ROWS 49152        // BS*12
#define NEL 49152         // B*S*12

__constant__ int d_REP[12] = {0,1,2,2,3,3,4,4,5,5,6,6};

typedef __attribute__((ext_vector_type(8))) short bf16x8;
typedef __attribute__((ext_vector_type(4))) float f32x4;

__device__ inline unsigned short f2bf(float x) {
    unsigned u = __builtin_bit_cast(unsigned, x);
    u += 0x7FFF + ((u >> 16) & 1);
    return (unsigned short)(u >> 16);
}

// ---------------- QF init (144 entries) + row sums (12) ----------------
__global__ void k_init_qf(float* qf) {
    int t = threadIdx.x;
    if (t < 144) {
        int r = t / 12, j = t % 12;
        double v;
        if (r == 0)      v = 1.0 / sqrt(12.0);
        else if (r == 1) v = ((j & 1) ? -1.0 : 1.0) / sqrt(12.0);
        else {
            int m = r >> 1;
            double ang = 2.0 * 3.14159265358979323846 * (double)m * (double)j / 12.0;
            v = (((r & 1) == 0) ? cos(ang) : sin(ang)) / sqrt(6.0);
        }
        qf[t] = (float)v;
    }
    __syncthreads();
    if (t < 12) {
        float s = 0.f;
        for (int j = 0; j < 12; ++j) s += qf[t * 12 + j];
        qf[144 + t] = s;
    }
}

// ---------------- embed head entry ----------------
__global__ __launch_bounds__(256) void k_embed(const float* __restrict__ x,
                                               const float* __restrict__ fb,
                                               const float* __restrict__ fw,
                                               const float* __restrict__ w1,
                                               const float* __restrict__ qf,
                                               float* __restrict__ out) {
    int bs = blockIdx.x;
    __shared__ float xs[12], h1[12];
    int t = threadIdx.x;
    if (t < 12) xs[t] = x[bs * 12 + t] + fb[0];
    __syncthreads();
    if (t < 12) {
        float a = 0.f;
        for (int p = 0; p < 12; ++p) a += qf[t * 12 + p] * xs[p];
        h1[t] = a * fw[0];
    }
    __syncthreads();
    for (int e = t; e < 12 * 64; e += 256) {
        int d = e >> 6, o = e & 63;
        out[((size_t)bs * 12 + d) * 64 + o] = h1[d] * w1[d_REP[d] * 64 + o];
    }
}

// ---------------- act ----------------
__global__ __launch_bounds__(256) void k_act(float* __restrict__ h,
                                             const float* __restrict__ qf,
                                             int mdim) {
    const int starts[7] = {0, 1, 2, 4, 6, 8, 10};
    const int dks[7]    = {1, 1, 2, 2, 2, 2, 2};
    int idx = blockIdx.x * 256 + threadIdx.x;
    int total = BSN * mdim;
    if (idx >= total) return;
    int bs = idx / mdim, m = idx - bs * mdim;
    float* base = h + (size_t)bs * 12 * mdim + m;
    float v[12], o[12];
    for (int d = 0; d < 12; ++d) v[d] = base[d * mdim];
    for (int k = 0; k < 7; ++k) {
        int s = starts[k], dk = dks[k];
        float g[12];
        for (int pp = 0; pp < 12; ++pp) {
            float a = 0.f;
            for (int d = 0; d < dk; ++d) a += qf[(s + d) * 12 + pp] * v[s + d];
            g[pp] = 0.5f * a * (1.0f + erff(a * 0.7071067811865475f));
        }
        for (int d = 0; d < dk; ++d) {
            float a = 0.f;
            for (int pp = 0; pp < 12; ++pp) a += qf[(s + d) * 12 + pp] * g[pp];
            o[s + d] = a;
        }
    }
    for (int d = 0; d < 12; ++d) base[d * mdim] = o[d];
}

// ---------------- register-tiled lin v3 ---------------------------------
// PERM: 0 = fp32 [bs][12][O]; 1 = bf16 head-major [bh][s][96]; 2 = bf16 V^T [bh][96][s]
template <int O, int I, int PERM, int RES>
__global__ __launch_bounds__(256) void k_lin3(const float* __restrict__ in,
                                              const float* __restrict__ W,
                                              const float* __restrict__ res,
                                              void* __restrict__ outv) {
    const int d   = blockIdx.x;
    const int bs0 = blockIdx.y * 64;
    const int c0  = blockIdx.z * 64;
    __shared__ float sIn[64 * 66];
    __shared__ float sW[64 * 66];
    const int t  = threadIdx.x;
    const int tr = t >> 4, tc = t & 15;
    float acc[4][4];
#pragma unroll
    for (int i = 0; i < 4; ++i)
#pragma unroll
        for (int j = 0; j < 4; ++j) acc[i][j] = 0.f;

    const float* wbase = W + ((size_t)d_REP[d] * O + c0) * I;

    for (int kc = 0; kc < I; kc += 64) {
        __syncthreads();
        for (int e = t; e < 1024; e += 256) {
            int r = e >> 4, q = e & 15;
            const float* g = in + ((size_t)(bs0 + r) * 12 + d) * I + kc + q * 4;
            float4 v = *(const float4*)g;
            float* s = &sIn[r * 66 + q * 4];
            s[0] = v.x; s[1] = v.y; s[2] = v.z; s[3] = v.w;
        }
        for (int e = t; e < 1024; e += 256) {
            int c = e >> 4, q = e & 15;
            const float* g = wbase + (size_t)c * I + kc + q * 4;
            float4 v = *(const float4*)g;
            float* s = &sW[c * 66 + q * 4];
            s[0] = v.x; s[1] = v.y; s[2] = v.z; s[3] = v.w;
        }
        __syncthreads();
#pragma unroll
        for (int k = 0; k < 64; k += 2) {
            float2 a[4], b[4];
#pragma unroll
            for (int i = 0; i < 4; ++i) a[i] = *(const float2*)&sIn[(tr + 16 * i) * 66 + k];
#pragma unroll
            for (int j = 0; j < 4; ++j) b[j] = *(const float2*)&sW[(tc + 16 * j) * 66 + k];
#pragma unroll
            for (int i = 0; i < 4; ++i)
#pragma unroll
                for (int j = 0; j < 4; ++j)
                    acc[i][j] += a[i].x * b[j].x + a[i].y * b[j].y;
        }
    }

#pragma unroll
    for (int i = 0; i < 4; ++i) {
        int bs = bs0 + tr + 16 * i;
        size_t row = (size_t)bs * 12 + d;
        if (PERM == 1) {
            unsigned short* oh = (unsigned short*)outv;
            int b = bs >> 9, s = bs & 511;
#pragma unroll
            for (int j = 0; j < 4; ++j) {
                int o = c0 + tc + 16 * j;
                int hh = o >> 3, mk = o & 7;
                oh[(((size_t)(b * 8 + hh) * 512 + s) * 96) + d * 8 + mk] = f2bf(acc[i][j]);
            }
        } else if (PERM == 2) {
            unsigned short* oh = (unsigned short*)outv;
            int b = bs >> 9, s = bs & 511;
#pragma unroll
            for (int j = 0; j < 4; ++j) {
                int o = c0 + tc + 16 * j;
                int hh = o >> 3, mk = o & 7;
                oh[(((size_t)(b * 8 + hh) * 96 + d * 8 + mk) * 512) + s] = f2bf(acc[i][j]);
            }
        } else if (RES) {
            float* ob = (float*)outv + row * O + c0;
            const float* rb = res + row * O + c0;
#pragma unroll
            for (int j = 0; j < 4; ++j) ob[tc + 16 * j] = acc[i][j] + rb[tc + 16 * j];
        } else {
            float* ob = (float*)outv + row * O + c0;
#pragma unroll
            for (int j = 0; j < 4; ++j) ob[tc + 16 * j] = acc[i][j];
        }
    }
}

// ---------------- attention v3: bf16 MFMA flash --------------------------
// grid: bh*8 + qtile, 256 threads (4 waves). 64 q-rows/block, 16/wave.
// qh/kh: bf16 [bh][512][96]; vt: bf16 [bh][96][512]. out: fp32 [bs][12][64].
__global__ __launch_bounds__(256) void k_attn3(const unsigned short* __restrict__ qh,
                                               const unsigned short* __restrict__ kh,
                                               const unsigned short* __restrict__ vt,
                                               float* __restrict__ out) {
    __shared__ unsigned short sK[64 * 104];     // 13312 B
    __shared__ unsigned short sV[96 * 72];      // 13824 B
    __shared__ unsigned short ps[4][16 * 72];   //  9216 B (per-wave P slab)
    const int bh = blockIdx.x >> 3;
    const int q0 = (blockIdx.x & 7) * 64;
    const int t = threadIdx.x;
    const int w = t >> 6;
    const int l = t & 63;
    const int lr = l & 15;
    const int lk = l >> 4;

    // Q fragments for this wave's 16 rows (3 k-steps of 32)
    const unsigned short* qg = qh + ((size_t)bh * 512 + q0 + w * 16) * 96;
    bf16x8 qa[3];
#pragma unroll
    for (int ks = 0; ks < 3; ++ks)
        qa[ks] = *(const bf16x8*)(qg + (size_t)lr * 96 + ks * 32 + lk * 8);

    float m[4], lsum[4];
    f32x4 o[6];
#pragma unroll
    for (int r = 0; r < 4; ++r) { m[r] = -3.4e38f; lsum[r] = 0.f; }
#pragma unroll
    for (int f = 0; f < 6; ++f) o[f] = (f32x4){0.f, 0.f, 0.f, 0.f};

    const unsigned short* kg = kh + (size_t)bh * 512 * 96;
    const unsigned short* vg = vt + (size_t)bh * 96 * 512;
    const float scale = 0.10206207261596577f;   // 1/sqrt(96)

    for (int tile = 0; tile < 8; ++tile) {
        __syncthreads();
        for (int e = t; e < 768; e += 256) {
            int row = e / 12, seg = e % 12;
            *(bf16x8*)&sK[row * 104 + seg * 8] =
                *(const bf16x8*)(kg + ((size_t)(tile * 64 + row)) * 96 + seg * 8);
        }
        for (int e = t; e < 768; e += 256) {
            int row = e / 8, seg = e % 8;
            *(bf16x8*)&sV[row * 72 + seg * 8] =
                *(const bf16x8*)(vg + (size_t)row * 512 + tile * 64 + seg * 8);
        }
        __syncthreads();

        // ---- S = Q K^T (16 x 64 per wave) ----
        f32x4 s[4];
#pragma unroll
        for (int f = 0; f < 4; ++f) {
            f32x4 acc = {0.f, 0.f, 0.f, 0.f};
#pragma unroll
            for (int ks = 0; ks < 3; ++ks) {
                bf16x8 kb = *(const bf16x8*)&sK[(f * 16 + lr) * 104 + ks * 32 + lk * 8];
                acc = __builtin_amdgcn_mfma_f32_16x16x32_bf16(qa[ks], kb, acc, 0, 0, 0);
            }
            s[f] = acc;
        }

        // ---- online softmax ----
        float sc[4];
#pragma unroll
        for (int r = 0; r < 4; ++r) {
            float mx = fmaxf(fmaxf(s[0][r], s[1][r]), fmaxf(s[2][r], s[3][r]));
#pragma unroll
            for (int d = 1; d < 16; d <<= 1) mx = fmaxf(mx, __shfl_xor(mx, d));
            float nm = fmaxf(m[r], mx);
            sc[r] = __expf((m[r] - nm) * scale);
            m[r] = nm;
        }
        float ts[4] = {0.f, 0.f, 0.f, 0.f};
#pragma unroll
        for (int f = 0; f < 4; ++f) {
#pragma unroll
            for (int r = 0; r < 4; ++r) {
                float p = __expf((s[f][r] - m[r]) * scale);
                ts[r] += p;
                ps[w][(lk * 4 + r) * 72 + f * 16 + lr] = f2bf(p);
            }
        }
#pragma unroll
        for (int r = 0; r < 4; ++r) {
            float s2 = ts[r];
#pragma unroll
            for (int d = 1; d < 16; d <<= 1) s2 += __shfl_xor(s2, d);
            lsum[r] = lsum[r] * sc[r] + s2;
        }
#pragma unroll
        for (int f = 0; f < 6; ++f)
#pragma unroll
            for (int r = 0; r < 4; ++r) o[f][r] *= sc[r];

        // ---- O += P V ----
        bf16x8 pa[2];
#pragma unroll
        for (int ks = 0; ks < 2; ++ks)
            pa[ks] = *(const bf16x8*)&ps[w][lr * 72 + ks * 32 + lk * 8];
#pragma unroll
        for (int f = 0; f < 6; ++f) {
            f32x4 acc = o[f];
#pragma unroll
            for (int ks = 0; ks < 2; ++ks) {
                bf16x8 vb = *(const bf16x8*)&sV[(f * 16 + lr) * 72 + ks * 32 + lk * 8];
                acc = __builtin_amdgcn_mfma_f32_16x16x32_bf16(pa[ks], vb, acc, 0, 0, 0);
            }
            o[f] = acc;
        }
    }

    // ---- epilogue: O/l -> fp32 [bs][12][64] ----
    const int b = bh >> 3, hh = bh & 7;
#pragma unroll
    for (int r = 0; r < 4; ++r) {
        int s = q0 + w * 16 + lk * 4 + r;
        float inv = 1.0f / lsum[r];
        float* ob = out + ((size_t)(b * 512 + s) * 12) * 64 + hh * 8;
#pragma unroll
        for (int f = 0; f < 6; ++f) {
            int col = f * 16 + lr;
            ob[(col >> 3) * 64 + (col & 7)] = o[f][r] * inv;
        }
    }
}

// ---------------- fc_out ----------------
__global__ void k_fcout(const float* __restrict__ h, const float* __restrict__ w,
                        const float* __restrict__ qf, float* __restrict__ z) {
    int bs = blockIdx.x;
    __shared__ float td[12];
    int t = threadIdx.x;
    if (t < 12) {
        const float* row = h + ((size_t)bs * 12 + t) * 64;
        const float* wr  = w + d_REP[t] * 64;
        float a = 0.f;
        for (int i = 0; i < 64; ++i) a += row[i] * wr[i];
        td[t] = a;
    }
    __syncthreads();
    if (t < 12) {
        float a = 0.f;
        for (int d = 0; d < 12; ++d) a += qf[d * 12 + t] * td[d];
        z[bs * 12 + t] = a / 7.0f;
    }
}

// ---------------- VQ ----------------
__global__ __launch_bounds__(256) void k_vq(const float* __restrict__ z,
                                            const float* __restrict__ cb,
                                            float* __restrict__ zvq,
                                            float* __restrict__ zst) {
    int bs = blockIdx.x;
    int t = threadIdx.x;
    __shared__ float zv[12];
    __shared__ float sb[256];
    __shared__ int   si[256];
    if (t < 12) zv[t] = z[bs * 12 + t];
    __syncthreads();
    float zz = 0.f;
    for (int j = 0; j < 12; ++j) zz += zv[j] * zv[j];
    float best = 3.4e38f; int bi = 0x7fffffff;
    for (int c = t; c < KCB; c += 256) {
        const float* cr = cb + c * 12;
        float cc = 0.f, dot = 0.f;
        for (int j = 0; j < 12; ++j) { cc += cr[j] * cr[j]; dot += zv[j] * cr[j]; }
        float dist = zz + cc - 2.0f * dot;
        if (dist < best) { best = dist; bi = c; }
    }
    sb[t] = best; si[t] = bi; __syncthreads();
    for (int st = 128; st > 0; st >>= 1) {
        if (t < st) {
            if (sb[t + st] < sb[t] || (sb[t + st] == sb[t] && si[t + st] < si[t])) {
                sb[t] = sb[t + st]; si[t] = si[t + st];
            }
        }
        __syncthreads();
    }
    if (t < 12) {
        float c = cb[si[0] * 12 + t];
        zvq[bs * 12 + t] = c;
        float zi = zv[t];
        zst[bs * 12 + t] = (c - zi) + zi;
    }
}

// ---------------- positional encoding add ------------------------------
__global__ __launch_bounds__(256) void k_posenc(float* __restrict__ h,
                                                const float* __restrict__ qf) {
    int idx = blockIdx.x * 256 + threadIdx.x;
    if (idx >= ROWS * 64) return;
    int m = idx & 63;
    int r = idx >> 6;
    int d = r % 12;
    int bs = r / 12;
    int s = bs % SS;
    int i = m >> 1;
    float dv = expf((float)(2 * i) * (-0.14391156831212787f));
    float arg = (float)s * dv;
    float pe = (m & 1) ? cosf(arg) : sinf(arg);
    h[idx] += qf[144 + d] * pe;
}

// ---------------- losses ----------------
__global__ __launch_bounds__(256) void k_recon(const float* __restrict__ x,
                                               const float* __restrict__ logits,
                                               float* __restrict__ xr_out,
                                               float* __restrict__ partial) {
    __shared__ float red[256];
    int t = threadIdx.x;
    float acc = 0.f;
    for (int i = blockIdx.x * 256 + t; i < NEL; i += gridDim.x * 256) {
        float lg = logits[i];
        float xr = 1.0f / (1.0f + expf(-lg));
        xr_out[i] = xr;
        float xi = x[i];
        float l1 = fmaxf(logf(xr), -100.0f);
        float l2 = fmaxf(logf(1.0f - xr), -100.0f);
        acc += xi * l1 + (1.0f - xi) * l2;
    }
    red[t] = acc; __syncthreads();
    for (int st = 128; st > 0; st >>= 1) { if (t < st) red[t] += red[t + st]; __syncthreads(); }
    if (t == 0) partial[blockIdx.x] = red[0];
}

__global__ __launch_bounds__(256) void k_embloss(const float* __restrict__ z,
                                                 const float* __restrict__ zvq,
                                                 float* __restrict__ partial) {
    __shared__ float red[256];
    int t = threadIdx.x;
    float acc = 0.f;
    for (int i = blockIdx.x * 256 + t; i < NEL; i += gridDim.x * 256) {
        float d = zvq[i] - z[i];
        acc += d * d;
    }
    red[t] = acc; __syncthreads();
    for (int st = 128; st > 0; st >>= 1) { if (t < st) red[t] += red[t + st]; __syncthreads(); }
    if (t == 0) partial[blockIdx.x] = red[0];
}

__global__ void k_final(const float* __restrict__ p1, const float* __restrict__ p2,
                        float* __restrict__ out) {
    if (threadIdx.x == 0) {
        float s1 = 0.f, s2 = 0.f;
        for (int i = 0; i < 96; ++i) { s1 += p1[i]; s2 += p2[i]; }
        out[NEL]     = -s1 / (float)NEL;
        out[NEL + 1] =  s2 / (float)NEL;
        out[NEL + 2] =  s2 / (float)NEL;
    }
}

// ------------------------------------------------------------------------
extern "C" void kernel_launch(void* const* d_in, const int* in_sizes, int n_in,
                              void* d_out, int out_size, void* d_ws, size_t ws_size,
                              hipStream_t stream) {
    const float* x   = (const float*)d_in[0];
    const float* efb = (const float*)d_in[1];
    const float* efw = (const float*)d_in[2];
    const float* ew1 = (const float*)d_in[3];
    const float* ew2 = (const float*)d_in[4];
    const float* ew3 = (const float*)d_in[5];
    const float* ewq = (const float*)d_in[6];
    const float* ewk = (const float*)d_in[7];
    const float* ewv = (const float*)d_in[8];
    const float* ewo = (const float*)d_in[9];
    const float* ef1 = (const float*)d_in[10];
    const float* ef2 = (const float*)d_in[11];
    const float* eow = (const float*)d_in[12];
    const float* cb  = (const float*)d_in[13];
    const float* dfb = (const float*)d_in[14];
    const float* dfw = (const float*)d_in[15];
    const float* dw1 = (const float*)d_in[16];
    const float* dw2 = (const float*)d_in[17];
    const float* dw3 = (const float*)d_in[18];
    const float* dwq = (const float*)d_in[19];
    const float* dwk = (const float*)d_in[20];
    const float* dwv = (const float*)d_in[21];
    const float* dwo = (const float*)d_in[22];
    const float* df1 = (const float*)d_in[23];
    const float* df2 = (const float*)d_in[24];
    const float* dow = (const float*)d_in[25];
    float* out = (float*)d_out;

    float* ws = (float*)d_ws;
    float* qf   = ws;                       // 256
    float* h    = ws + 256;                 // 3,145,728
    float* big  = h + 3145728;              // 4 x 3,145,728
    unsigned short* q  = (unsigned short*)big;
    unsigned short* kk = (unsigned short*)(big + 3145728);
    unsigned short* vv = (unsigned short*)(big + 2 * (size_t)3145728);
    float* t1   = big + 3 * (size_t)3145728;
    float* fmid = big;                      // aliases q/kk/vv (dead then)
    float* z    = big + 4 * (size_t)3145728;
    float* zvq  = z + NEL;
    float* zst  = zvq + NEL;
    float* z2   = zst + NEL;
    float* p1   = z2 + NEL;
    float* p2   = p1 + 128;

    auto run_half = [&](const float* xin, const float* fb, const float* fw,
                        const float* w1, const float* w2, const float* w3,
                        const float* wq, const float* wk, const float* wv,
                        const float* wo, const float* f1, const float* f2,
                        const float* owt, float* zout) {
        k_embed<<<BSN, 256, 0, stream>>>(xin, fb, fw, w1, qf, h);
        k_act<<<(BSN * 64 + 255) / 256, 256, 0, stream>>>(h, qf, 64);
        k_lin3<64, 64, 0, 0><<<dim3(12, 64, 1), 256, 0, stream>>>(h, w2, nullptr, t1);
        k_act<<<(BSN * 64 + 255) / 256, 256, 0, stream>>>(t1, qf, 64);
        k_lin3<64, 64, 0, 0><<<dim3(12, 64, 1), 256, 0, stream>>>(t1, w3, nullptr, h);
        k_posenc<<<(ROWS * 64 + 255) / 256, 256, 0, stream>>>(h, qf);
        for (int l = 0; l < LLAY; ++l) {
            size_t off  = (size_t)l * 7 * 64 * 64;
            size_t offf = (size_t)l * 7 * 256 * 64;
            k_lin3<64, 64, 1, 0><<<dim3(12, 64, 1), 256, 0, stream>>>(h, wq + off, nullptr, q);
            k_lin3<64, 64, 1, 0><<<dim3(12, 64, 1), 256, 0, stream>>>(h, wk + off, nullptr, kk);
            k_lin3<64, 64, 2, 0><<<dim3(12, 64, 1), 256, 0, stream>>>(h, wv + off, nullptr, vv);
            k_attn3<<<BB * HHEAD * 8, 256, 0, stream>>>(q, kk, vv, t1);
            k_lin3<64, 64, 0, 1><<<dim3(12, 64, 1), 256, 0, stream>>>(t1, wo + off, h, h);
            k_lin3<256, 64, 0, 0><<<dim3(12, 64, 4), 256, 0, stream>>>(h, f1 + offf, nullptr, fmid);
            k_act<<<(BSN * 256 + 255) / 256, 256, 0, stream>>>(fmid, qf, 256);
            k_lin3<64, 256, 0, 1><<<dim3(12, 64, 1), 256, 0, stream>>>(fmid, f2 + offf, h, h);
        }
        k_fcout<<<BSN, 64, 0, stream>>>(h, owt, qf, zout);
    };

    k_init_qf<<<1, 256, 0, stream>>>(qf);
    run_half(x, efb, efw, ew1, ew2, ew3, ewq, ewk, ewv, ewo, ef1, ef2, eow, z);
    k_vq<<<BSN, 256, 0, stream>>>(z, cb, zvq, zst);
    run_half(zst, dfb, dfw, dw1, dw2, dw3, dwq, dwk, dwv, dwo, df1, df2, dow, z2);
    k_recon<<<96, 256, 0, stream>>>(x, z2, out, p1);
    k_embloss<<<96, 256, 0, stream>>>(z, zvq, p2);
    k_final<<<1, 64, 0, stream>>>(p1, p2, out);
}

// Round 5
// 1870.643 us; speedup vs baseline: 13.6181x; 1.2963x over previous
//
#include <hip/hip_runtime.h>
#include <math.h>

#define BB 8
#define SS 512
#define HHEAD 8
#define LLAY 4
#define KCB 1024
#define BSN 4096          // B*S
#define ROWS 49152        // BS*12
#define NEL 49152         // B*S*12

__constant__ int d_REP[12] = {0,1,2,2,3,3,4,4,5,5,6,6};

typedef __attribute__((ext_vector_type(8))) short bf16x8;
typedef __attribute__((ext_vector_type(4))) float f32x4;

__device__ inline unsigned short f2bf(float x) {
    unsigned u = __builtin_bit_cast(unsigned, x);
    u += 0x7FFF + ((u >> 16) & 1);
    return (unsigned short)(u >> 16);
}

// fast exact-enough gelu: erf via Abramowitz-Stegun 7.1.26 (|err| < 1.5e-7)
__device__ inline float fast_gelu(float a) {
    float x = a * 0.7071067811865475f;
    float ax = fabsf(x);
    float tt = 1.0f / (1.0f + 0.3275911f * ax);
    float poly = ((((1.061405429f * tt - 1.453152027f) * tt + 1.421413741f) * tt
                   - 0.284496736f) * tt + 0.254829592f) * tt;
    float y = 1.0f - poly * __expf(-x * x);
    float er = copysignf(y, x);
    return 0.5f * a * (1.0f + er);
}

// ---------------- QF init (144 entries) + row sums (12) ----------------
__global__ void k_init_qf(float* qf) {
    int t = threadIdx.x;
    if (t < 144) {
        int r = t / 12, j = t % 12;
        double v;
        if (r == 0)      v = 1.0 / sqrt(12.0);
        else if (r == 1) v = ((j & 1) ? -1.0 : 1.0) / sqrt(12.0);
        else {
            int m = r >> 1;
            double ang = 2.0 * 3.14159265358979323846 * (double)m * (double)j / 12.0;
            v = (((r & 1) == 0) ? cos(ang) : sin(ang)) / sqrt(6.0);
        }
        qf[t] = (float)v;
    }
    __syncthreads();
    if (t < 12) {
        float s = 0.f;
        for (int j = 0; j < 12; ++j) s += qf[t * 12 + j];
        qf[144 + t] = s;
    }
}

// ---------------- embed head entry ----------------
__global__ __launch_bounds__(256) void k_embed(const float* __restrict__ x,
                                               const float* __restrict__ fb,
                                               const float* __restrict__ fw,
                                               const float* __restrict__ w1,
                                               const float* __restrict__ qf,
                                               float* __restrict__ out) {
    int bs = blockIdx.x;
    __shared__ float xs[12], h1[12];
    int t = threadIdx.x;
    if (t < 12) xs[t] = x[bs * 12 + t] + fb[0];
    __syncthreads();
    if (t < 12) {
        float a = 0.f;
        for (int p = 0; p < 12; ++p) a += qf[t * 12 + p] * xs[p];
        h1[t] = a * fw[0];
    }
    __syncthreads();
    for (int e = t; e < 12 * 64; e += 256) {
        int d = e >> 6, o = e & 63;
        out[((size_t)bs * 12 + d) * 64 + o] = h1[d] * w1[d_REP[d] * 64 + o];
    }
}

// ---------------- act ----------------
__global__ __launch_bounds__(256) void k_act(float* __restrict__ h,
                                             const float* __restrict__ qf,
                                             int mdim) {
    const int starts[7] = {0, 1, 2, 4, 6, 8, 10};
    const int dks[7]    = {1, 1, 2, 2, 2, 2, 2};
    int idx = blockIdx.x * 256 + threadIdx.x;
    int total = BSN * mdim;
    if (idx >= total) return;
    int bs = idx / mdim, m = idx - bs * mdim;
    float* base = h + (size_t)bs * 12 * mdim + m;
    float v[12], o[12];
    for (int d = 0; d < 12; ++d) v[d] = base[d * mdim];
    for (int k = 0; k < 7; ++k) {
        int s = starts[k], dk = dks[k];
        float g[12];
        for (int pp = 0; pp < 12; ++pp) {
            float a = 0.f;
            for (int d = 0; d < dk; ++d) a += qf[(s + d) * 12 + pp] * v[s + d];
            g[pp] = fast_gelu(a);
        }
        for (int d = 0; d < dk; ++d) {
            float a = 0.f;
            for (int pp = 0; pp < 12; ++pp) a += qf[(s + d) * 12 + pp] * g[pp];
            o[s + d] = a;
        }
    }
    for (int d = 0; d < 12; ++d) base[d * mdim] = o[d];
}

// ---------------- MFMA bf16 lin v4 --------------------------------------
// grid (12, BSN/64, O/64). 256 thr = 4 waves. 64x64 out tile per block.
// A = in rows (fp32 -> bf16 in staging), B = weight rows. out fp32/bf16-perm.
// PERM: 0 fp32 [bs][12][O]; 1 bf16 head-major [bh][s][96]; 2 bf16 V^T [bh][96][s]
template <int O, int I, int PERM, int RES>
__global__ __launch_bounds__(256) void k_lin4(const float* __restrict__ in,
                                              const float* __restrict__ W,
                                              const float* __restrict__ res,
                                              void* __restrict__ outv) {
    const int d   = blockIdx.x;
    const int bs0 = blockIdx.y * 64;
    const int c0  = blockIdx.z * 64;
    __shared__ unsigned short sA[64 * 72];   // row stride 144 B
    __shared__ unsigned short sB[64 * 72];
    const int t  = threadIdx.x;
    const int w  = t >> 6;
    const int l  = t & 63;
    const int lr = l & 15;
    const int lk = l >> 4;

    f32x4 acc[4];
#pragma unroll
    for (int f = 0; f < 4; ++f) acc[f] = (f32x4){0.f, 0.f, 0.f, 0.f};

    const float* wbase = W + ((size_t)d_REP[d] * O + c0) * I;

    for (int kc = 0; kc < I; kc += 64) {
        __syncthreads();
        for (int e = t; e < 1024; e += 256) {
            int r = e >> 4, qq = e & 15;
            float4 v = *(const float4*)(in + ((size_t)(bs0 + r) * 12 + d) * I + kc + qq * 4);
            ushort4 u = {f2bf(v.x), f2bf(v.y), f2bf(v.z), f2bf(v.w)};
            *(ushort4*)&sA[r * 72 + qq * 4] = u;
        }
        for (int e = t; e < 1024; e += 256) {
            int c = e >> 4, qq = e & 15;
            float4 v = *(const float4*)(wbase + (size_t)c * I + kc + qq * 4);
            ushort4 u = {f2bf(v.x), f2bf(v.y), f2bf(v.z), f2bf(v.w)};
            *(ushort4*)&sB[c * 72 + qq * 4] = u;
        }
        __syncthreads();
#pragma unroll
        for (int ks = 0; ks < 2; ++ks) {
            bf16x8 a = *(const bf16x8*)&sA[(w * 16 + lr) * 72 + ks * 32 + lk * 8];
#pragma unroll
            for (int f = 0; f < 4; ++f) {
                bf16x8 b = *(const bf16x8*)&sB[(f * 16 + lr) * 72 + ks * 32 + lk * 8];
                acc[f] = __builtin_amdgcn_mfma_f32_16x16x32_bf16(a, b, acc[f], 0, 0, 0);
            }
        }
    }

    // D[row=(lk*4+reg)][col=f*16+lr] per wave-strip w
#pragma unroll
    for (int f = 0; f < 4; ++f) {
#pragma unroll
        for (int reg = 0; reg < 4; ++reg) {
            int bs = bs0 + w * 16 + lk * 4 + reg;
            int o  = c0 + f * 16 + lr;
            float val = acc[f][reg];
            size_t row = (size_t)bs * 12 + d;
            if (PERM == 1) {
                unsigned short* oh = (unsigned short*)outv;
                int b = bs >> 9, s = bs & 511;
                oh[(((size_t)(b * 8 + (o >> 3)) * 512 + s) * 96) + d * 8 + (o & 7)] = f2bf(val);
            } else if (PERM == 2) {
                unsigned short* oh = (unsigned short*)outv;
                int b = bs >> 9, s = bs & 511;
                oh[(((size_t)(b * 8 + (o >> 3)) * 96 + d * 8 + (o & 7)) * 512) + s] = f2bf(val);
            } else {
                if (RES) val += res[row * O + o];
                ((float*)outv)[row * O + o] = val;
            }
        }
    }
}

// ---------------- attention v3: bf16 MFMA flash --------------------------
__global__ __launch_bounds__(256) void k_attn3(const unsigned short* __restrict__ qh,
                                               const unsigned short* __restrict__ kh,
                                               const unsigned short* __restrict__ vt,
                                               float* __restrict__ out) {
    __shared__ unsigned short sK[64 * 104];
    __shared__ unsigned short sV[96 * 72];
    __shared__ unsigned short ps[4][16 * 72];
    const int bh = blockIdx.x >> 3;
    const int q0 = (blockIdx.x & 7) * 64;
    const int t = threadIdx.x;
    const int w = t >> 6;
    const int l = t & 63;
    const int lr = l & 15;
    const int lk = l >> 4;

    const unsigned short* qg = qh + ((size_t)bh * 512 + q0 + w * 16) * 96;
    bf16x8 qa[3];
#pragma unroll
    for (int ks = 0; ks < 3; ++ks)
        qa[ks] = *(const bf16x8*)(qg + (size_t)lr * 96 + ks * 32 + lk * 8);

    float m[4], lsum[4];
    f32x4 o[6];
#pragma unroll
    for (int r = 0; r < 4; ++r) { m[r] = -3.4e38f; lsum[r] = 0.f; }
#pragma unroll
    for (int f = 0; f < 6; ++f) o[f] = (f32x4){0.f, 0.f, 0.f, 0.f};

    const unsigned short* kg = kh + (size_t)bh * 512 * 96;
    const unsigned short* vg = vt + (size_t)bh * 96 * 512;
    const float scale = 0.10206207261596577f;   // 1/sqrt(96)

    for (int tile = 0; tile < 8; ++tile) {
        __syncthreads();
        for (int e = t; e < 768; e += 256) {
            int row = e / 12, seg = e % 12;
            *(bf16x8*)&sK[row * 104 + seg * 8] =
                *(const bf16x8*)(kg + ((size_t)(tile * 64 + row)) * 96 + seg * 8);
        }
        for (int e = t; e < 768; e += 256) {
            int row = e / 8, seg = e % 8;
            *(bf16x8*)&sV[row * 72 + seg * 8] =
                *(const bf16x8*)(vg + (size_t)row * 512 + tile * 64 + seg * 8);
        }
        __syncthreads();

        f32x4 s[4];
#pragma unroll
        for (int f = 0; f < 4; ++f) {
            f32x4 acc = {0.f, 0.f, 0.f, 0.f};
#pragma unroll
            for (int ks = 0; ks < 3; ++ks) {
                bf16x8 kb = *(const bf16x8*)&sK[(f * 16 + lr) * 104 + ks * 32 + lk * 8];
                acc = __builtin_amdgcn_mfma_f32_16x16x32_bf16(qa[ks], kb, acc, 0, 0, 0);
            }
            s[f] = acc;
        }

        float sc[4];
#pragma unroll
        for (int r = 0; r < 4; ++r) {
            float mx = fmaxf(fmaxf(s[0][r], s[1][r]), fmaxf(s[2][r], s[3][r]));
#pragma unroll
            for (int d = 1; d < 16; d <<= 1) mx = fmaxf(mx, __shfl_xor(mx, d));
            float nm = fmaxf(m[r], mx);
            sc[r] = __expf((m[r] - nm) * scale);
            m[r] = nm;
        }
        float ts[4] = {0.f, 0.f, 0.f, 0.f};
#pragma unroll
        for (int f = 0; f < 4; ++f) {
#pragma unroll
            for (int r = 0; r < 4; ++r) {
                float p = __expf((s[f][r] - m[r]) * scale);
                ts[r] += p;
                ps[w][(lk * 4 + r) * 72 + f * 16 + lr] = f2bf(p);
            }
        }
#pragma unroll
        for (int r = 0; r < 4; ++r) {
            float s2 = ts[r];
#pragma unroll
            for (int d = 1; d < 16; d <<= 1) s2 += __shfl_xor(s2, d);
            lsum[r] = lsum[r] * sc[r] + s2;
        }
#pragma unroll
        for (int f = 0; f < 6; ++f)
#pragma unroll
            for (int r = 0; r < 4; ++r) o[f][r] *= sc[r];

        bf16x8 pa[2];
#pragma unroll
        for (int ks = 0; ks < 2; ++ks)
            pa[ks] = *(const bf16x8*)&ps[w][lr * 72 + ks * 32 + lk * 8];
#pragma unroll
        for (int f = 0; f < 6; ++f) {
            f32x4 acc = o[f];
#pragma unroll
            for (int ks = 0; ks < 2; ++ks) {
                bf16x8 vb = *(const bf16x8*)&sV[(f * 16 + lr) * 72 + ks * 32 + lk * 8];
                acc = __builtin_amdgcn_mfma_f32_16x16x32_bf16(pa[ks], vb, acc, 0, 0, 0);
            }
            o[f] = acc;
        }
    }

    const int b = bh >> 3, hh = bh & 7;
#pragma unroll
    for (int r = 0; r < 4; ++r) {
        int s = q0 + w * 16 + lk * 4 + r;
        float inv = 1.0f / lsum[r];
        float* ob = out + ((size_t)(b * 512 + s) * 12) * 64 + hh * 8;
#pragma unroll
        for (int f = 0; f < 6; ++f) {
            int col = f * 16 + lr;
            ob[(col >> 3) * 64 + (col & 7)] = o[f][r] * inv;
        }
    }
}

// ---------------- fc_out ----------------
__global__ void k_fcout(const float* __restrict__ h, const float* __restrict__ w,
                        const float* __restrict__ qf, float* __restrict__ z) {
    int bs = blockIdx.x;
    __shared__ float td[12];
    int t = threadIdx.x;
    if (t < 12) {
        const float* row = h + ((size_t)bs * 12 + t) * 64;
        const float* wr  = w + d_REP[t] * 64;
        float a = 0.f;
        for (int i = 0; i < 64; ++i) a += row[i] * wr[i];
        td[t] = a;
    }
    __syncthreads();
    if (t < 12) {
        float a = 0.f;
        for (int d = 0; d < 12; ++d) a += qf[d * 12 + t] * td[d];
        z[bs * 12 + t] = a / 7.0f;
    }
}

// ---------------- VQ ----------------
__global__ __launch_bounds__(256) void k_vq(const float* __restrict__ z,
                                            const float* __restrict__ cb,
                                            float* __restrict__ zvq,
                                            float* __restrict__ zst) {
    int bs = blockIdx.x;
    int t = threadIdx.x;
    __shared__ float zv[12];
    __shared__ float sb[256];
    __shared__ int   si[256];
    if (t < 12) zv[t] = z[bs * 12 + t];
    __syncthreads();
    float zz = 0.f;
    for (int j = 0; j < 12; ++j) zz += zv[j] * zv[j];
    float best = 3.4e38f; int bi = 0x7fffffff;
    for (int c = t; c < KCB; c += 256) {
        const float* cr = cb + c * 12;
        float cc = 0.f, dot = 0.f;
        for (int j = 0; j < 12; ++j) { cc += cr[j] * cr[j]; dot += zv[j] * cr[j]; }
        float dist = zz + cc - 2.0f * dot;
        if (dist < best) { best = dist; bi = c; }
    }
    sb[t] = best; si[t] = bi; __syncthreads();
    for (int st = 128; st > 0; st >>= 1) {
        if (t < st) {
            if (sb[t + st] < sb[t] || (sb[t + st] == sb[t] && si[t + st] < si[t])) {
                sb[t] = sb[t + st]; si[t] = si[t + st];
            }
        }
        __syncthreads();
    }
    if (t < 12) {
        float c = cb[si[0] * 12 + t];
        zvq[bs * 12 + t] = c;
        float zi = zv[t];
        zst[bs * 12 + t] = (c - zi) + zi;
    }
}

// ---------------- positional encoding add ------------------------------
__global__ __launch_bounds__(256) void k_posenc(float* __restrict__ h,
                                                const float* __restrict__ qf) {
    int idx = blockIdx.x * 256 + threadIdx.x;
    if (idx >= ROWS * 64) return;
    int m = idx & 63;
    int r = idx >> 6;
    int d = r % 12;
    int bs = r / 12;
    int s = bs % SS;
    int i = m >> 1;
    float dv = expf((float)(2 * i) * (-0.14391156831212787f));
    float arg = (float)s * dv;
    float pe = (m & 1) ? cosf(arg) : sinf(arg);
    h[idx] += qf[144 + d] * pe;
}

// ---------------- losses ----------------
__global__ __launch_bounds__(256) void k_recon(const float* __restrict__ x,
                                               const float* __restrict__ logits,
                                               float* __restrict__ xr_out,
                                               float* __restrict__ partial) {
    __shared__ float red[256];
    int t = threadIdx.x;
    float acc = 0.f;
    for (int i = blockIdx.x * 256 + t; i < NEL; i += gridDim.x * 256) {
        float lg = logits[i];
        float xr = 1.0f / (1.0f + expf(-lg));
        xr_out[i] = xr;
        float xi = x[i];
        float l1 = fmaxf(logf(xr), -100.0f);
        float l2 = fmaxf(logf(1.0f - xr), -100.0f);
        acc += xi * l1 + (1.0f - xi) * l2;
    }
    red[t] = acc; __syncthreads();
    for (int st = 128; st > 0; st >>= 1) { if (t < st) red[t] += red[t + st]; __syncthreads(); }
    if (t == 0) partial[blockIdx.x] = red[0];
}

__global__ __launch_bounds__(256) void k_embloss(const float* __restrict__ z,
                                                 const float* __restrict__ zvq,
                                                 float* __restrict__ partial) {
    __shared__ float red[256];
    int t = threadIdx.x;
    float acc = 0.f;
    for (int i = blockIdx.x * 256 + t; i < NEL; i += gridDim.x * 256) {
        float d = zvq[i] - z[i];
        acc += d * d;
    }
    red[t] = acc; __syncthreads();
    for (int st = 128; st > 0; st >>= 1) { if (t < st) red[t] += red[t + st]; __syncthreads(); }
    if (t == 0) partial[blockIdx.x] = red[0];
}

__global__ void k_final(const float* __restrict__ p1, const float* __restrict__ p2,
                        float* __restrict__ out) {
    if (threadIdx.x == 0) {
        float s1 = 0.f, s2 = 0.f;
        for (int i = 0; i < 96; ++i) { s1 += p1[i]; s2 += p2[i]; }
        out[NEL]     = -s1 / (float)NEL;
        out[NEL + 1] =  s2 / (float)NEL;
        out[NEL + 2] =  s2 / (float)NEL;
    }
}

// ------------------------------------------------------------------------
extern "C" void kernel_launch(void* const* d_in, const int* in_sizes, int n_in,
                              void* d_out, int out_size, void* d_ws, size_t ws_size,
                              hipStream_t stream) {
    const float* x   = (const float*)d_in[0];
    const float* efb = (const float*)d_in[1];
    const float* efw = (const float*)d_in[2];
    const float* ew1 = (const float*)d_in[3];
    const float* ew2 = (const float*)d_in[4];
    const float* ew3 = (const float*)d_in[5];
    const float* ewq = (const float*)d_in[6];
    const float* ewk = (const float*)d_in[7];
    const float* ewv = (const float*)d_in[8];
    const float* ewo = (const float*)d_in[9];
    const float* ef1 = (const float*)d_in[10];
    const float* ef2 = (const float*)d_in[11];
    const float* eow = (const float*)d_in[12];
    const float* cb  = (const float*)d_in[13];
    const float* dfb = (const float*)d_in[14];
    const float* dfw = (const float*)d_in[15];
    const float* dw1 = (const float*)d_in[16];
    const float* dw2 = (const float*)d_in[17];
    const float* dw3 = (const float*)d_in[18];
    const float* dwq = (const float*)d_in[19];
    const float* dwk = (const float*)d_in[20];
    const float* dwv = (const float*)d_in[21];
    const float* dwo = (const float*)d_in[22];
    const float* df1 = (const float*)d_in[23];
    const float* df2 = (const float*)d_in[24];
    const float* dow = (const float*)d_in[25];
    float* out = (float*)d_out;

    float* ws = (float*)d_ws;
    float* qf   = ws;                       // 256
    float* h    = ws + 256;                 // 3,145,728
    float* big  = h + 3145728;              // 4 x 3,145,728
    unsigned short* q  = (unsigned short*)big;
    unsigned short* kk = (unsigned short*)(big + 3145728);
    unsigned short* vv = (unsigned short*)(big + 2 * (size_t)3145728);
    float* t1   = big + 3 * (size_t)3145728;
    float* fmid = big;                      // aliases q/kk/vv (dead then)
    float* z    = big + 4 * (size_t)3145728;
    float* zvq  = z + NEL;
    float* zst  = zvq + NEL;
    float* z2   = zst + NEL;
    float* p1   = z2 + NEL;
    float* p2   = p1 + 128;

    auto run_half = [&](const float* xin, const float* fb, const float* fw,
                        const float* w1, const float* w2, const float* w3,
                        const float* wq, const float* wk, const float* wv,
                        const float* wo, const float* f1, const float* f2,
                        const float* owt, float* zout) {
        k_embed<<<BSN, 256, 0, stream>>>(xin, fb, fw, w1, qf, h);
        k_act<<<(BSN * 64 + 255) / 256, 256, 0, stream>>>(h, qf, 64);
        k_lin4<64, 64, 0, 0><<<dim3(12, 64, 1), 256, 0, stream>>>(h, w2, nullptr, t1);
        k_act<<<(BSN * 64 + 255) / 256, 256, 0, stream>>>(t1, qf, 64);
        k_lin4<64, 64, 0, 0><<<dim3(12, 64, 1), 256, 0, stream>>>(t1, w3, nullptr, h);
        k_posenc<<<(ROWS * 64 + 255) / 256, 256, 0, stream>>>(h, qf);
        for (int l = 0; l < LLAY; ++l) {
            size_t off  = (size_t)l * 7 * 64 * 64;
            size_t offf = (size_t)l * 7 * 256 * 64;
            k_lin4<64, 64, 1, 0><<<dim3(12, 64, 1), 256, 0, stream>>>(h, wq + off, nullptr, q);
            k_lin4<64, 64, 1, 0><<<dim3(12, 64, 1), 256, 0, stream>>>(h, wk + off, nullptr, kk);
            k_lin4<64, 64, 2, 0><<<dim3(12, 64, 1), 256, 0, stream>>>(h, wv + off, nullptr, vv);
            k_attn3<<<BB * HHEAD * 8, 256, 0, stream>>>(q, kk, vv, t1);
            k_lin4<64, 64, 0, 1><<<dim3(12, 64, 1), 256, 0, stream>>>(t1, wo + off, h, h);
            k_lin4<256, 64, 0, 0><<<dim3(12, 64, 4), 256, 0, stream>>>(h, f1 + offf, nullptr, fmid);
            k_act<<<(BSN * 256 + 255) / 256, 256, 0, stream>>>(fmid, qf, 256);
            k_lin4<64, 256, 0, 1><<<dim3(12, 64, 1), 256, 0, stream>>>(fmid, f2 + offf, h, h);
        }
        k_fcout<<<BSN, 64, 0, stream>>>(h, owt, qf, zout);
    };

    k_init_qf<<<1, 256, 0, stream>>>(qf);
    run_half(x, efb, efw, ew1, ew2, ew3, ewq, ewk, ewv, ewo, ef1, ef2, eow, z);
    k_vq<<<BSN, 256, 0, stream>>>(z, cb, zvq, zst);
    run_half(zst, dfb, dfw, dw1, dw2, dw3, dwq, dwk, dwv, dwo, df1, df2, dow, z2);
    k_recon<<<96, 256, 0, stream>>>(x, z2, out, p1);
    k_embloss<<<96, 256, 0, stream>>>(z, zvq, p2);
    k_final<<<1, 64, 0, stream>>>(p1, p2, out);
}

// Round 6
// 1200.457 us; speedup vs baseline: 21.2208x; 1.5583x over previous
//
#include <hip/hip_runtime.h>
#include <math.h>

#define BB 8
#define SS 512
#define HHEAD 8
#define LLAY 4
#define KCB 1024
#define BSN 4096          // B*S
#define ROWS 49152        // BS*12
#define NEL 49152         // B*S*12

__constant__ int d_REP[12] = {0,1,2,2,3,3,4,4,5,5,6,6};

typedef __attribute__((ext_vector_type(8))) short bf16x8;
typedef __attribute__((ext_vector_type(4))) float f32x4;

__device__ inline unsigned short f2bf(float x) {
    unsigned u = __builtin_bit_cast(unsigned, x);
    u += 0x7FFF + ((u >> 16) & 1);
    return (unsigned short)(u >> 16);
}

// fast gelu: erf via Abramowitz-Stegun 7.1.26 (|err| < 1.5e-7), HW rcp
__device__ inline float fast_gelu(float a) {
    float x = a * 0.7071067811865475f;
    float ax = fabsf(x);
    float tt = __builtin_amdgcn_rcpf(fmaf(0.3275911f, ax, 1.0f));
    float poly = ((((1.061405429f * tt - 1.453152027f) * tt + 1.421413741f) * tt
                   - 0.284496736f) * tt + 0.254829592f) * tt;
    float y = fmaf(-poly, __expf(-x * x), 1.0f);
    return 0.5f * a * (1.0f + copysignf(y, x));
}

// act group structure: period of distinct gelu inputs per group
// P = {1,2,12,6,4,3,12}; u-offsets UOFF (sum 40); QO offsets OOFF (sum dk*P = 77)

// ---------------- QF init + rowsums + reduced act tables ----------------
// qf layout: [0:144] QF, [144:156] rowsums, [160:240] QP (40 x 2), [256:333] QO
__global__ void k_init_qf(float* qf) {
    int t = threadIdx.x;
    if (t < 144) {
        int r = t / 12, j = t % 12;
        double v;
        if (r == 0)      v = 1.0 / sqrt(12.0);
        else if (r == 1) v = ((j & 1) ? -1.0 : 1.0) / sqrt(12.0);
        else {
            int m = r >> 1;
            double ang = 2.0 * 3.14159265358979323846 * (double)m * (double)j / 12.0;
            v = (((r & 1) == 0) ? cos(ang) : sin(ang)) / sqrt(6.0);
        }
        qf[t] = (float)v;
    }
    __syncthreads();
    if (t < 12) {
        float s = 0.f;
        for (int j = 0; j < 12; ++j) s += qf[t * 12 + j];
        qf[144 + t] = s;
    }
    __syncthreads();
    if (t == 0) {
        const int S_[7]  = {0, 1, 2, 4, 6, 8, 10};
        const int DKv[7] = {1, 1, 2, 2, 2, 2, 2};
        const int P_[7]  = {1, 2, 12, 6, 4, 3, 12};
        const int UO[7]  = {0, 1, 3, 15, 21, 25, 28};
        const int OO[7]  = {0, 1, 3, 27, 39, 47, 53};
        for (int k = 0; k < 7; ++k) {
            for (int u = 0; u < P_[k]; ++u) {
                qf[160 + (UO[k] + u) * 2]     = qf[S_[k] * 12 + u];
                qf[160 + (UO[k] + u) * 2 + 1] = (DKv[k] == 2) ? qf[(S_[k] + 1) * 12 + u] : 0.f;
            }
            for (int d = 0; d < DKv[k]; ++d)
                for (int u = 0; u < P_[k]; ++u) {
                    float a = 0.f;
                    for (int pp = u; pp < 12; pp += P_[k]) a += qf[(S_[k] + d) * 12 + pp];
                    qf[256 + OO[k] + d * P_[k] + u] = a;
                }
        }
    }
}

// ---------------- pe table [512][64] ----------------
__global__ void k_init_pe(float* pe) {
    int s = blockIdx.x, m = threadIdx.x;
    int i = m >> 1;
    float dv = expf((float)(2 * i) * (-0.14391156831212787f));
    float arg = (float)s * dv;
    pe[s * 64 + m] = (m & 1) ? cosf(arg) : sinf(arg);
}

// ---------------- embed head entry ----------------
__global__ __launch_bounds__(256) void k_embed(const float* __restrict__ x,
                                               const float* __restrict__ fb,
                                               const float* __restrict__ fw,
                                               const float* __restrict__ w1,
                                               const float* __restrict__ qf,
                                               float* __restrict__ out) {
    int bs = blockIdx.x;
    __shared__ float xs[12], h1[12];
    int t = threadIdx.x;
    if (t < 12) xs[t] = x[bs * 12 + t] + fb[0];
    __syncthreads();
    if (t < 12) {
        float a = 0.f;
        for (int p = 0; p < 12; ++p) a += qf[t * 12 + p] * xs[p];
        h1[t] = a * fw[0];
    }
    __syncthreads();
    for (int e = t; e < 12 * 64; e += 256) {
        int d = e >> 6, o = e & 63;
        out[((size_t)bs * 12 + d) * 64 + o] = h1[d] * w1[d_REP[d] * 64 + o];
    }
}

// ---------------- act v2: symmetry-reduced (40 gelus) ----------------
__global__ __launch_bounds__(256) void k_act(float* __restrict__ h,
                                             const float* __restrict__ qf,
                                             int mdim) {
    constexpr int S_[7]  = {0, 1, 2, 4, 6, 8, 10};
    constexpr int DKv[7] = {1, 1, 2, 2, 2, 2, 2};
    constexpr int P_[7]  = {1, 2, 12, 6, 4, 3, 12};
    constexpr int UO[7]  = {0, 1, 3, 15, 21, 25, 28};
    constexpr int OO[7]  = {0, 1, 3, 27, 39, 47, 53};
    int idx = blockIdx.x * 256 + threadIdx.x;
    int total = BSN * mdim;
    if (idx >= total) return;
    int bs = idx / mdim, m = idx - bs * mdim;
    float* base = h + (size_t)bs * 12 * mdim + m;
    const float* QP = qf + 160;
    const float* QO = qf + 256;
    float v[12], o[12];
#pragma unroll
    for (int d = 0; d < 12; ++d) v[d] = base[d * mdim];
#pragma unroll
    for (int k = 0; k < 7; ++k) {
        float g[12];
#pragma unroll
        for (int u = 0; u < P_[k]; ++u) {
            float p = QP[(UO[k] + u) * 2] * v[S_[k]];
            if (DKv[k] == 2) p = fmaf(QP[(UO[k] + u) * 2 + 1], v[S_[k] + 1], p);
            g[u] = fast_gelu(p);
        }
#pragma unroll
        for (int d = 0; d < DKv[k]; ++d) {
            float a = 0.f;
#pragma unroll
            for (int u = 0; u < P_[k]; ++u) a = fmaf(QO[OO[k] + d * P_[k] + u], g[u], a);
            o[S_[k] + d] = a;
        }
    }
#pragma unroll
    for (int d = 0; d < 12; ++d) base[d * mdim] = o[d];
}

// ---------------- MFMA bf16 lin v4 --------------------------------------
// PERM: 0 fp32 [bs][12][O]; 1 bf16 head-major [bh][s][96]; 2 bf16 V^T [bh][96][s]
// PE: add positional encoding (PERM==0 only): val += qf[144+d]*pe[(bs&511)*64+o]
template <int O, int I, int PERM, int RES, int PE>
__global__ __launch_bounds__(256) void k_lin4(const float* __restrict__ in,
                                              const float* __restrict__ W,
                                              const float* __restrict__ res,
                                              const float* __restrict__ qfp,
                                              const float* __restrict__ pe,
                                              void* __restrict__ outv) {
    const int d   = blockIdx.x;
    const int bs0 = blockIdx.y * 64;
    const int c0  = blockIdx.z * 64;
    __shared__ unsigned short sA[64 * 72];
    __shared__ unsigned short sB[64 * 72];
    const int t  = threadIdx.x;
    const int w  = t >> 6;
    const int l  = t & 63;
    const int lr = l & 15;
    const int lk = l >> 4;

    f32x4 acc[4];
#pragma unroll
    for (int f = 0; f < 4; ++f) acc[f] = (f32x4){0.f, 0.f, 0.f, 0.f};

    const float* wbase = W + ((size_t)d_REP[d] * O + c0) * I;

    for (int kc = 0; kc < I; kc += 64) {
        __syncthreads();
        for (int e = t; e < 1024; e += 256) {
            int r = e >> 4, qq = e & 15;
            float4 v = *(const float4*)(in + ((size_t)(bs0 + r) * 12 + d) * I + kc + qq * 4);
            ushort4 u = {f2bf(v.x), f2bf(v.y), f2bf(v.z), f2bf(v.w)};
            *(ushort4*)&sA[r * 72 + qq * 4] = u;
        }
        for (int e = t; e < 1024; e += 256) {
            int c = e >> 4, qq = e & 15;
            float4 v = *(const float4*)(wbase + (size_t)c * I + kc + qq * 4);
            ushort4 u = {f2bf(v.x), f2bf(v.y), f2bf(v.z), f2bf(v.w)};
            *(ushort4*)&sB[c * 72 + qq * 4] = u;
        }
        __syncthreads();
#pragma unroll
        for (int ks = 0; ks < 2; ++ks) {
            bf16x8 a = *(const bf16x8*)&sA[(w * 16 + lr) * 72 + ks * 32 + lk * 8];
#pragma unroll
            for (int f = 0; f < 4; ++f) {
                bf16x8 b = *(const bf16x8*)&sB[(f * 16 + lr) * 72 + ks * 32 + lk * 8];
                acc[f] = __builtin_amdgcn_mfma_f32_16x16x32_bf16(a, b, acc[f], 0, 0, 0);
            }
        }
    }

#pragma unroll
    for (int f = 0; f < 4; ++f) {
#pragma unroll
        for (int reg = 0; reg < 4; ++reg) {
            int bs = bs0 + w * 16 + lk * 4 + reg;
            int o  = c0 + f * 16 + lr;
            float val = acc[f][reg];
            size_t row = (size_t)bs * 12 + d;
            if (PERM == 1) {
                unsigned short* oh = (unsigned short*)outv;
                int b = bs >> 9, s = bs & 511;
                oh[(((size_t)(b * 8 + (o >> 3)) * 512 + s) * 96) + d * 8 + (o & 7)] = f2bf(val);
            } else if (PERM == 2) {
                unsigned short* oh = (unsigned short*)outv;
                int b = bs >> 9, s = bs & 511;
                oh[(((size_t)(b * 8 + (o >> 3)) * 96 + d * 8 + (o & 7)) * 512) + s] = f2bf(val);
            } else {
                if (RES) val += res[row * O + o];
                if (PE)  val += qfp[144 + d] * pe[(bs & 511) * 64 + o];
                ((float*)outv)[row * O + o] = val;
            }
        }
    }
}

// ---------------- attention v3: bf16 MFMA flash --------------------------
__global__ __launch_bounds__(256) void k_attn3(const unsigned short* __restrict__ qh,
                                               const unsigned short* __restrict__ kh,
                                               const unsigned short* __restrict__ vt,
                                               float* __restrict__ out) {
    __shared__ unsigned short sK[64 * 104];
    __shared__ unsigned short sV[96 * 72];
    __shared__ unsigned short ps[4][16 * 72];
    const int bh = blockIdx.x >> 3;
    const int q0 = (blockIdx.x & 7) * 64;
    const int t = threadIdx.x;
    const int w = t >> 6;
    const int l = t & 63;
    const int lr = l & 15;
    const int lk = l >> 4;

    const unsigned short* qg = qh + ((size_t)bh * 512 + q0 + w * 16) * 96;
    bf16x8 qa[3];
#pragma unroll
    for (int ks = 0; ks < 3; ++ks)
        qa[ks] = *(const bf16x8*)(qg + (size_t)lr * 96 + ks * 32 + lk * 8);

    float m[4], lsum[4];
    f32x4 o[6];
#pragma unroll
    for (int r = 0; r < 4; ++r) { m[r] = -3.4e38f; lsum[r] = 0.f; }
#pragma unroll
    for (int f = 0; f < 6; ++f) o[f] = (f32x4){0.f, 0.f, 0.f, 0.f};

    const unsigned short* kg = kh + (size_t)bh * 512 * 96;
    const unsigned short* vg = vt + (size_t)bh * 96 * 512;
    const float scale = 0.10206207261596577f;   // 1/sqrt(96)

    for (int tile = 0; tile < 8; ++tile) {
        __syncthreads();
        for (int e = t; e < 768; e += 256) {
            int row = e / 12, seg = e % 12;
            *(bf16x8*)&sK[row * 104 + seg * 8] =
                *(const bf16x8*)(kg + ((size_t)(tile * 64 + row)) * 96 + seg * 8);
        }
        for (int e = t; e < 768; e += 256) {
            int row = e / 8, seg = e % 8;
            *(bf16x8*)&sV[row * 72 + seg * 8] =
                *(const bf16x8*)(vg + (size_t)row * 512 + tile * 64 + seg * 8);
        }
        __syncthreads();

        f32x4 s[4];
#pragma unroll
        for (int f = 0; f < 4; ++f) {
            f32x4 acc = {0.f, 0.f, 0.f, 0.f};
#pragma unroll
            for (int ks = 0; ks < 3; ++ks) {
                bf16x8 kb = *(const bf16x8*)&sK[(f * 16 + lr) * 104 + ks * 32 + lk * 8];
                acc = __builtin_amdgcn_mfma_f32_16x16x32_bf16(qa[ks], kb, acc, 0, 0, 0);
            }
            s[f] = acc;
        }

        float sc[4];
#pragma unroll
        for (int r = 0; r < 4; ++r) {
            float mx = fmaxf(fmaxf(s[0][r], s[1][r]), fmaxf(s[2][r], s[3][r]));
#pragma unroll
            for (int d = 1; d < 16; d <<= 1) mx = fmaxf(mx, __shfl_xor(mx, d));
            float nm = fmaxf(m[r], mx);
            sc[r] = __expf((m[r] - nm) * scale);
            m[r] = nm;
        }
        float ts[4] = {0.f, 0.f, 0.f, 0.f};
#pragma unroll
        for (int f = 0; f < 4; ++f) {
#pragma unroll
            for (int r = 0; r < 4; ++r) {
                float p = __expf((s[f][r] - m[r]) * scale);
                ts[r] += p;
                ps[w][(lk * 4 + r) * 72 + f * 16 + lr] = f2bf(p);
            }
        }
#pragma unroll
        for (int r = 0; r < 4; ++r) {
            float s2 = ts[r];
#pragma unroll
            for (int d = 1; d < 16; d <<= 1) s2 += __shfl_xor(s2, d);
            lsum[r] = lsum[r] * sc[r] + s2;
        }
#pragma unroll
        for (int f = 0; f < 6; ++f)
#pragma unroll
            for (int r = 0; r < 4; ++r) o[f][r] *= sc[r];

        bf16x8 pa[2];
#pragma unroll
        for (int ks = 0; ks < 2; ++ks)
            pa[ks] = *(const bf16x8*)&ps[w][lr * 72 + ks * 32 + lk * 8];
#pragma unroll
        for (int f = 0; f < 6; ++f) {
            f32x4 acc = o[f];
#pragma unroll
            for (int ks = 0; ks < 2; ++ks) {
                bf16x8 vb = *(const bf16x8*)&sV[(f * 16 + lr) * 72 + ks * 32 + lk * 8];
                acc = __builtin_amdgcn_mfma_f32_16x16x32_bf16(pa[ks], vb, acc, 0, 0, 0);
            }
            o[f] = acc;
        }
    }

    const int b = bh >> 3, hh = bh & 7;
#pragma unroll
    for (int r = 0; r < 4; ++r) {
        int s = q0 + w * 16 + lk * 4 + r;
        float inv = 1.0f / lsum[r];
        float* ob = out + ((size_t)(b * 512 + s) * 12) * 64 + hh * 8;
#pragma unroll
        for (int f = 0; f < 6; ++f) {
            int col = f * 16 + lr;
            ob[(col >> 3) * 64 + (col & 7)] = o[f][r] * inv;
        }
    }
}

// ---------------- fc_out ----------------
__global__ void k_fcout(const float* __restrict__ h, const float* __restrict__ w,
                        const float* __restrict__ qf, float* __restrict__ z) {
    int bs = blockIdx.x;
    __shared__ float td[12];
    int t = threadIdx.x;
    if (t < 12) {
        const float* row = h + ((size_t)bs * 12 + t) * 64;
        const float* wr  = w + d_REP[t] * 64;
        float a = 0.f;
        for (int i = 0; i < 64; ++i) a += row[i] * wr[i];
        td[t] = a;
    }
    __syncthreads();
    if (t < 12) {
        float a = 0.f;
        for (int d = 0; d < 12; ++d) a += qf[d * 12 + t] * td[d];
        z[bs * 12 + t] = a / 7.0f;
    }
}

// ---------------- VQ ----------------
__global__ __launch_bounds__(256) void k_vq(const float* __restrict__ z,
                                            const float* __restrict__ cb,
                                            float* __restrict__ zvq,
                                            float* __restrict__ zst) {
    int bs = blockIdx.x;
    int t = threadIdx.x;
    __shared__ float zv[12];
    __shared__ float sb[256];
    __shared__ int   si[256];
    if (t < 12) zv[t] = z[bs * 12 + t];
    __syncthreads();
    float zz = 0.f;
    for (int j = 0; j < 12; ++j) zz += zv[j] * zv[j];
    float best = 3.4e38f; int bi = 0x7fffffff;
    for (int c = t; c < KCB; c += 256) {
        const float* cr = cb + c * 12;
        float cc = 0.f, dot = 0.f;
        for (int j = 0; j < 12; ++j) { cc += cr[j] * cr[j]; dot += zv[j] * cr[j]; }
        float dist = zz + cc - 2.0f * dot;
        if (dist < best) { best = dist; bi = c; }
    }
    sb[t] = best; si[t] = bi; __syncthreads();
    for (int st = 128; st > 0; st >>= 1) {
        if (t < st) {
            if (sb[t + st] < sb[t] || (sb[t + st] == sb[t] && si[t + st] < si[t])) {
                sb[t] = sb[t + st]; si[t] = si[t + st];
            }
        }
        __syncthreads();
    }
    if (t < 12) {
        float c = cb[si[0] * 12 + t];
        zvq[bs * 12 + t] = c;
        float zi = zv[t];
        zst[bs * 12 + t] = (c - zi) + zi;
    }
}

// ---------------- losses ----------------
__global__ __launch_bounds__(256) void k_recon(const float* __restrict__ x,
                                               const float* __restrict__ logits,
                                               float* __restrict__ xr_out,
                                               float* __restrict__ partial) {
    __shared__ float red[256];
    int t = threadIdx.x;
    float acc = 0.f;
    for (int i = blockIdx.x * 256 + t; i < NEL; i += gridDim.x * 256) {
        float lg = logits[i];
        float xr = 1.0f / (1.0f + expf(-lg));
        xr_out[i] = xr;
        float xi = x[i];
        float l1 = fmaxf(logf(xr), -100.0f);
        float l2 = fmaxf(logf(1.0f - xr), -100.0f);
        acc += xi * l1 + (1.0f - xi) * l2;
    }
    red[t] = acc; __syncthreads();
    for (int st = 128; st > 0; st >>= 1) { if (t < st) red[t] += red[t + st]; __syncthreads(); }
    if (t == 0) partial[blockIdx.x] = red[0];
}

__global__ __launch_bounds__(256) void k_embloss(const float* __restrict__ z,
                                                 const float* __restrict__ zvq,
                                                 float* __restrict__ partial) {
    __shared__ float red[256];
    int t = threadIdx.x;
    float acc = 0.f;
    for (int i = blockIdx.x * 256 + t; i < NEL; i += gridDim.x * 256) {
        float d = zvq[i] - z[i];
        acc += d * d;
    }
    red[t] = acc; __syncthreads();
    for (int st = 128; st > 0; st >>= 1) { if (t < st) red[t] += red[t + st]; __syncthreads(); }
    if (t == 0) partial[blockIdx.x] = red[0];
}

__global__ void k_final(const float* __restrict__ p1, const float* __restrict__ p2,
                        float* __restrict__ out) {
    if (threadIdx.x == 0) {
        float s1 = 0.f, s2 = 0.f;
        for (int i = 0; i < 96; ++i) { s1 += p1[i]; s2 += p2[i]; }
        out[NEL]     = -s1 / (float)NEL;
        out[NEL + 1] =  s2 / (float)NEL;
        out[NEL + 2] =  s2 / (float)NEL;
    }
}

// ------------------------------------------------------------------------
extern "C" void kernel_launch(void* const* d_in, const int* in_sizes, int n_in,
                              void* d_out, int out_size, void* d_ws, size_t ws_size,
                              hipStream_t stream) {
    const float* x   = (const float*)d_in[0];
    const float* efb = (const float*)d_in[1];
    const float* efw = (const float*)d_in[2];
    const float* ew1 = (const float*)d_in[3];
    const float* ew2 = (const float*)d_in[4];
    const float* ew3 = (const float*)d_in[5];
    const float* ewq = (const float*)d_in[6];
    const float* ewk = (const float*)d_in[7];
    const float* ewv = (const float*)d_in[8];
    const float* ewo = (const float*)d_in[9];
    const float* ef1 = (const float*)d_in[10];
    const float* ef2 = (const float*)d_in[11];
    const float* eow = (const float*)d_in[12];
    const float* cb  = (const float*)d_in[13];
    const float* dfb = (const float*)d_in[14];
    const float* dfw = (const float*)d_in[15];
    const float* dw1 = (const float*)d_in[16];
    const float* dw2 = (const float*)d_in[17];
    const float* dw3 = (const float*)d_in[18];
    const float* dwq = (const float*)d_in[19];
    const float* dwk = (const float*)d_in[20];
    const float* dwv = (const float*)d_in[21];
    const float* dwo = (const float*)d_in[22];
    const float* df1 = (const float*)d_in[23];
    const float* df2 = (const float*)d_in[24];
    const float* dow = (const float*)d_in[25];
    float* out = (float*)d_out;

    float* ws = (float*)d_ws;
    float* qf   = ws;                       // 512 (QF + rowsums + QP + QO)
    float* h    = ws + 512;                 // 3,145,728
    float* big  = h + 3145728;              // 4 x 3,145,728
    unsigned short* q  = (unsigned short*)big;
    unsigned short* kk = (unsigned short*)(big + 3145728);
    unsigned short* vv = (unsigned short*)(big + 2 * (size_t)3145728);
    float* t1   = big + 3 * (size_t)3145728;
    float* fmid = big;                      // aliases q/kk/vv (dead then)
    float* z    = big + 4 * (size_t)3145728;
    float* zvq  = z + NEL;
    float* zst  = zvq + NEL;
    float* z2   = zst + NEL;
    float* p1   = z2 + NEL;
    float* p2   = p1 + 128;
    float* pe   = p2 + 128;                 // 32768 floats

    auto run_half = [&](const float* xin, const float* fb, const float* fw,
                        const float* w1, const float* w2, const float* w3,
                        const float* wq, const float* wk, const float* wv,
                        const float* wo, const float* f1, const float* f2,
                        const float* owt, float* zout) {
        k_embed<<<BSN, 256, 0, stream>>>(xin, fb, fw, w1, qf, h);
        k_act<<<(BSN * 64 + 255) / 256, 256, 0, stream>>>(h, qf, 64);
        k_lin4<64, 64, 0, 0, 0><<<dim3(12, 64, 1), 256, 0, stream>>>(h, w2, nullptr, qf, nullptr, t1);
        k_act<<<(BSN * 64 + 255) / 256, 256, 0, stream>>>(t1, qf, 64);
        k_lin4<64, 64, 0, 0, 1><<<dim3(12, 64, 1), 256, 0, stream>>>(t1, w3, nullptr, qf, pe, h);
        for (int l = 0; l < LLAY; ++l) {
            size_t off  = (size_t)l * 7 * 64 * 64;
            size_t offf = (size_t)l * 7 * 256 * 64;
            k_lin4<64, 64, 1, 0, 0><<<dim3(12, 64, 1), 256, 0, stream>>>(h, wq + off, nullptr, qf, nullptr, q);
            k_lin4<64, 64, 1, 0, 0><<<dim3(12, 64, 1), 256, 0, stream>>>(h, wk + off, nullptr, qf, nullptr, kk);
            k_lin4<64, 64, 2, 0, 0><<<dim3(12, 64, 1), 256, 0, stream>>>(h, wv + off, nullptr, qf, nullptr, vv);
            k_attn3<<<BB * HHEAD * 8, 256, 0, stream>>>(q, kk, vv, t1);
            k_lin4<64, 64, 0, 1, 0><<<dim3(12, 64, 1), 256, 0, stream>>>(t1, wo + off, h, qf, nullptr, h);
            k_lin4<256, 64, 0, 0, 0><<<dim3(12, 64, 4), 256, 0, stream>>>(h, f1 + offf, nullptr, qf, nullptr, fmid);
            k_act<<<(BSN * 256 + 255) / 256, 256, 0, stream>>>(fmid, qf, 256);
            k_lin4<64, 256, 0, 1, 0><<<dim3(12, 64, 1), 256, 0, stream>>>(fmid, f2 + offf, h, qf, nullptr, h);
        }
        k_fcout<<<BSN, 64, 0, stream>>>(h, owt, qf, zout);
    };

    k_init_qf<<<1, 256, 0, stream>>>(qf);
    k_init_pe<<<512, 64, 0, stream>>>(pe);
    run_half(x, efb, efw, ew1, ew2, ew3, ewq, ewk, ewv, ewo, ef1, ef2, eow, z);
    k_vq<<<BSN, 256, 0, stream>>>(z, cb, zvq, zst);
    run_half(zst, dfb, dfw, dw1, dw2, dw3, dwq, dwk, dwv, dwo, df1, df2, dow, z2);
    k_recon<<<96, 256, 0, stream>>>(x, z2, out, p1);
    k_embloss<<<96, 256, 0, stream>>>(z, zvq, p2);
    k_final<<<1, 64, 0, stream>>>(p1, p2, out);
}

// Round 7
// 1186.260 us; speedup vs baseline: 21.4748x; 1.0120x over previous
//
#include <hip/hip_runtime.h>
#include <math.h>

#define BB 8
#define SS 512
#define HHEAD 8
#define LLAY 4
#define KCB 1024
#define BSN 4096          // B*S
#define ROWS 49152        // BS*12
#define NEL 49152         // B*S*12

__constant__ int d_REP[12] = {0,1,2,2,3,3,4,4,5,5,6,6};

typedef __attribute__((ext_vector_type(8))) short bf16x8;
typedef __attribute__((ext_vector_type(4))) float f32x4;

__device__ inline unsigned short f2bf(float x) {
    unsigned u = __builtin_bit_cast(unsigned, x);
    u += 0x7FFF + ((u >> 16) & 1);
    return (unsigned short)(u >> 16);
}

// fast gelu: erf via Abramowitz-Stegun 7.1.26 (|err| < 1.5e-7), HW rcp
__device__ inline float fast_gelu(float a) {
    float x = a * 0.7071067811865475f;
    float ax = fabsf(x);
    float tt = __builtin_amdgcn_rcpf(fmaf(0.3275911f, ax, 1.0f));
    float poly = ((((1.061405429f * tt - 1.453152027f) * tt + 1.421413741f) * tt
                   - 0.284496736f) * tt + 0.254829592f) * tt;
    float y = fmaf(-poly, __expf(-x * x), 1.0f);
    return 0.5f * a * (1.0f + copysignf(y, x));
}

// symmetry-reduced act on one 12-vector (tables in qf[160..] / qf[256..])
__device__ inline void act12(const float* __restrict__ qf, const float v[12], float o[12]) {
    constexpr int S_[7]  = {0, 1, 2, 4, 6, 8, 10};
    constexpr int DKv[7] = {1, 1, 2, 2, 2, 2, 2};
    constexpr int P_[7]  = {1, 2, 12, 6, 4, 3, 12};
    constexpr int UO[7]  = {0, 1, 3, 15, 21, 25, 28};
    constexpr int OO[7]  = {0, 1, 3, 27, 39, 47, 53};
    const float* QP = qf + 160;
    const float* QO = qf + 256;
#pragma unroll
    for (int k = 0; k < 7; ++k) {
        float g[12];
#pragma unroll
        for (int u = 0; u < P_[k]; ++u) {
            float p = QP[(UO[k] + u) * 2] * v[S_[k]];
            if (DKv[k] == 2) p = fmaf(QP[(UO[k] + u) * 2 + 1], v[S_[k] + 1], p);
            g[u] = fast_gelu(p);
        }
#pragma unroll
        for (int d = 0; d < DKv[k]; ++d) {
            float a = 0.f;
#pragma unroll
            for (int u = 0; u < P_[k]; ++u) a = fmaf(QO[OO[k] + d * P_[k] + u], g[u], a);
            o[S_[k] + d] = a;
        }
    }
}

// ---------------- QF init + rowsums + reduced act tables ----------------
__global__ void k_init_qf(float* qf) {
    int t = threadIdx.x;
    if (t < 144) {
        int r = t / 12, j = t % 12;
        double v;
        if (r == 0)      v = 1.0 / sqrt(12.0);
        else if (r == 1) v = ((j & 1) ? -1.0 : 1.0) / sqrt(12.0);
        else {
            int m = r >> 1;
            double ang = 2.0 * 3.14159265358979323846 * (double)m * (double)j / 12.0;
            v = (((r & 1) == 0) ? cos(ang) : sin(ang)) / sqrt(6.0);
        }
        qf[t] = (float)v;
    }
    __syncthreads();
    if (t < 12) {
        float s = 0.f;
        for (int j = 0; j < 12; ++j) s += qf[t * 12 + j];
        qf[144 + t] = s;
    }
    __syncthreads();
    if (t == 0) {
        const int S_[7]  = {0, 1, 2, 4, 6, 8, 10};
        const int DKv[7] = {1, 1, 2, 2, 2, 2, 2};
        const int P_[7]  = {1, 2, 12, 6, 4, 3, 12};
        const int UO[7]  = {0, 1, 3, 15, 21, 25, 28};
        const int OO[7]  = {0, 1, 3, 27, 39, 47, 53};
        for (int k = 0; k < 7; ++k) {
            for (int u = 0; u < P_[k]; ++u) {
                qf[160 + (UO[k] + u) * 2]     = qf[S_[k] * 12 + u];
                qf[160 + (UO[k] + u) * 2 + 1] = (DKv[k] == 2) ? qf[(S_[k] + 1) * 12 + u] : 0.f;
            }
            for (int d = 0; d < DKv[k]; ++d)
                for (int u = 0; u < P_[k]; ++u) {
                    float a = 0.f;
                    for (int pp = u; pp < 12; pp += P_[k]) a += qf[(S_[k] + d) * 12 + pp];
                    qf[256 + OO[k] + d * P_[k] + u] = a;
                }
        }
    }
}

// ---------------- pe table [512][64] ----------------
__global__ void k_init_pe(float* pe) {
    int s = blockIdx.x, m = threadIdx.x;
    int i = m >> 1;
    float dv = expf((float)(2 * i) * (-0.14391156831212787f));
    float arg = (float)s * dv;
    pe[s * 64 + m] = (m & 1) ? cosf(arg) : sinf(arg);
}

// ---------------- fused embed + act64: 4 bs per block -------------------
__global__ __launch_bounds__(256) void k_embact(const float* __restrict__ x,
                                                const float* __restrict__ fb,
                                                const float* __restrict__ fw,
                                                const float* __restrict__ w1,
                                                const float* __restrict__ qf,
                                                float* __restrict__ out) {
    int bs0 = blockIdx.x * 4;
    int t = threadIdx.x;
    __shared__ float xs[4][12], h1[4][12];
    if (t < 48) {
        int sb = t / 12, j = t % 12;
        xs[sb][j] = x[(bs0 + sb) * 12 + j] + fb[0];
    }
    __syncthreads();
    if (t < 48) {
        int sb = t / 12, j = t % 12;
        float a = 0.f;
        for (int p = 0; p < 12; ++p) a += qf[j * 12 + p] * xs[sb][p];
        h1[sb][j] = a * fw[0];
    }
    __syncthreads();
    int sb = t >> 6, m = t & 63;
    float v[12], o[12];
#pragma unroll
    for (int d = 0; d < 12; ++d) v[d] = h1[sb][d] * w1[d_REP[d] * 64 + m];
    act12(qf, v, o);
    float* ob = out + ((size_t)(bs0 + sb) * 12) * 64 + m;
#pragma unroll
    for (int d = 0; d < 12; ++d) ob[d * 64] = o[d];
}

// ---------------- act (standalone, for t1-64 and fmid-256) --------------
__global__ __launch_bounds__(256) void k_act(float* __restrict__ h,
                                             const float* __restrict__ qf,
                                             int mdim) {
    int idx = blockIdx.x * 256 + threadIdx.x;
    int total = BSN * mdim;
    if (idx >= total) return;
    int bs = idx / mdim, m = idx - bs * mdim;
    float* base = h + (size_t)bs * 12 * mdim + m;
    float v[12], o[12];
#pragma unroll
    for (int d = 0; d < 12; ++d) v[d] = base[d * mdim];
    act12(qf, v, o);
#pragma unroll
    for (int d = 0; d < 12; ++d) base[d * mdim] = o[d];
}

// ---------------- MFMA bf16 lin v4 (w2 / w3+pe / f2) --------------------
template <int O, int I, int RES, int PE>
__global__ __launch_bounds__(256) void k_lin4(const float* __restrict__ in,
                                              const float* __restrict__ W,
                                              const float* __restrict__ res,
                                              const float* __restrict__ qfp,
                                              const float* __restrict__ pe,
                                              float* __restrict__ outv) {
    const int d   = blockIdx.x;
    const int bs0 = blockIdx.y * 64;
    const int c0  = blockIdx.z * 64;
    __shared__ unsigned short sA[64 * 72];
    __shared__ unsigned short sB[64 * 72];
    const int t  = threadIdx.x;
    const int w  = t >> 6;
    const int l  = t & 63;
    const int lr = l & 15;
    const int lk = l >> 4;

    f32x4 acc[4];
#pragma unroll
    for (int f = 0; f < 4; ++f) acc[f] = (f32x4){0.f, 0.f, 0.f, 0.f};

    const float* wbase = W + ((size_t)d_REP[d] * O + c0) * I;

    for (int kc = 0; kc < I; kc += 64) {
        __syncthreads();
        for (int e = t; e < 1024; e += 256) {
            int r = e >> 4, qq = e & 15;
            float4 v = *(const float4*)(in + ((size_t)(bs0 + r) * 12 + d) * I + kc + qq * 4);
            ushort4 u = {f2bf(v.x), f2bf(v.y), f2bf(v.z), f2bf(v.w)};
            *(ushort4*)&sA[r * 72 + qq * 4] = u;
        }
        for (int e = t; e < 1024; e += 256) {
            int c = e >> 4, qq = e & 15;
            float4 v = *(const float4*)(wbase + (size_t)c * I + kc + qq * 4);
            ushort4 u = {f2bf(v.x), f2bf(v.y), f2bf(v.z), f2bf(v.w)};
            *(ushort4*)&sB[c * 72 + qq * 4] = u;
        }
        __syncthreads();
#pragma unroll
        for (int ks = 0; ks < 2; ++ks) {
            bf16x8 a = *(const bf16x8*)&sA[(w * 16 + lr) * 72 + ks * 32 + lk * 8];
#pragma unroll
            for (int f = 0; f < 4; ++f) {
                bf16x8 b = *(const bf16x8*)&sB[(f * 16 + lr) * 72 + ks * 32 + lk * 8];
                acc[f] = __builtin_amdgcn_mfma_f32_16x16x32_bf16(a, b, acc[f], 0, 0, 0);
            }
        }
    }

#pragma unroll
    for (int f = 0; f < 4; ++f) {
#pragma unroll
        for (int reg = 0; reg < 4; ++reg) {
            int bs = bs0 + w * 16 + lk * 4 + reg;
            int o  = c0 + f * 16 + lr;
            float val = acc[f][reg];
            size_t row = (size_t)bs * 12 + d;
            if (RES) val += res[row * O + o];
            if (PE)  val += qfp[144 + d] * pe[(bs & 511) * 64 + o];
            outv[row * O + o] = val;
        }
    }
}

// ---------------- fused QKV projection ----------------------------------
// grid (12, 64). A staged once; 3 sequential GEMMs. q,k: head-major bf16;
// v: transposed bf16 [bh][96][512].
__global__ __launch_bounds__(256) void k_linqkv(const float* __restrict__ in,
                                                const float* __restrict__ wq,
                                                const float* __restrict__ wk,
                                                const float* __restrict__ wv,
                                                unsigned short* __restrict__ oq,
                                                unsigned short* __restrict__ ok,
                                                unsigned short* __restrict__ ov) {
    const int d   = blockIdx.x;
    const int bs0 = blockIdx.y * 64;
    __shared__ unsigned short sA[64 * 72];
    __shared__ unsigned short sB[64 * 72];
    const int t  = threadIdx.x;
    const int w  = t >> 6;
    const int l  = t & 63;
    const int lr = l & 15;
    const int lk = l >> 4;
    const int rep = d_REP[d];

    for (int e = t; e < 1024; e += 256) {
        int r = e >> 4, qq = e & 15;
        float4 v = *(const float4*)(in + ((size_t)(bs0 + r) * 12 + d) * 64 + qq * 4);
        ushort4 u = {f2bf(v.x), f2bf(v.y), f2bf(v.z), f2bf(v.w)};
        *(ushort4*)&sA[r * 72 + qq * 4] = u;
    }

    for (int part = 0; part < 3; ++part) {
        const float* wsel = (part == 0) ? wq : (part == 1) ? wk : wv;
        const float* wbase = wsel + (size_t)rep * 64 * 64;
        __syncthreads();
        for (int e = t; e < 1024; e += 256) {
            int c = e >> 4, qq = e & 15;
            float4 v = *(const float4*)(wbase + (size_t)c * 64 + qq * 4);
            ushort4 u = {f2bf(v.x), f2bf(v.y), f2bf(v.z), f2bf(v.w)};
            *(ushort4*)&sB[c * 72 + qq * 4] = u;
        }
        __syncthreads();
        f32x4 acc[4];
#pragma unroll
        for (int f = 0; f < 4; ++f) acc[f] = (f32x4){0.f, 0.f, 0.f, 0.f};
#pragma unroll
        for (int ks = 0; ks < 2; ++ks) {
            bf16x8 a = *(const bf16x8*)&sA[(w * 16 + lr) * 72 + ks * 32 + lk * 8];
#pragma unroll
            for (int f = 0; f < 4; ++f) {
                bf16x8 b = *(const bf16x8*)&sB[(f * 16 + lr) * 72 + ks * 32 + lk * 8];
                acc[f] = __builtin_amdgcn_mfma_f32_16x16x32_bf16(a, b, acc[f], 0, 0, 0);
            }
        }
        unsigned short* oh = (part == 0) ? oq : (part == 1) ? ok : ov;
#pragma unroll
        for (int f = 0; f < 4; ++f) {
#pragma unroll
            for (int reg = 0; reg < 4; ++reg) {
                int bs = bs0 + w * 16 + lk * 4 + reg;
                int o  = f * 16 + lr;
                int b = bs >> 9, s = bs & 511;
                unsigned short hv = f2bf(acc[f][reg]);
                if (part < 2)
                    oh[(((size_t)(b * 8 + (o >> 3)) * 512 + s) * 96) + d * 8 + (o & 7)] = hv;
                else
                    oh[(((size_t)(b * 8 + (o >> 3)) * 96 + d * 8 + (o & 7)) * 512) + s] = hv;
            }
        }
    }
}

// ---------------- fused wo-GEMM + residual + f1-GEMM --------------------
// grid (12, 64). h' = t1*wo + h written in place to h AND kept in LDS (bf16);
// then fmid[64][256] = h' * f1w written fp32.
__global__ __launch_bounds__(256) void k_wof1(const float* __restrict__ t1,
                                              const float* __restrict__ wo,
                                              const float* __restrict__ f1w,
                                              float* __restrict__ h,
                                              float* __restrict__ fmid) {
    const int d   = blockIdx.x;
    const int bs0 = blockIdx.y * 64;
    __shared__ unsigned short sA[64 * 72];
    __shared__ unsigned short sB[64 * 72];
    __shared__ unsigned short sA2[64 * 72];
    const int t  = threadIdx.x;
    const int w  = t >> 6;
    const int l  = t & 63;
    const int lr = l & 15;
    const int lk = l >> 4;
    const int rep = d_REP[d];

    // phase 1: h' = t1 * wo + h
    for (int e = t; e < 1024; e += 256) {
        int r = e >> 4, qq = e & 15;
        float4 v = *(const float4*)(t1 + ((size_t)(bs0 + r) * 12 + d) * 64 + qq * 4);
        ushort4 u = {f2bf(v.x), f2bf(v.y), f2bf(v.z), f2bf(v.w)};
        *(ushort4*)&sA[r * 72 + qq * 4] = u;
    }
    {
        const float* wbase = wo + (size_t)rep * 64 * 64;
        for (int e = t; e < 1024; e += 256) {
            int c = e >> 4, qq = e & 15;
            float4 v = *(const float4*)(wbase + (size_t)c * 64 + qq * 4);
            ushort4 u = {f2bf(v.x), f2bf(v.y), f2bf(v.z), f2bf(v.w)};
            *(ushort4*)&sB[c * 72 + qq * 4] = u;
        }
    }
    __syncthreads();
    f32x4 acc[4];
#pragma unroll
    for (int f = 0; f < 4; ++f) acc[f] = (f32x4){0.f, 0.f, 0.f, 0.f};
#pragma unroll
    for (int ks = 0; ks < 2; ++ks) {
        bf16x8 a = *(const bf16x8*)&sA[(w * 16 + lr) * 72 + ks * 32 + lk * 8];
#pragma unroll
        for (int f = 0; f < 4; ++f) {
            bf16x8 b = *(const bf16x8*)&sB[(f * 16 + lr) * 72 + ks * 32 + lk * 8];
            acc[f] = __builtin_amdgcn_mfma_f32_16x16x32_bf16(a, b, acc[f], 0, 0, 0);
        }
    }
#pragma unroll
    for (int f = 0; f < 4; ++f) {
#pragma unroll
        for (int reg = 0; reg < 4; ++reg) {
            int rloc = w * 16 + lk * 4 + reg;
            int bs = bs0 + rloc;
            int o  = f * 16 + lr;
            size_t row = (size_t)bs * 12 + d;
            float val = acc[f][reg] + h[row * 64 + o];
            h[row * 64 + o] = val;
            sA2[rloc * 72 + o] = f2bf(val);
        }
    }

    // phase 2: fmid = h' * f1w (256 cols in 4 tiles)
    const float* f1base = f1w + (size_t)rep * 256 * 64;
    for (int ct = 0; ct < 4; ++ct) {
        __syncthreads();
        for (int e = t; e < 1024; e += 256) {
            int c = e >> 4, qq = e & 15;
            float4 v = *(const float4*)(f1base + (size_t)(ct * 64 + c) * 64 + qq * 4);
            ushort4 u = {f2bf(v.x), f2bf(v.y), f2bf(v.z), f2bf(v.w)};
            *(ushort4*)&sB[c * 72 + qq * 4] = u;
        }
        __syncthreads();
        f32x4 acc2[4];
#pragma unroll
        for (int f = 0; f < 4; ++f) acc2[f] = (f32x4){0.f, 0.f, 0.f, 0.f};
#pragma unroll
        for (int ks = 0; ks < 2; ++ks) {
            bf16x8 a = *(const bf16x8*)&sA2[(w * 16 + lr) * 72 + ks * 32 + lk * 8];
#pragma unroll
            for (int f = 0; f < 4; ++f) {
                bf16x8 b = *(const bf16x8*)&sB[(f * 16 + lr) * 72 + ks * 32 + lk * 8];
                acc2[f] = __builtin_amdgcn_mfma_f32_16x16x32_bf16(a, b, acc2[f], 0, 0, 0);
            }
        }
#pragma unroll
        for (int f = 0; f < 4; ++f) {
#pragma unroll
            for (int reg = 0; reg < 4; ++reg) {
                int bs = bs0 + w * 16 + lk * 4 + reg;
                int o  = ct * 64 + f * 16 + lr;
                fmid[((size_t)bs * 12 + d) * 256 + o] = acc2[f][reg];
            }
        }
    }
}

// ---------------- attention v4: 32 q-rows, 2 waves ----------------------
__global__ __launch_bounds__(128) void k_attn4(const unsigned short* __restrict__ qh,
                                               const unsigned short* __restrict__ kh,
                                               const unsigned short* __restrict__ vt,
                                               float* __restrict__ out) {
    __shared__ unsigned short sK[64 * 104];
    __shared__ unsigned short sV[96 * 72];
    __shared__ unsigned short ps[2][16 * 72];
    const int bh = blockIdx.x >> 4;
    const int q0 = (blockIdx.x & 15) * 32;
    const int t = threadIdx.x;
    const int w = t >> 6;
    const int l = t & 63;
    const int lr = l & 15;
    const int lk = l >> 4;

    const unsigned short* qg = qh + ((size_t)bh * 512 + q0 + w * 16) * 96;
    bf16x8 qa[3];
#pragma unroll
    for (int ks = 0; ks < 3; ++ks)
        qa[ks] = *(const bf16x8*)(qg + (size_t)lr * 96 + ks * 32 + lk * 8);

    float m[4], lsum[4];
    f32x4 o[6];
#pragma unroll
    for (int r = 0; r < 4; ++r) { m[r] = -3.4e38f; lsum[r] = 0.f; }
#pragma unroll
    for (int f = 0; f < 6; ++f) o[f] = (f32x4){0.f, 0.f, 0.f, 0.f};

    const unsigned short* kg = kh + (size_t)bh * 512 * 96;
    const unsigned short* vg = vt + (size_t)bh * 96 * 512;
    const float scale = 0.10206207261596577f;   // 1/sqrt(96)

    for (int tile = 0; tile < 8; ++tile) {
        __syncthreads();
        for (int e = t; e < 768; e += 128) {
            int row = e / 12, seg = e % 12;
            *(bf16x8*)&sK[row * 104 + seg * 8] =
                *(const bf16x8*)(kg + ((size_t)(tile * 64 + row)) * 96 + seg * 8);
        }
        for (int e = t; e < 768; e += 128) {
            int row = e / 8, seg = e % 8;
            *(bf16x8*)&sV[row * 72 + seg * 8] =
                *(const bf16x8*)(vg + (size_t)row * 512 + tile * 64 + seg * 8);
        }
        __syncthreads();

        f32x4 s[4];
#pragma unroll
        for (int f = 0; f < 4; ++f) {
            f32x4 acc = {0.f, 0.f, 0.f, 0.f};
#pragma unroll
            for (int ks = 0; ks < 3; ++ks) {
                bf16x8 kb = *(const bf16x8*)&sK[(f * 16 + lr) * 104 + ks * 32 + lk * 8];
                acc = __builtin_amdgcn_mfma_f32_16x16x32_bf16(qa[ks], kb, acc, 0, 0, 0);
            }
            s[f] = acc;
        }

        float sc[4];
#pragma unroll
        for (int r = 0; r < 4; ++r) {
            float mx = fmaxf(fmaxf(s[0][r], s[1][r]), fmaxf(s[2][r], s[3][r]));
#pragma unroll
            for (int d = 1; d < 16; d <<= 1) mx = fmaxf(mx, __shfl_xor(mx, d));
            float nm = fmaxf(m[r], mx);
            sc[r] = __expf((m[r] - nm) * scale);
            m[r] = nm;
        }
        float ts[4] = {0.f, 0.f, 0.f, 0.f};
#pragma unroll
        for (int f = 0; f < 4; ++f) {
#pragma unroll
            for (int r = 0; r < 4; ++r) {
                float p = __expf((s[f][r] - m[r]) * scale);
                ts[r] += p;
                ps[w][(lk * 4 + r) * 72 + f * 16 + lr] = f2bf(p);
            }
        }
#pragma unroll
        for (int r = 0; r < 4; ++r) {
            float s2 = ts[r];
#pragma unroll
            for (int d = 1; d < 16; d <<= 1) s2 += __shfl_xor(s2, d);
            lsum[r] = lsum[r] * sc[r] + s2;
        }
#pragma unroll
        for (int f = 0; f < 6; ++f)
#pragma unroll
            for (int r = 0; r < 4; ++r) o[f][r] *= sc[r];

        bf16x8 pa[2];
#pragma unroll
        for (int ks = 0; ks < 2; ++ks)
            pa[ks] = *(const bf16x8*)&ps[w][lr * 72 + ks * 32 + lk * 8];
#pragma unroll
        for (int f = 0; f < 6; ++f) {
            f32x4 acc = o[f];
#pragma unroll
            for (int ks = 0; ks < 2; ++ks) {
                bf16x8 vb = *(const bf16x8*)&sV[(f * 16 + lr) * 72 + ks * 32 + lk * 8];
                acc = __builtin_amdgcn_mfma_f32_16x16x32_bf16(pa[ks], vb, acc, 0, 0, 0);
            }
            o[f] = acc;
        }
    }

    const int b = bh >> 3, hh = bh & 7;
#pragma unroll
    for (int r = 0; r < 4; ++r) {
        int s = q0 + w * 16 + lk * 4 + r;
        float inv = 1.0f / lsum[r];
        float* ob = out + ((size_t)(b * 512 + s) * 12) * 64 + hh * 8;
#pragma unroll
        for (int f = 0; f < 6; ++f) {
            int col = f * 16 + lr;
            ob[(col >> 3) * 64 + (col & 7)] = o[f][r] * inv;
        }
    }
}

// ---------------- fc_out (decoder tail) ----------------
__global__ void k_fcout(const float* __restrict__ h, const float* __restrict__ w,
                        const float* __restrict__ qf, float* __restrict__ z) {
    int bs = blockIdx.x;
    __shared__ float td[12];
    int t = threadIdx.x;
    if (t < 12) {
        const float* row = h + ((size_t)bs * 12 + t) * 64;
        const float* wr  = w + d_REP[t] * 64;
        float a = 0.f;
        for (int i = 0; i < 64; ++i) a += row[i] * wr[i];
        td[t] = a;
    }
    __syncthreads();
    if (t < 12) {
        float a = 0.f;
        for (int d = 0; d < 12; ++d) a += qf[d * 12 + t] * td[d];
        z[bs * 12 + t] = a / 7.0f;
    }
}

// ---------------- fused fc_out + VQ (encoder tail) ----------------------
__global__ __launch_bounds__(256) void k_fcvq(const float* __restrict__ h,
                                              const float* __restrict__ w,
                                              const float* __restrict__ qf,
                                              const float* __restrict__ cb,
                                              float* __restrict__ z,
                                              float* __restrict__ zvq,
                                              float* __restrict__ zst) {
    int bs = blockIdx.x;
    int t = threadIdx.x;
    __shared__ float td[12];
    __shared__ float zv[12];
    __shared__ float sb[256];
    __shared__ int   si[256];
    if (t < 12) {
        const float* row = h + ((size_t)bs * 12 + t) * 64;
        const float* wr  = w + d_REP[t] * 64;
        float a = 0.f;
        for (int i = 0; i < 64; ++i) a += row[i] * wr[i];
        td[t] = a;
    }
    __syncthreads();
    if (t < 12) {
        float a = 0.f;
        for (int d = 0; d < 12; ++d) a += qf[d * 12 + t] * td[d];
        a /= 7.0f;
        zv[t] = a;
        z[bs * 12 + t] = a;
    }
    __syncthreads();
    float zz = 0.f;
    for (int j = 0; j < 12; ++j) zz += zv[j] * zv[j];
    float best = 3.4e38f; int bi = 0x7fffffff;
    for (int c = t; c < KCB; c += 256) {
        const float* cr = cb + c * 12;
        float cc = 0.f, dot = 0.f;
        for (int j = 0; j < 12; ++j) { cc += cr[j] * cr[j]; dot += zv[j] * cr[j]; }
        float dist = zz + cc - 2.0f * dot;
        if (dist < best) { best = dist; bi = c; }
    }
    sb[t] = best; si[t] = bi; __syncthreads();
    for (int st = 128; st > 0; st >>= 1) {
        if (t < st) {
            if (sb[t + st] < sb[t] || (sb[t + st] == sb[t] && si[t + st] < si[t])) {
                sb[t] = sb[t + st]; si[t] = si[t + st];
            }
        }
        __syncthreads();
    }
    if (t < 12) {
        float c = cb[si[0] * 12 + t];
        zvq[bs * 12 + t] = c;
        float zi = zv[t];
        zst[bs * 12 + t] = (c - zi) + zi;
    }
}

// ---------------- merged losses ----------------
__global__ __launch_bounds__(256) void k_loss(const float* __restrict__ x,
                                              const float* __restrict__ logits,
                                              const float* __restrict__ z,
                                              const float* __restrict__ zvq,
                                              float* __restrict__ xr_out,
                                              float* __restrict__ p1,
                                              float* __restrict__ p2) {
    __shared__ float red[256];
    int t = threadIdx.x;
    float acc1 = 0.f, acc2 = 0.f;
    for (int i = blockIdx.x * 256 + t; i < NEL; i += gridDim.x * 256) {
        float lg = logits[i];
        float xr = 1.0f / (1.0f + expf(-lg));
        xr_out[i] = xr;
        float xi = x[i];
        float l1 = fmaxf(logf(xr), -100.0f);
        float l2 = fmaxf(logf(1.0f - xr), -100.0f);
        acc1 += xi * l1 + (1.0f - xi) * l2;
        float dd = zvq[i] - z[i];
        acc2 += dd * dd;
    }
    red[t] = acc1; __syncthreads();
    for (int st = 128; st > 0; st >>= 1) { if (t < st) red[t] += red[t + st]; __syncthreads(); }
    if (t == 0) p1[blockIdx.x] = red[0];
    __syncthreads();
    red[t] = acc2; __syncthreads();
    for (int st = 128; st > 0; st >>= 1) { if (t < st) red[t] += red[t + st]; __syncthreads(); }
    if (t == 0) p2[blockIdx.x] = red[0];
}

__global__ void k_final(const float* __restrict__ p1, const float* __restrict__ p2,
                        float* __restrict__ out) {
    if (threadIdx.x == 0) {
        float s1 = 0.f, s2 = 0.f;
        for (int i = 0; i < 96; ++i) { s1 += p1[i]; s2 += p2[i]; }
        out[NEL]     = -s1 / (float)NEL;
        out[NEL + 1] =  s2 / (float)NEL;
        out[NEL + 2] =  s2 / (float)NEL;
    }
}

// ------------------------------------------------------------------------
extern "C" void kernel_launch(void* const* d_in, const int* in_sizes, int n_in,
                              void* d_out, int out_size, void* d_ws, size_t ws_size,
                              hipStream_t stream) {
    const float* x   = (const float*)d_in[0];
    const float* efb = (const float*)d_in[1];
    const float* efw = (const float*)d_in[2];
    const float* ew1 = (const float*)d_in[3];
    const float* ew2 = (const float*)d_in[4];
    const float* ew3 = (const float*)d_in[5];
    const float* ewq = (const float*)d_in[6];
    const float* ewk = (const float*)d_in[7];
    const float* ewv = (const float*)d_in[8];
    const float* ewo = (const float*)d_in[9];
    const float* ef1 = (const float*)d_in[10];
    const float* ef2 = (const float*)d_in[11];
    const float* eow = (const float*)d_in[12];
    const float* cb  = (const float*)d_in[13];
    const float* dfb = (const float*)d_in[14];
    const float* dfw = (const float*)d_in[15];
    const float* dw1 = (const float*)d_in[16];
    const float* dw2 = (const float*)d_in[17];
    const float* dw3 = (const float*)d_in[18];
    const float* dwq = (const float*)d_in[19];
    const float* dwk = (const float*)d_in[20];
    const float* dwv = (const float*)d_in[21];
    const float* dwo = (const float*)d_in[22];
    const float* df1 = (const float*)d_in[23];
    const float* df2 = (const float*)d_in[24];
    const float* dow = (const float*)d_in[25];
    float* out = (float*)d_out;

    float* ws = (float*)d_ws;
    float* qf   = ws;                           // 512
    float* h    = ws + 512;                     // 3,145,728
    float* fmid = h + 3145728;                  // 12,582,912 (also aliases q/kk/vv)
    float* t1   = fmid + 12582912;              // 3,145,728
    float* z    = t1 + 3145728;
    float* zvq  = z + NEL;
    float* zst  = zvq + NEL;
    float* z2   = zst + NEL;
    float* p1   = z2 + NEL;
    float* p2   = p1 + 128;
    float* pe   = p2 + 128;                     // 32768
    unsigned short* q  = (unsigned short*)fmid;
    unsigned short* kk = (unsigned short*)(fmid + 3145728);
    unsigned short* vv = (unsigned short*)(fmid + 2 * (size_t)3145728);

    auto run_half = [&](const float* xin, const float* fb, const float* fw,
                        const float* w1, const float* w2, const float* w3,
                        const float* wq, const float* wk, const float* wv,
                        const float* wo, const float* f1, const float* f2) {
        k_embact<<<BSN / 4, 256, 0, stream>>>(xin, fb, fw, w1, qf, h);
        k_lin4<64, 64, 0, 0><<<dim3(12, 64, 1), 256, 0, stream>>>(h, w2, nullptr, qf, nullptr, t1);
        k_act<<<(BSN * 64 + 255) / 256, 256, 0, stream>>>(t1, qf, 64);
        k_lin4<64, 64, 0, 1><<<dim3(12, 64, 1), 256, 0, stream>>>(t1, w3, nullptr, qf, pe, h);
        for (int l = 0; l < LLAY; ++l) {
            size_t off  = (size_t)l * 7 * 64 * 64;
            size_t offf = (size_t)l * 7 * 256 * 64;
            k_linqkv<<<dim3(12, 64), 256, 0, stream>>>(h, wq + off, wk + off, wv + off, q, kk, vv);
            k_attn4<<<BB * HHEAD * 16, 128, 0, stream>>>(q, kk, vv, t1);
            k_wof1<<<dim3(12, 64), 256, 0, stream>>>(t1, wo + off, f1 + offf, h, fmid);
            k_act<<<(BSN * 256 + 255) / 256, 256, 0, stream>>>(fmid, qf, 256);
            k_lin4<64, 256, 1, 0><<<dim3(12, 64, 1), 256, 0, stream>>>(fmid, f2 + offf, h, qf, nullptr, h);
        }
    };

    k_init_qf<<<1, 256, 0, stream>>>(qf);
    k_init_pe<<<512, 64, 0, stream>>>(pe);
    run_half(x, efb, efw, ew1, ew2, ew3, ewq, ewk, ewv, ewo, ef1, ef2);
    k_fcvq<<<BSN, 256, 0, stream>>>(h, eow, qf, cb, z, zvq, zst);
    run_half(zst, dfb, dfw, dw1, dw2, dw3, dwq, dwk, dwv, dwo, df1, df2);
    k_fcout<<<BSN, 64, 0, stream>>>(h, dow, qf, z2);
    k_loss<<<96, 256, 0, stream>>>(x, z2, z, zvq, out, p1, p2);
    k_final<<<1, 64, 0, stream>>>(p1, p2, out);
}

// Round 8
// 1124.161 us; speedup vs baseline: 22.6610x; 1.0552x over previous
//
#include <hip/hip_runtime.h>
#include <math.h>

#define BB 8
#define SS 512
#define HHEAD 8
#define LLAY 4
#define KCB 1024
#define BSN 4096          // B*S
#define ROWS 49152        // BS*12
#define NEL 49152         // B*S*12

__constant__ int d_REP[12] = {0,1,2,2,3,3,4,4,5,5,6,6};

typedef __attribute__((ext_vector_type(8))) short bf16x8;
typedef __attribute__((ext_vector_type(4))) float f32x4;

__device__ inline unsigned short f2bf(float x) {
    unsigned u = __builtin_bit_cast(unsigned, x);
    u += 0x7FFF + ((u >> 16) & 1);
    return (unsigned short)(u >> 16);
}

// fast gelu: erf via Abramowitz-Stegun 7.1.26 (|err| < 1.5e-7), HW rcp
__device__ inline float fast_gelu(float a) {
    float x = a * 0.7071067811865475f;
    float ax = fabsf(x);
    float tt = __builtin_amdgcn_rcpf(fmaf(0.3275911f, ax, 1.0f));
    float poly = ((((1.061405429f * tt - 1.453152027f) * tt + 1.421413741f) * tt
                   - 0.284496736f) * tt + 0.254829592f) * tt;
    float y = fmaf(-poly, __expf(-x * x), 1.0f);
    return 0.5f * a * (1.0f + copysignf(y, x));
}

// symmetry-reduced act on one 12-vector (tables in qf[160..] / qf[256..])
__device__ inline void act12(const float* __restrict__ qf, const float v[12], float o[12]) {
    constexpr int S_[7]  = {0, 1, 2, 4, 6, 8, 10};
    constexpr int DKv[7] = {1, 1, 2, 2, 2, 2, 2};
    constexpr int P_[7]  = {1, 2, 12, 6, 4, 3, 12};
    constexpr int UO[7]  = {0, 1, 3, 15, 21, 25, 28};
    constexpr int OO[7]  = {0, 1, 3, 27, 39, 47, 53};
    const float* QP = qf + 160;
    const float* QO = qf + 256;
#pragma unroll
    for (int k = 0; k < 7; ++k) {
        float g[12];
#pragma unroll
        for (int u = 0; u < P_[k]; ++u) {
            float p = QP[(UO[k] + u) * 2] * v[S_[k]];
            if (DKv[k] == 2) p = fmaf(QP[(UO[k] + u) * 2 + 1], v[S_[k] + 1], p);
            g[u] = fast_gelu(p);
        }
#pragma unroll
        for (int d = 0; d < DKv[k]; ++d) {
            float a = 0.f;
#pragma unroll
            for (int u = 0; u < P_[k]; ++u) a = fmaf(QO[OO[k] + d * P_[k] + u], g[u], a);
            o[S_[k] + d] = a;
        }
    }
}

// ---------------- QF init + rowsums + reduced act tables ----------------
__global__ void k_init_qf(float* qf) {
    int t = threadIdx.x;
    if (t < 144) {
        int r = t / 12, j = t % 12;
        double v;
        if (r == 0)      v = 1.0 / sqrt(12.0);
        else if (r == 1) v = ((j & 1) ? -1.0 : 1.0) / sqrt(12.0);
        else {
            int m = r >> 1;
            double ang = 2.0 * 3.14159265358979323846 * (double)m * (double)j / 12.0;
            v = (((r & 1) == 0) ? cos(ang) : sin(ang)) / sqrt(6.0);
        }
        qf[t] = (float)v;
    }
    __syncthreads();
    if (t < 12) {
        float s = 0.f;
        for (int j = 0; j < 12; ++j) s += qf[t * 12 + j];
        qf[144 + t] = s;
    }
    __syncthreads();
    if (t == 0) {
        const int S_[7]  = {0, 1, 2, 4, 6, 8, 10};
        const int DKv[7] = {1, 1, 2, 2, 2, 2, 2};
        const int P_[7]  = {1, 2, 12, 6, 4, 3, 12};
        const int UO[7]  = {0, 1, 3, 15, 21, 25, 28};
        const int OO[7]  = {0, 1, 3, 27, 39, 47, 53};
        for (int k = 0; k < 7; ++k) {
            for (int u = 0; u < P_[k]; ++u) {
                qf[160 + (UO[k] + u) * 2]     = qf[S_[k] * 12 + u];
                qf[160 + (UO[k] + u) * 2 + 1] = (DKv[k] == 2) ? qf[(S_[k] + 1) * 12 + u] : 0.f;
            }
            for (int d = 0; d < DKv[k]; ++d)
                for (int u = 0; u < P_[k]; ++u) {
                    float a = 0.f;
                    for (int pp = u; pp < 12; pp += P_[k]) a += qf[(S_[k] + d) * 12 + pp];
                    qf[256 + OO[k] + d * P_[k] + u] = a;
                }
        }
    }
}

// ---------------- pe table [512][64] ----------------
__global__ void k_init_pe(float* pe) {
    int s = blockIdx.x, m = threadIdx.x;
    int i = m >> 1;
    float dv = expf((float)(2 * i) * (-0.14391156831212787f));
    float arg = (float)s * dv;
    pe[s * 64 + m] = (m & 1) ? cosf(arg) : sinf(arg);
}

// ---------------- fused embed + act64: 4 bs per block -------------------
__global__ __launch_bounds__(256) void k_embact(const float* __restrict__ x,
                                                const float* __restrict__ fb,
                                                const float* __restrict__ fw,
                                                const float* __restrict__ w1,
                                                const float* __restrict__ qf,
                                                float* __restrict__ out) {
    int bs0 = blockIdx.x * 4;
    int t = threadIdx.x;
    __shared__ float xs[4][12], h1[4][12];
    if (t < 48) {
        int sb = t / 12, j = t % 12;
        xs[sb][j] = x[(bs0 + sb) * 12 + j] + fb[0];
    }
    __syncthreads();
    if (t < 48) {
        int sb = t / 12, j = t % 12;
        float a = 0.f;
        for (int p = 0; p < 12; ++p) a += qf[j * 12 + p] * xs[sb][p];
        h1[sb][j] = a * fw[0];
    }
    __syncthreads();
    int sb = t >> 6, m = t & 63;
    float v[12], o[12];
#pragma unroll
    for (int d = 0; d < 12; ++d) v[d] = h1[sb][d] * w1[d_REP[d] * 64 + m];
    act12(qf, v, o);
    float* ob = out + ((size_t)(bs0 + sb) * 12) * 64 + m;
#pragma unroll
    for (int d = 0; d < 12; ++d) ob[d * 64] = o[d];
}

// ---------------- act standalone (t1, mdim=64) --------------------------
__global__ __launch_bounds__(256) void k_act(float* __restrict__ h,
                                             const float* __restrict__ qf) {
    int idx = blockIdx.x * 256 + threadIdx.x;
    if (idx >= BSN * 64) return;
    int bs = idx >> 6, m = idx & 63;
    float* base = h + (size_t)bs * 12 * 64 + m;
    float v[12], o[12];
#pragma unroll
    for (int d = 0; d < 12; ++d) v[d] = base[d * 64];
    act12(qf, v, o);
#pragma unroll
    for (int d = 0; d < 12; ++d) base[d * 64] = o[d];
}

// ---------------- MFMA bf16 lin (64x64, fp32 in/out) --------------------
template <int RES, int PE>
__global__ __launch_bounds__(256) void k_lin4(const float* __restrict__ in,
                                              const float* __restrict__ W,
                                              const float* __restrict__ res,
                                              const float* __restrict__ qfp,
                                              const float* __restrict__ pe,
                                              float* __restrict__ outv) {
    const int d   = blockIdx.x;
    const int bs0 = blockIdx.y * 64;
    __shared__ unsigned short sA[64 * 72];
    __shared__ unsigned short sB[64 * 72];
    const int t  = threadIdx.x;
    const int w  = t >> 6;
    const int l  = t & 63;
    const int lr = l & 15;
    const int lk = l >> 4;

    f32x4 acc[4];
#pragma unroll
    for (int f = 0; f < 4; ++f) acc[f] = (f32x4){0.f, 0.f, 0.f, 0.f};

    const float* wbase = W + (size_t)d_REP[d] * 64 * 64;

    for (int e = t; e < 1024; e += 256) {
        int r = e >> 4, qq = e & 15;
        float4 v = *(const float4*)(in + ((size_t)(bs0 + r) * 12 + d) * 64 + qq * 4);
        ushort4 u = {f2bf(v.x), f2bf(v.y), f2bf(v.z), f2bf(v.w)};
        *(ushort4*)&sA[r * 72 + qq * 4] = u;
    }
    for (int e = t; e < 1024; e += 256) {
        int c = e >> 4, qq = e & 15;
        float4 v = *(const float4*)(wbase + (size_t)c * 64 + qq * 4);
        ushort4 u = {f2bf(v.x), f2bf(v.y), f2bf(v.z), f2bf(v.w)};
        *(ushort4*)&sB[c * 72 + qq * 4] = u;
    }
    __syncthreads();
#pragma unroll
    for (int ks = 0; ks < 2; ++ks) {
        bf16x8 a = *(const bf16x8*)&sA[(w * 16 + lr) * 72 + ks * 32 + lk * 8];
#pragma unroll
        for (int f = 0; f < 4; ++f) {
            bf16x8 b = *(const bf16x8*)&sB[(f * 16 + lr) * 72 + ks * 32 + lk * 8];
            acc[f] = __builtin_amdgcn_mfma_f32_16x16x32_bf16(a, b, acc[f], 0, 0, 0);
        }
    }

#pragma unroll
    for (int f = 0; f < 4; ++f) {
#pragma unroll
        for (int reg = 0; reg < 4; ++reg) {
            int bs = bs0 + w * 16 + lk * 4 + reg;
            int o  = f * 16 + lr;
            float val = acc[f][reg];
            size_t row = (size_t)bs * 12 + d;
            if (RES) val += res[row * 64 + o];
            if (PE)  val += qfp[144 + d] * pe[(bs & 511) * 64 + o];
            outv[row * 64 + o] = val;
        }
    }
}

// ---------------- fused QKV projection ----------------------------------
__global__ __launch_bounds__(256) void k_linqkv(const float* __restrict__ in,
                                                const float* __restrict__ wq,
                                                const float* __restrict__ wk,
                                                const float* __restrict__ wv,
                                                unsigned short* __restrict__ oq,
                                                unsigned short* __restrict__ ok,
                                                unsigned short* __restrict__ ov) {
    const int d   = blockIdx.x;
    const int bs0 = blockIdx.y * 64;
    __shared__ unsigned short sA[64 * 72];
    __shared__ unsigned short sB[64 * 72];
    const int t  = threadIdx.x;
    const int w  = t >> 6;
    const int l  = t & 63;
    const int lr = l & 15;
    const int lk = l >> 4;
    const int rep = d_REP[d];

    for (int e = t; e < 1024; e += 256) {
        int r = e >> 4, qq = e & 15;
        float4 v = *(const float4*)(in + ((size_t)(bs0 + r) * 12 + d) * 64 + qq * 4);
        ushort4 u = {f2bf(v.x), f2bf(v.y), f2bf(v.z), f2bf(v.w)};
        *(ushort4*)&sA[r * 72 + qq * 4] = u;
    }

    for (int part = 0; part < 3; ++part) {
        const float* wsel = (part == 0) ? wq : (part == 1) ? wk : wv;
        const float* wbase = wsel + (size_t)rep * 64 * 64;
        __syncthreads();
        for (int e = t; e < 1024; e += 256) {
            int c = e >> 4, qq = e & 15;
            float4 v = *(const float4*)(wbase + (size_t)c * 64 + qq * 4);
            ushort4 u = {f2bf(v.x), f2bf(v.y), f2bf(v.z), f2bf(v.w)};
            *(ushort4*)&sB[c * 72 + qq * 4] = u;
        }
        __syncthreads();
        f32x4 acc[4];
#pragma unroll
        for (int f = 0; f < 4; ++f) acc[f] = (f32x4){0.f, 0.f, 0.f, 0.f};
#pragma unroll
        for (int ks = 0; ks < 2; ++ks) {
            bf16x8 a = *(const bf16x8*)&sA[(w * 16 + lr) * 72 + ks * 32 + lk * 8];
#pragma unroll
            for (int f = 0; f < 4; ++f) {
                bf16x8 b = *(const bf16x8*)&sB[(f * 16 + lr) * 72 + ks * 32 + lk * 8];
                acc[f] = __builtin_amdgcn_mfma_f32_16x16x32_bf16(a, b, acc[f], 0, 0, 0);
            }
        }
        unsigned short* oh = (part == 0) ? oq : (part == 1) ? ok : ov;
#pragma unroll
        for (int f = 0; f < 4; ++f) {
#pragma unroll
            for (int reg = 0; reg < 4; ++reg) {
                int bs = bs0 + w * 16 + lk * 4 + reg;
                int o  = f * 16 + lr;
                int b = bs >> 9, s = bs & 511;
                unsigned short hv = f2bf(acc[f][reg]);
                if (part < 2)
                    oh[(((size_t)(b * 8 + (o >> 3)) * 512 + s) * 96) + d * 8 + (o & 7)] = hv;
                else
                    oh[(((size_t)(b * 8 + (o >> 3)) * 96 + d * 8 + (o & 7)) * 512) + s] = hv;
            }
        }
    }
}

// ---------------- attention v5: 64 q-rows, no-max softmax ----------------
// softmax is shift-invariant; scores here are far below exp-overflow, so
// p = exp(s*scale) directly; row sums deferred to a single epilogue reduce.
__global__ __launch_bounds__(256) void k_attn5(const unsigned short* __restrict__ qh,
                                               const unsigned short* __restrict__ kh,
                                               const unsigned short* __restrict__ vt,
                                               float* __restrict__ out) {
    __shared__ unsigned short sK[64 * 104];
    __shared__ unsigned short sV[96 * 72];
    __shared__ unsigned short ps[4][16 * 72];
    const int bh = blockIdx.x >> 3;
    const int q0 = (blockIdx.x & 7) * 64;
    const int t = threadIdx.x;
    const int w = t >> 6;
    const int l = t & 63;
    const int lr = l & 15;
    const int lk = l >> 4;

    const unsigned short* qg = qh + ((size_t)bh * 512 + q0 + w * 16) * 96;
    bf16x8 qa[3];
#pragma unroll
    for (int ks = 0; ks < 3; ++ks)
        qa[ks] = *(const bf16x8*)(qg + (size_t)lr * 96 + ks * 32 + lk * 8);

    float ts[4] = {0.f, 0.f, 0.f, 0.f};
    f32x4 o[6];
#pragma unroll
    for (int f = 0; f < 6; ++f) o[f] = (f32x4){0.f, 0.f, 0.f, 0.f};

    const unsigned short* kg = kh + (size_t)bh * 512 * 96;
    const unsigned short* vg = vt + (size_t)bh * 96 * 512;
    const float scale = 0.10206207261596577f;   // 1/sqrt(96)

    for (int tile = 0; tile < 8; ++tile) {
        __syncthreads();
        for (int e = t; e < 768; e += 256) {
            int row = e / 12, seg = e % 12;
            *(bf16x8*)&sK[row * 104 + seg * 8] =
                *(const bf16x8*)(kg + ((size_t)(tile * 64 + row)) * 96 + seg * 8);
        }
        for (int e = t; e < 768; e += 256) {
            int row = e / 8, seg = e % 8;
            *(bf16x8*)&sV[row * 72 + seg * 8] =
                *(const bf16x8*)(vg + (size_t)row * 512 + tile * 64 + seg * 8);
        }
        __syncthreads();

        // S = Q K^T (16 x 64 per wave), p = exp(s*scale), P -> LDS
#pragma unroll
        for (int f = 0; f < 4; ++f) {
            f32x4 acc = {0.f, 0.f, 0.f, 0.f};
#pragma unroll
            for (int ks = 0; ks < 3; ++ks) {
                bf16x8 kb = *(const bf16x8*)&sK[(f * 16 + lr) * 104 + ks * 32 + lk * 8];
                acc = __builtin_amdgcn_mfma_f32_16x16x32_bf16(qa[ks], kb, acc, 0, 0, 0);
            }
#pragma unroll
            for (int r = 0; r < 4; ++r) {
                float p = __expf(acc[r] * scale);
                ts[r] += p;
                ps[w][(lk * 4 + r) * 72 + f * 16 + lr] = f2bf(p);
            }
        }

        // O += P V (wave-private P; compiler orders ds_write->ds_read)
        bf16x8 pa[2];
#pragma unroll
        for (int ks = 0; ks < 2; ++ks)
            pa[ks] = *(const bf16x8*)&ps[w][lr * 72 + ks * 32 + lk * 8];
#pragma unroll
        for (int f = 0; f < 6; ++f) {
            f32x4 acc = o[f];
#pragma unroll
            for (int ks = 0; ks < 2; ++ks) {
                bf16x8 vb = *(const bf16x8*)&sV[(f * 16 + lr) * 72 + ks * 32 + lk * 8];
                acc = __builtin_amdgcn_mfma_f32_16x16x32_bf16(pa[ks], vb, acc, 0, 0, 0);
            }
            o[f] = acc;
        }
    }

    // epilogue: row-sum reduce (once), normalize, write
    float inv[4];
#pragma unroll
    for (int r = 0; r < 4; ++r) {
        float s2 = ts[r];
#pragma unroll
        for (int d = 1; d < 16; d <<= 1) s2 += __shfl_xor(s2, d);
        inv[r] = 1.0f / s2;
    }
    const int b = bh >> 3, hh = bh & 7;
#pragma unroll
    for (int r = 0; r < 4; ++r) {
        int s = q0 + w * 16 + lk * 4 + r;
        float* ob = out + ((size_t)(b * 512 + s) * 12) * 64 + hh * 8;
#pragma unroll
        for (int f = 0; f < 6; ++f) {
            int col = f * 16 + lr;
            ob[(col >> 3) * 64 + (col & 7)] = o[f][r] * inv[r];
        }
    }
}

// ---------------- fused f1-GEMM + act -> bf16 fmid ----------------------
// grid (128, 4): 32 bs-rows x 64 fmid-cols, ALL 12 d per block.
// MFMA C-layout identical per d => each thread holds v[12] for its
// (row,col) positions => act12 in registers, store bf16.
__global__ __launch_bounds__(256) void k_f1act(const float* __restrict__ h,
                                               const float* __restrict__ f1w,
                                               const float* __restrict__ qf,
                                               unsigned short* __restrict__ fmidb) {
    const int bs0 = blockIdx.x * 32;
    const int c0  = blockIdx.y * 64;
    __shared__ unsigned short sA[32 * 72];
    __shared__ unsigned short sB[64 * 72];
    const int t  = threadIdx.x;
    const int w  = t >> 6;
    const int l  = t & 63;
    const int lr = l & 15;
    const int lk = l >> 4;
    const int s_ = w & 1;     // row strip (16 rows)
    const int ch = w >> 1;    // col half (frags 2ch, 2ch+1)

    f32x4 acc[12][2];
#pragma unroll
    for (int d = 0; d < 12; ++d) {
        acc[d][0] = (f32x4){0.f, 0.f, 0.f, 0.f};
        acc[d][1] = (f32x4){0.f, 0.f, 0.f, 0.f};
    }

    int curRep = -1;
#pragma unroll
    for (int d = 0; d < 12; ++d) {
        int rep = d_REP[d];
        __syncthreads();
        for (int e = t; e < 512; e += 256) {
            int r = e >> 4, qq = e & 15;
            float4 v = *(const float4*)(h + ((size_t)(bs0 + r) * 12 + d) * 64 + qq * 4);
            ushort4 u = {f2bf(v.x), f2bf(v.y), f2bf(v.z), f2bf(v.w)};
            *(ushort4*)&sA[r * 72 + qq * 4] = u;
        }
        if (rep != curRep) {
            const float* wbase = f1w + (size_t)rep * 256 * 64 + (size_t)c0 * 64;
            for (int e = t; e < 1024; e += 256) {
                int c = e >> 4, qq = e & 15;
                float4 v = *(const float4*)(wbase + (size_t)c * 64 + qq * 4);
                ushort4 u = {f2bf(v.x), f2bf(v.y), f2bf(v.z), f2bf(v.w)};
                *(ushort4*)&sB[c * 72 + qq * 4] = u;
            }
            curRep = rep;
        }
        __syncthreads();
#pragma unroll
        for (int ks = 0; ks < 2; ++ks) {
            bf16x8 a = *(const bf16x8*)&sA[(s_ * 16 + lr) * 72 + ks * 32 + lk * 8];
#pragma unroll
            for (int fl = 0; fl < 2; ++fl) {
                int f = ch * 2 + fl;
                bf16x8 b = *(const bf16x8*)&sB[(f * 16 + lr) * 72 + ks * 32 + lk * 8];
                acc[d][fl] = __builtin_amdgcn_mfma_f32_16x16x32_bf16(a, b, acc[d][fl], 0, 0, 0);
            }
        }
    }

    // act + bf16 store
#pragma unroll
    for (int fl = 0; fl < 2; ++fl) {
#pragma unroll
        for (int reg = 0; reg < 4; ++reg) {
            float v[12], o[12];
#pragma unroll
            for (int d = 0; d < 12; ++d) v[d] = acc[d][fl][reg];
            act12(qf, v, o);
            int row = bs0 + s_ * 16 + lk * 4 + reg;
            int col = c0 + (ch * 2 + fl) * 16 + lr;
#pragma unroll
            for (int d = 0; d < 12; ++d)
                fmidb[((size_t)row * 12 + d) * 256 + col] = f2bf(o[d]);
        }
    }
}

// ---------------- f2 GEMM: bf16 A (fmid), fp32 res/out ------------------
__global__ __launch_bounds__(256) void k_linf2(const unsigned short* __restrict__ inb,
                                               const float* __restrict__ W,
                                               const float* __restrict__ res,
                                               float* __restrict__ outv) {
    const int d   = blockIdx.x;
    const int bs0 = blockIdx.y * 64;
    __shared__ unsigned short sA[64 * 72];
    __shared__ unsigned short sB[64 * 72];
    const int t  = threadIdx.x;
    const int w  = t >> 6;
    const int l  = t & 63;
    const int lr = l & 15;
    const int lk = l >> 4;

    f32x4 acc[4];
#pragma unroll
    for (int f = 0; f < 4; ++f) acc[f] = (f32x4){0.f, 0.f, 0.f, 0.f};

    const float* wbase = W + (size_t)d_REP[d] * 64 * 256;

    for (int kc = 0; kc < 256; kc += 64) {
        __syncthreads();
        for (int e = t; e < 512; e += 256) {
            int r = e >> 3, seg = e & 7;
            *(bf16x8*)&sA[r * 72 + seg * 8] =
                *(const bf16x8*)(inb + ((size_t)(bs0 + r) * 12 + d) * 256 + kc + seg * 8);
        }
        for (int e = t; e < 1024; e += 256) {
            int c = e >> 4, qq = e & 15;
            float4 v = *(const float4*)(wbase + (size_t)c * 256 + kc + qq * 4);
            ushort4 u = {f2bf(v.x), f2bf(v.y), f2bf(v.z), f2bf(v.w)};
            *(ushort4*)&sB[c * 72 + qq * 4] = u;
        }
        __syncthreads();
#pragma unroll
        for (int ks = 0; ks < 2; ++ks) {
            bf16x8 a = *(const bf16x8*)&sA[(w * 16 + lr) * 72 + ks * 32 + lk * 8];
#pragma unroll
            for (int f = 0; f < 4; ++f) {
                bf16x8 b = *(const bf16x8*)&sB[(f * 16 + lr) * 72 + ks * 32 + lk * 8];
                acc[f] = __builtin_amdgcn_mfma_f32_16x16x32_bf16(a, b, acc[f], 0, 0, 0);
            }
        }
    }

#pragma unroll
    for (int f = 0; f < 4; ++f) {
#pragma unroll
        for (int reg = 0; reg < 4; ++reg) {
            int bs = bs0 + w * 16 + lk * 4 + reg;
            int o  = f * 16 + lr;
            size_t row = (size_t)bs * 12 + d;
            outv[row * 64 + o] = acc[f][reg] + res[row * 64 + o];
        }
    }
}

// ---------------- fc_out (decoder tail) ----------------
__global__ void k_fcout(const float* __restrict__ h, const float* __restrict__ w,
                        const float* __restrict__ qf, float* __restrict__ z) {
    int bs = blockIdx.x;
    __shared__ float td[12];
    int t = threadIdx.x;
    if (t < 12) {
        const float* row = h + ((size_t)bs * 12 + t) * 64;
        const float* wr  = w + d_REP[t] * 64;
        float a = 0.f;
        for (int i = 0; i < 64; ++i) a += row[i] * wr[i];
        td[t] = a;
    }
    __syncthreads();
    if (t < 12) {
        float a = 0.f;
        for (int d = 0; d < 12; ++d) a += qf[d * 12 + t] * td[d];
        z[bs * 12 + t] = a / 7.0f;
    }
}

// ---------------- fused fc_out + VQ (encoder tail) ----------------------
__global__ __launch_bounds__(256) void k_fcvq(const float* __restrict__ h,
                                              const float* __restrict__ w,
                                              const float* __restrict__ qf,
                                              const float* __restrict__ cb,
                                              float* __restrict__ z,
                                              float* __restrict__ zvq,
                                              float* __restrict__ zst) {
    int bs = blockIdx.x;
    int t = threadIdx.x;
    __shared__ float td[12];
    __shared__ float zv[12];
    __shared__ float sb[256];
    __shared__ int   si[256];
    if (t < 12) {
        const float* row = h + ((size_t)bs * 12 + t) * 64;
        const float* wr  = w + d_REP[t] * 64;
        float a = 0.f;
        for (int i = 0; i < 64; ++i) a += row[i] * wr[i];
        td[t] = a;
    }
    __syncthreads();
    if (t < 12) {
        float a = 0.f;
        for (int d = 0; d < 12; ++d) a += qf[d * 12 + t] * td[d];
        a /= 7.0f;
        zv[t] = a;
        z[bs * 12 + t] = a;
    }
    __syncthreads();
    float zz = 0.f;
    for (int j = 0; j < 12; ++j) zz += zv[j] * zv[j];
    float best = 3.4e38f; int bi = 0x7fffffff;
    for (int c = t; c < KCB; c += 256) {
        const float* cr = cb + c * 12;
        float cc = 0.f, dot = 0.f;
        for (int j = 0; j < 12; ++j) { cc += cr[j] * cr[j]; dot += zv[j] * cr[j]; }
        float dist = zz + cc - 2.0f * dot;
        if (dist < best) { best = dist; bi = c; }
    }
    sb[t] = best; si[t] = bi; __syncthreads();
    for (int st = 128; st > 0; st >>= 1) {
        if (t < st) {
            if (sb[t + st] < sb[t] || (sb[t + st] == sb[t] && si[t + st] < si[t])) {
                sb[t] = sb[t + st]; si[t] = si[t + st];
            }
        }
        __syncthreads();
    }
    if (t < 12) {
        float c = cb[si[0] * 12 + t];
        zvq[bs * 12 + t] = c;
        float zi = zv[t];
        zst[bs * 12 + t] = (c - zi) + zi;
    }
}

// ---------------- merged losses ----------------
__global__ __launch_bounds__(256) void k_loss(const float* __restrict__ x,
                                              const float* __restrict__ logits,
                                              const float* __restrict__ z,
                                              const float* __restrict__ zvq,
                                              float* __restrict__ xr_out,
                                              float* __restrict__ p1,
                                              float* __restrict__ p2) {
    __shared__ float red[256];
    int t = threadIdx.x;
    float acc1 = 0.f, acc2 = 0.f;
    for (int i = blockIdx.x * 256 + t; i < NEL; i += gridDim.x * 256) {
        float lg = logits[i];
        float xr = 1.0f / (1.0f + expf(-lg));
        xr_out[i] = xr;
        float xi = x[i];
        float l1 = fmaxf(logf(xr), -100.0f);
        float l2 = fmaxf(logf(1.0f - xr), -100.0f);
        acc1 += xi * l1 + (1.0f - xi) * l2;
        float dd = zvq[i] - z[i];
        acc2 += dd * dd;
    }
    red[t] = acc1; __syncthreads();
    for (int st = 128; st > 0; st >>= 1) { if (t < st) red[t] += red[t + st]; __syncthreads(); }
    if (t == 0) p1[blockIdx.x] = red[0];
    __syncthreads();
    red[t] = acc2; __syncthreads();
    for (int st = 128; st > 0; st >>= 1) { if (t < st) red[t] += red[t + st]; __syncthreads(); }
    if (t == 0) p2[blockIdx.x] = red[0];
}

__global__ void k_final(const float* __restrict__ p1, const float* __restrict__ p2,
                        float* __restrict__ out) {
    if (threadIdx.x == 0) {
        float s1 = 0.f, s2 = 0.f;
        for (int i = 0; i < 96; ++i) { s1 += p1[i]; s2 += p2[i]; }
        out[NEL]     = -s1 / (float)NEL;
        out[NEL + 1] =  s2 / (float)NEL;
        out[NEL + 2] =  s2 / (float)NEL;
    }
}

// ------------------------------------------------------------------------
extern "C" void kernel_launch(void* const* d_in, const int* in_sizes, int n_in,
                              void* d_out, int out_size, void* d_ws, size_t ws_size,
                              hipStream_t stream) {
    const float* x   = (const float*)d_in[0];
    const float* efb = (const float*)d_in[1];
    const float* efw = (const float*)d_in[2];
    const float* ew1 = (const float*)d_in[3];
    const float* ew2 = (const float*)d_in[4];
    const float* ew3 = (const float*)d_in[5];
    const float* ewq = (const float*)d_in[6];
    const float* ewk = (const float*)d_in[7];
    const float* ewv = (const float*)d_in[8];
    const float* ewo = (const float*)d_in[9];
    const float* ef1 = (const float*)d_in[10];
    const float* ef2 = (const float*)d_in[11];
    const float* eow = (const float*)d_in[12];
    const float* cb  = (const float*)d_in[13];
    const float* dfb = (const float*)d_in[14];
    const float* dfw = (const float*)d_in[15];
    const float* dw1 = (const float*)d_in[16];
    const float* dw2 = (const float*)d_in[17];
    const float* dw3 = (const float*)d_in[18];
    const float* dwq = (const float*)d_in[19];
    const float* dwk = (const float*)d_in[20];
    const float* dwv = (const float*)d_in[21];
    const float* dwo = (const float*)d_in[22];
    const float* df1 = (const float*)d_in[23];
    const float* df2 = (const float*)d_in[24];
    const float* dow = (const float*)d_in[25];
    float* out = (float*)d_out;

    float* ws = (float*)d_ws;
    float* qf   = ws;                           // 512
    float* h    = ws + 512;                     // 3,145,728
    float* fmid = h + 3145728;                  // 12,582,912 region (bf16 fmid + q/kk/vv aliases)
    float* t1   = fmid + 12582912;              // 3,145,728
    float* z    = t1 + 3145728;
    float* zvq  = z + NEL;
    float* zst  = zvq + NEL;
    float* z2   = zst + NEL;
    float* p1   = z2 + NEL;
    float* p2   = p1 + 128;
    float* pe   = p2 + 128;                     // 32768
    unsigned short* fmidb = (unsigned short*)fmid;                    // 12.6M ushorts
    unsigned short* q  = (unsigned short*)(fmid + 6291456);           // after fmidb
    unsigned short* kk = q + 3145728;
    unsigned short* vv = kk + 3145728;

    auto run_half = [&](const float* xin, const float* fb, const float* fw,
                        const float* w1, const float* w2, const float* w3,
                        const float* wq, const float* wk, const float* wv,
                        const float* wo, const float* f1, const float* f2) {
        k_embact<<<BSN / 4, 256, 0, stream>>>(xin, fb, fw, w1, qf, h);
        k_lin4<0, 0><<<dim3(12, 64), 256, 0, stream>>>(h, w2, nullptr, qf, nullptr, t1);
        k_act<<<(BSN * 64 + 255) / 256, 256, 0, stream>>>(t1, qf);
        k_lin4<0, 1><<<dim3(12, 64), 256, 0, stream>>>(t1, w3, nullptr, qf, pe, h);
        for (int l = 0; l < LLAY; ++l) {
            size_t off  = (size_t)l * 7 * 64 * 64;
            size_t offf = (size_t)l * 7 * 256 * 64;
            k_linqkv<<<dim3(12, 64), 256, 0, stream>>>(h, wq + off, wk + off, wv + off, q, kk, vv);
            k_attn5<<<BB * HHEAD * 8, 256, 0, stream>>>(q, kk, vv, t1);
            k_lin4<1, 0><<<dim3(12, 64), 256, 0, stream>>>(t1, wo + off, h, qf, nullptr, h);
            k_f1act<<<dim3(128, 4), 256, 0, stream>>>(h, f1 + offf, qf, fmidb);
            k_linf2<<<dim3(12, 64), 256, 0, stream>>>(fmidb, f2 + offf, h, h);
        }
    };

    k_init_qf<<<1, 256, 0, stream>>>(qf);
    k_init_pe<<<512, 64, 0, stream>>>(pe);
    run_half(x, efb, efw, ew1, ew2, ew3, ewq, ewk, ewv, ewo, ef1, ef2);
    k_fcvq<<<BSN, 256, 0, stream>>>(h, eow, qf, cb, z, zvq, zst);
    run_half(zst, dfb, dfw, dw1, dw2, dw3, dwq, dwk, dwv, dwo, df1, df2);
    k_fcout<<<BSN, 64, 0, stream>>>(h, dow, qf, z2);
    k_loss<<<96, 256, 0, stream>>>(x, z2, z, zvq, out, p1, p2);
    k_final<<<1, 64, 0, stream>>>(p1, p2, out);
}

// Round 9
// 1041.960 us; speedup vs baseline: 24.4488x; 1.0789x over previous
//
#include <hip/hip_runtime.h>
#include <math.h>

#define BB 8
#define SS 512
#define HHEAD 8
#define LLAY 4
#define KCB 1024
#define BSN 4096          // B*S
#define ROWS 49152        // BS*12
#define NEL 49152         // B*S*12

__constant__ int d_REP[12] = {0,1,2,2,3,3,4,4,5,5,6,6};

typedef __attribute__((ext_vector_type(8))) short bf16x8;
typedef __attribute__((ext_vector_type(4))) float f32x4;

__device__ inline unsigned short f2bf(float x) {
    unsigned u = __builtin_bit_cast(unsigned, x);
    u += 0x7FFF + ((u >> 16) & 1);
    return (unsigned short)(u >> 16);
}

// fast gelu: erf via Abramowitz-Stegun 7.1.26 (|err| < 1.5e-7), HW rcp
__device__ inline float fast_gelu(float a) {
    float x = a * 0.7071067811865475f;
    float ax = fabsf(x);
    float tt = __builtin_amdgcn_rcpf(fmaf(0.3275911f, ax, 1.0f));
    float poly = ((((1.061405429f * tt - 1.453152027f) * tt + 1.421413741f) * tt
                   - 0.284496736f) * tt + 0.254829592f) * tt;
    float y = fmaf(-poly, __expf(-x * x), 1.0f);
    return 0.5f * a * (1.0f + copysignf(y, x));
}

// symmetry-reduced act on one 12-vector (tables in qf[160..] / qf[256..])
__device__ inline void act12(const float* __restrict__ qf, const float v[12], float o[12]) {
    constexpr int S_[7]  = {0, 1, 2, 4, 6, 8, 10};
    constexpr int DKv[7] = {1, 1, 2, 2, 2, 2, 2};
    constexpr int P_[7]  = {1, 2, 12, 6, 4, 3, 12};
    constexpr int UO[7]  = {0, 1, 3, 15, 21, 25, 28};
    constexpr int OO[7]  = {0, 1, 3, 27, 39, 47, 53};
    const float* QP = qf + 160;
    const float* QO = qf + 256;
#pragma unroll
    for (int k = 0; k < 7; ++k) {
        float g[12];
#pragma unroll
        for (int u = 0; u < P_[k]; ++u) {
            float p = QP[(UO[k] + u) * 2] * v[S_[k]];
            if (DKv[k] == 2) p = fmaf(QP[(UO[k] + u) * 2 + 1], v[S_[k] + 1], p);
            g[u] = fast_gelu(p);
        }
#pragma unroll
        for (int d = 0; d < DKv[k]; ++d) {
            float a = 0.f;
#pragma unroll
            for (int u = 0; u < P_[k]; ++u) a = fmaf(QO[OO[k] + d * P_[k] + u], g[u], a);
            o[S_[k] + d] = a;
        }
    }
}

// ---------------- QF init + rowsums + reduced act tables ----------------
__global__ void k_init_qf(float* qf) {
    int t = threadIdx.x;
    if (t < 144) {
        int r = t / 12, j = t % 12;
        double v;
        if (r == 0)      v = 1.0 / sqrt(12.0);
        else if (r == 1) v = ((j & 1) ? -1.0 : 1.0) / sqrt(12.0);
        else {
            int m = r >> 1;
            double ang = 2.0 * 3.14159265358979323846 * (double)m * (double)j / 12.0;
            v = (((r & 1) == 0) ? cos(ang) : sin(ang)) / sqrt(6.0);
        }
        qf[t] = (float)v;
    }
    __syncthreads();
    if (t < 12) {
        float s = 0.f;
        for (int j = 0; j < 12; ++j) s += qf[t * 12 + j];
        qf[144 + t] = s;
    }
    __syncthreads();
    if (t == 0) {
        const int S_[7]  = {0, 1, 2, 4, 6, 8, 10};
        const int DKv[7] = {1, 1, 2, 2, 2, 2, 2};
        const int P_[7]  = {1, 2, 12, 6, 4, 3, 12};
        const int UO[7]  = {0, 1, 3, 15, 21, 25, 28};
        const int OO[7]  = {0, 1, 3, 27, 39, 47, 53};
        for (int k = 0; k < 7; ++k) {
            for (int u = 0; u < P_[k]; ++u) {
                qf[160 + (UO[k] + u) * 2]     = qf[S_[k] * 12 + u];
                qf[160 + (UO[k] + u) * 2 + 1] = (DKv[k] == 2) ? qf[(S_[k] + 1) * 12 + u] : 0.f;
            }
            for (int d = 0; d < DKv[k]; ++d)
                for (int u = 0; u < P_[k]; ++u) {
                    float a = 0.f;
                    for (int pp = u; pp < 12; pp += P_[k]) a += qf[(S_[k] + d) * 12 + pp];
                    qf[256 + OO[k] + d * P_[k] + u] = a;
                }
        }
    }
}

// ---------------- pe table [512][64] ----------------
__global__ void k_init_pe(float* pe) {
    int s = blockIdx.x, m = threadIdx.x;
    int i = m >> 1;
    float dv = expf((float)(2 * i) * (-0.14391156831212787f));
    float arg = (float)s * dv;
    pe[s * 64 + m] = (m & 1) ? cosf(arg) : sinf(arg);
}

// ---------------- fused embed + act64: 4 bs per block -------------------
__global__ __launch_bounds__(256) void k_embact(const float* __restrict__ x,
                                                const float* __restrict__ fb,
                                                const float* __restrict__ fw,
                                                const float* __restrict__ w1,
                                                const float* __restrict__ qf,
                                                float* __restrict__ out) {
    int bs0 = blockIdx.x * 4;
    int t = threadIdx.x;
    __shared__ float xs[4][12], h1[4][12];
    if (t < 48) {
        int sb = t / 12, j = t % 12;
        xs[sb][j] = x[(bs0 + sb) * 12 + j] + fb[0];
    }
    __syncthreads();
    if (t < 48) {
        int sb = t / 12, j = t % 12;
        float a = 0.f;
        for (int p = 0; p < 12; ++p) a += qf[j * 12 + p] * xs[sb][p];
        h1[sb][j] = a * fw[0];
    }
    __syncthreads();
    int sb = t >> 6, m = t & 63;
    float v[12], o[12];
#pragma unroll
    for (int d = 0; d < 12; ++d) v[d] = h1[sb][d] * w1[d_REP[d] * 64 + m];
    act12(qf, v, o);
    float* ob = out + ((size_t)(bs0 + sb) * 12) * 64 + m;
#pragma unroll
    for (int d = 0; d < 12; ++d) ob[d * 64] = o[d];
}

// ---------------- act standalone (t1, mdim=64) --------------------------
__global__ __launch_bounds__(256) void k_act(float* __restrict__ h,
                                             const float* __restrict__ qf) {
    int idx = blockIdx.x * 256 + threadIdx.x;
    if (idx >= BSN * 64) return;
    int bs = idx >> 6, m = idx & 63;
    float* base = h + (size_t)bs * 12 * 64 + m;
    float v[12], o[12];
#pragma unroll
    for (int d = 0; d < 12; ++d) v[d] = base[d * 64];
    act12(qf, v, o);
#pragma unroll
    for (int d = 0; d < 12; ++d) base[d * 64] = o[d];
}

// ---------------- MFMA bf16 lin (64x64, fp32 in/out) --------------------
template <int RES, int PE>
__global__ __launch_bounds__(256) void k_lin4(const float* __restrict__ in,
                                              const float* __restrict__ W,
                                              const float* __restrict__ res,
                                              const float* __restrict__ qfp,
                                              const float* __restrict__ pe,
                                              float* __restrict__ outv) {
    const int d   = blockIdx.x;
    const int bs0 = blockIdx.y * 64;
    __shared__ unsigned short sA[64 * 72];
    __shared__ unsigned short sB[64 * 72];
    const int t  = threadIdx.x;
    const int w  = t >> 6;
    const int l  = t & 63;
    const int lr = l & 15;
    const int lk = l >> 4;

    f32x4 acc[4];
#pragma unroll
    for (int f = 0; f < 4; ++f) acc[f] = (f32x4){0.f, 0.f, 0.f, 0.f};

    const float* wbase = W + (size_t)d_REP[d] * 64 * 64;

    for (int e = t; e < 1024; e += 256) {
        int r = e >> 4, qq = e & 15;
        float4 v = *(const float4*)(in + ((size_t)(bs0 + r) * 12 + d) * 64 + qq * 4);
        ushort4 u = {f2bf(v.x), f2bf(v.y), f2bf(v.z), f2bf(v.w)};
        *(ushort4*)&sA[r * 72 + qq * 4] = u;
    }
    for (int e = t; e < 1024; e += 256) {
        int c = e >> 4, qq = e & 15;
        float4 v = *(const float4*)(wbase + (size_t)c * 64 + qq * 4);
        ushort4 u = {f2bf(v.x), f2bf(v.y), f2bf(v.z), f2bf(v.w)};
        *(ushort4*)&sB[c * 72 + qq * 4] = u;
    }
    __syncthreads();
#pragma unroll
    for (int ks = 0; ks < 2; ++ks) {
        bf16x8 a = *(const bf16x8*)&sA[(w * 16 + lr) * 72 + ks * 32 + lk * 8];
#pragma unroll
        for (int f = 0; f < 4; ++f) {
            bf16x8 b = *(const bf16x8*)&sB[(f * 16 + lr) * 72 + ks * 32 + lk * 8];
            acc[f] = __builtin_amdgcn_mfma_f32_16x16x32_bf16(a, b, acc[f], 0, 0, 0);
        }
    }

#pragma unroll
    for (int f = 0; f < 4; ++f) {
#pragma unroll
        for (int reg = 0; reg < 4; ++reg) {
            int bs = bs0 + w * 16 + lk * 4 + reg;
            int o  = f * 16 + lr;
            float val = acc[f][reg];
            size_t row = (size_t)bs * 12 + d;
            if (RES) val += res[row * 64 + o];
            if (PE)  val += qfp[144 + d] * pe[(bs & 511) * 64 + o];
            outv[row * 64 + o] = val;
        }
    }
}

// ---------------- fused QKV projection ----------------------------------
__global__ __launch_bounds__(256) void k_linqkv(const float* __restrict__ in,
                                                const float* __restrict__ wq,
                                                const float* __restrict__ wk,
                                                const float* __restrict__ wv,
                                                unsigned short* __restrict__ oq,
                                                unsigned short* __restrict__ ok,
                                                unsigned short* __restrict__ ov) {
    const int d   = blockIdx.x;
    const int bs0 = blockIdx.y * 64;
    __shared__ unsigned short sA[64 * 72];
    __shared__ unsigned short sB[64 * 72];
    const int t  = threadIdx.x;
    const int w  = t >> 6;
    const int l  = t & 63;
    const int lr = l & 15;
    const int lk = l >> 4;
    const int rep = d_REP[d];

    for (int e = t; e < 1024; e += 256) {
        int r = e >> 4, qq = e & 15;
        float4 v = *(const float4*)(in + ((size_t)(bs0 + r) * 12 + d) * 64 + qq * 4);
        ushort4 u = {f2bf(v.x), f2bf(v.y), f2bf(v.z), f2bf(v.w)};
        *(ushort4*)&sA[r * 72 + qq * 4] = u;
    }

    for (int part = 0; part < 3; ++part) {
        const float* wsel = (part == 0) ? wq : (part == 1) ? wk : wv;
        const float* wbase = wsel + (size_t)rep * 64 * 64;
        __syncthreads();
        for (int e = t; e < 1024; e += 256) {
            int c = e >> 4, qq = e & 15;
            float4 v = *(const float4*)(wbase + (size_t)c * 64 + qq * 4);
            ushort4 u = {f2bf(v.x), f2bf(v.y), f2bf(v.z), f2bf(v.w)};
            *(ushort4*)&sB[c * 72 + qq * 4] = u;
        }
        __syncthreads();
        f32x4 acc[4];
#pragma unroll
        for (int f = 0; f < 4; ++f) acc[f] = (f32x4){0.f, 0.f, 0.f, 0.f};
#pragma unroll
        for (int ks = 0; ks < 2; ++ks) {
            bf16x8 a = *(const bf16x8*)&sA[(w * 16 + lr) * 72 + ks * 32 + lk * 8];
#pragma unroll
            for (int f = 0; f < 4; ++f) {
                bf16x8 b = *(const bf16x8*)&sB[(f * 16 + lr) * 72 + ks * 32 + lk * 8];
                acc[f] = __builtin_amdgcn_mfma_f32_16x16x32_bf16(a, b, acc[f], 0, 0, 0);
            }
        }
        unsigned short* oh = (part == 0) ? oq : (part == 1) ? ok : ov;
#pragma unroll
        for (int f = 0; f < 4; ++f) {
#pragma unroll
            for (int reg = 0; reg < 4; ++reg) {
                int bs = bs0 + w * 16 + lk * 4 + reg;
                int o  = f * 16 + lr;
                int b = bs >> 9, s = bs & 511;
                unsigned short hv = f2bf(acc[f][reg]);
                if (part < 2)
                    oh[(((size_t)(b * 8 + (o >> 3)) * 512 + s) * 96) + d * 8 + (o & 7)] = hv;
                else
                    oh[(((size_t)(b * 8 + (o >> 3)) * 96 + d * 8 + (o & 7)) * 512) + s] = hv;
            }
        }
    }
}

// ---------------- attention v5: 64 q-rows, no-max softmax ----------------
__global__ __launch_bounds__(256) void k_attn5(const unsigned short* __restrict__ qh,
                                               const unsigned short* __restrict__ kh,
                                               const unsigned short* __restrict__ vt,
                                               float* __restrict__ out) {
    __shared__ unsigned short sK[64 * 104];
    __shared__ unsigned short sV[96 * 72];
    __shared__ unsigned short ps[4][16 * 72];
    const int bh = blockIdx.x >> 3;
    const int q0 = (blockIdx.x & 7) * 64;
    const int t = threadIdx.x;
    const int w = t >> 6;
    const int l = t & 63;
    const int lr = l & 15;
    const int lk = l >> 4;

    const unsigned short* qg = qh + ((size_t)bh * 512 + q0 + w * 16) * 96;
    bf16x8 qa[3];
#pragma unroll
    for (int ks = 0; ks < 3; ++ks)
        qa[ks] = *(const bf16x8*)(qg + (size_t)lr * 96 + ks * 32 + lk * 8);

    float ts[4] = {0.f, 0.f, 0.f, 0.f};
    f32x4 o[6];
#pragma unroll
    for (int f = 0; f < 6; ++f) o[f] = (f32x4){0.f, 0.f, 0.f, 0.f};

    const unsigned short* kg = kh + (size_t)bh * 512 * 96;
    const unsigned short* vg = vt + (size_t)bh * 96 * 512;
    const float scale = 0.10206207261596577f;   // 1/sqrt(96)

    for (int tile = 0; tile < 8; ++tile) {
        __syncthreads();
        for (int e = t; e < 768; e += 256) {
            int row = e / 12, seg = e % 12;
            *(bf16x8*)&sK[row * 104 + seg * 8] =
                *(const bf16x8*)(kg + ((size_t)(tile * 64 + row)) * 96 + seg * 8);
        }
        for (int e = t; e < 768; e += 256) {
            int row = e / 8, seg = e % 8;
            *(bf16x8*)&sV[row * 72 + seg * 8] =
                *(const bf16x8*)(vg + (size_t)row * 512 + tile * 64 + seg * 8);
        }
        __syncthreads();

#pragma unroll
        for (int f = 0; f < 4; ++f) {
            f32x4 acc = {0.f, 0.f, 0.f, 0.f};
#pragma unroll
            for (int ks = 0; ks < 3; ++ks) {
                bf16x8 kb = *(const bf16x8*)&sK[(f * 16 + lr) * 104 + ks * 32 + lk * 8];
                acc = __builtin_amdgcn_mfma_f32_16x16x32_bf16(qa[ks], kb, acc, 0, 0, 0);
            }
#pragma unroll
            for (int r = 0; r < 4; ++r) {
                float p = __expf(acc[r] * scale);
                ts[r] += p;
                ps[w][(lk * 4 + r) * 72 + f * 16 + lr] = f2bf(p);
            }
        }

        bf16x8 pa[2];
#pragma unroll
        for (int ks = 0; ks < 2; ++ks)
            pa[ks] = *(const bf16x8*)&ps[w][lr * 72 + ks * 32 + lk * 8];
#pragma unroll
        for (int f = 0; f < 6; ++f) {
            f32x4 acc = o[f];
#pragma unroll
            for (int ks = 0; ks < 2; ++ks) {
                bf16x8 vb = *(const bf16x8*)&sV[(f * 16 + lr) * 72 + ks * 32 + lk * 8];
                acc = __builtin_amdgcn_mfma_f32_16x16x32_bf16(pa[ks], vb, acc, 0, 0, 0);
            }
            o[f] = acc;
        }
    }

    float inv[4];
#pragma unroll
    for (int r = 0; r < 4; ++r) {
        float s2 = ts[r];
#pragma unroll
        for (int d = 1; d < 16; d <<= 1) s2 += __shfl_xor(s2, d);
        inv[r] = 1.0f / s2;
    }
    const int b = bh >> 3, hh = bh & 7;
#pragma unroll
    for (int r = 0; r < 4; ++r) {
        int s = q0 + w * 16 + lk * 4 + r;
        float* ob = out + ((size_t)(b * 512 + s) * 12) * 64 + hh * 8;
#pragma unroll
        for (int f = 0; f < 6; ++f) {
            int col = f * 16 + lr;
            ob[(col >> 3) * 64 + (col & 7)] = o[f][r] * inv[r];
        }
    }
}

// ---------------- fused f1-GEMM + act -> bf16 fmid (v2) -----------------
// grid (256, 4): 16 bs-rows x 64 fmid-cols per block; wave = col frag.
// acc[12] (48 VGPR) instead of acc[12][2]; 1024 blocks for latency hiding.
__global__ __launch_bounds__(256) void k_f1act(const float* __restrict__ h,
                                               const float* __restrict__ f1w,
                                               const float* __restrict__ qf,
                                               unsigned short* __restrict__ fmidb) {
    const int bs0 = blockIdx.x * 16;
    const int c0  = blockIdx.y * 64;
    __shared__ unsigned short sA[16 * 72];
    __shared__ unsigned short sB[64 * 72];
    const int t  = threadIdx.x;
    const int w  = t >> 6;      // wave = col fragment
    const int l  = t & 63;
    const int lr = l & 15;
    const int lk = l >> 4;

    f32x4 acc[12];
#pragma unroll
    for (int d = 0; d < 12; ++d) acc[d] = (f32x4){0.f, 0.f, 0.f, 0.f};

    int curRep = -1;
#pragma unroll
    for (int d = 0; d < 12; ++d) {
        int rep = d_REP[d];
        __syncthreads();
        {
            int r = t >> 4, qq = t & 15;   // 256 threads = 16 rows x 16 quads
            float4 v = *(const float4*)(h + ((size_t)(bs0 + r) * 12 + d) * 64 + qq * 4);
            ushort4 u = {f2bf(v.x), f2bf(v.y), f2bf(v.z), f2bf(v.w)};
            *(ushort4*)&sA[r * 72 + qq * 4] = u;
        }
        if (rep != curRep) {
            const float* wbase = f1w + (size_t)rep * 256 * 64 + (size_t)c0 * 64;
            for (int e = t; e < 1024; e += 256) {
                int c = e >> 4, qq = e & 15;
                float4 v = *(const float4*)(wbase + (size_t)c * 64 + qq * 4);
                ushort4 u = {f2bf(v.x), f2bf(v.y), f2bf(v.z), f2bf(v.w)};
                *(ushort4*)&sB[c * 72 + qq * 4] = u;
            }
            curRep = rep;
        }
        __syncthreads();
#pragma unroll
        for (int ks = 0; ks < 2; ++ks) {
            bf16x8 a = *(const bf16x8*)&sA[lr * 72 + ks * 32 + lk * 8];
            bf16x8 b = *(const bf16x8*)&sB[(w * 16 + lr) * 72 + ks * 32 + lk * 8];
            acc[d] = __builtin_amdgcn_mfma_f32_16x16x32_bf16(a, b, acc[d], 0, 0, 0);
        }
    }

    // act in registers + bf16 store
#pragma unroll
    for (int reg = 0; reg < 4; ++reg) {
        float v[12], o[12];
#pragma unroll
        for (int d = 0; d < 12; ++d) v[d] = acc[d][reg];
        act12(qf, v, o);
        int row = bs0 + lk * 4 + reg;
        int col = c0 + w * 16 + lr;
#pragma unroll
        for (int d = 0; d < 12; ++d)
            fmidb[((size_t)row * 12 + d) * 256 + col] = f2bf(o[d]);
    }
}

// ---------------- f2 GEMM: bf16 A (fmid), fp32 res/out ------------------
__global__ __launch_bounds__(256) void k_linf2(const unsigned short* __restrict__ inb,
                                               const float* __restrict__ W,
                                               const float* __restrict__ res,
                                               float* __restrict__ outv) {
    const int d   = blockIdx.x;
    const int bs0 = blockIdx.y * 64;
    __shared__ unsigned short sA[64 * 72];
    __shared__ unsigned short sB[64 * 72];
    const int t  = threadIdx.x;
    const int w  = t >> 6;
    const int l  = t & 63;
    const int lr = l & 15;
    const int lk = l >> 4;

    f32x4 acc[4];
#pragma unroll
    for (int f = 0; f < 4; ++f) acc[f] = (f32x4){0.f, 0.f, 0.f, 0.f};

    const float* wbase = W + (size_t)d_REP[d] * 64 * 256;

    for (int kc = 0; kc < 256; kc += 64) {
        __syncthreads();
        for (int e = t; e < 512; e += 256) {
            int r = e >> 3, seg = e & 7;
            *(bf16x8*)&sA[r * 72 + seg * 8] =
                *(const bf16x8*)(inb + ((size_t)(bs0 + r) * 12 + d) * 256 + kc + seg * 8);
        }
        for (int e = t; e < 1024; e += 256) {
            int c = e >> 4, qq = e & 15;
            float4 v = *(const float4*)(wbase + (size_t)c * 256 + kc + qq * 4);
            ushort4 u = {f2bf(v.x), f2bf(v.y), f2bf(v.z), f2bf(v.w)};
            *(ushort4*)&sB[c * 72 + qq * 4] = u;
        }
        __syncthreads();
#pragma unroll
        for (int ks = 0; ks < 2; ++ks) {
            bf16x8 a = *(const bf16x8*)&sA[(w * 16 + lr) * 72 + ks * 32 + lk * 8];
#pragma unroll
            for (int f = 0; f < 4; ++f) {
                bf16x8 b = *(const bf16x8*)&sB[(f * 16 + lr) * 72 + ks * 32 + lk * 8];
                acc[f] = __builtin_amdgcn_mfma_f32_16x16x32_bf16(a, b, acc[f], 0, 0, 0);
            }
        }
    }

#pragma unroll
    for (int f = 0; f < 4; ++f) {
#pragma unroll
        for (int reg = 0; reg < 4; ++reg) {
            int bs = bs0 + w * 16 + lk * 4 + reg;
            int o  = f * 16 + lr;
            size_t row = (size_t)bs * 12 + d;
            outv[row * 64 + o] = acc[f][reg] + res[row * 64 + o];
        }
    }
}

// ---------------- fc_out (decoder tail) ----------------
__global__ void k_fcout(const float* __restrict__ h, const float* __restrict__ w,
                        const float* __restrict__ qf, float* __restrict__ z) {
    int bs = blockIdx.x;
    __shared__ float td[12];
    int t = threadIdx.x;
    if (t < 12) {
        const float* row = h + ((size_t)bs * 12 + t) * 64;
        const float* wr  = w + d_REP[t] * 64;
        float a = 0.f;
        for (int i = 0; i < 64; ++i) a += row[i] * wr[i];
        td[t] = a;
    }
    __syncthreads();
    if (t < 12) {
        float a = 0.f;
        for (int d = 0; d < 12; ++d) a += qf[d * 12 + t] * td[d];
        z[bs * 12 + t] = a / 7.0f;
    }
}

// ---------------- fused fc_out + VQ (encoder tail) ----------------------
__global__ __launch_bounds__(256) void k_fcvq(const float* __restrict__ h,
                                              const float* __restrict__ w,
                                              const float* __restrict__ qf,
                                              const float* __restrict__ cb,
                                              float* __restrict__ z,
                                              float* __restrict__ zvq,
                                              float* __restrict__ zst) {
    int bs = blockIdx.x;
    int t = threadIdx.x;
    __shared__ float td[12];
    __shared__ float zv[12];
    __shared__ float sb[256];
    __shared__ int   si[256];
    if (t < 12) {
        const float* row = h + ((size_t)bs * 12 + t) * 64;
        const float* wr  = w + d_REP[t] * 64;
        float a = 0.f;
        for (int i = 0; i < 64; ++i) a += row[i] * wr[i];
        td[t] = a;
    }
    __syncthreads();
    if (t < 12) {
        float a = 0.f;
        for (int d = 0; d < 12; ++d) a += qf[d * 12 + t] * td[d];
        a /= 7.0f;
        zv[t] = a;
        z[bs * 12 + t] = a;
    }
    __syncthreads();
    float zz = 0.f;
    for (int j = 0; j < 12; ++j) zz += zv[j] * zv[j];
    float best = 3.4e38f; int bi = 0x7fffffff;
    for (int c = t; c < KCB; c += 256) {
        const float* cr = cb + c * 12;
        float cc = 0.f, dot = 0.f;
        for (int j = 0; j < 12; ++j) { cc += cr[j] * cr[j]; dot += zv[j] * cr[j]; }
        float dist = zz + cc - 2.0f * dot;
        if (dist < best) { best = dist; bi = c; }
    }
    sb[t] = best; si[t] = bi; __syncthreads();
    for (int st = 128; st > 0; st >>= 1) {
        if (t < st) {
            if (sb[t + st] < sb[t] || (sb[t + st] == sb[t] && si[t + st] < si[t])) {
                sb[t] = sb[t + st]; si[t] = si[t + st];
            }
        }
        __syncthreads();
    }
    if (t < 12) {
        float c = cb[si[0] * 12 + t];
        zvq[bs * 12 + t] = c;
        float zi = zv[t];
        zst[bs * 12 + t] = (c - zi) + zi;
    }
}

// ---------------- merged losses ----------------
__global__ __launch_bounds__(256) void k_loss(const float* __restrict__ x,
                                              const float* __restrict__ logits,
                                              const float* __restrict__ z,
                                              const float* __restrict__ zvq,
                                              float* __restrict__ xr_out,
                                              float* __restrict__ p1,
                                              float* __restrict__ p2) {
    __shared__ float red[256];
    int t = threadIdx.x;
    float acc1 = 0.f, acc2 = 0.f;
    for (int i = blockIdx.x * 256 + t; i < NEL; i += gridDim.x * 256) {
        float lg = logits[i];
        float xr = 1.0f / (1.0f + expf(-lg));
        xr_out[i] = xr;
        float xi = x[i];
        float l1 = fmaxf(logf(xr), -100.0f);
        float l2 = fmaxf(logf(1.0f - xr), -100.0f);
        acc1 += xi * l1 + (1.0f - xi) * l2;
        float dd = zvq[i] - z[i];
        acc2 += dd * dd;
    }
    red[t] = acc1; __syncthreads();
    for (int st = 128; st > 0; st >>= 1) { if (t < st) red[t] += red[t + st]; __syncthreads(); }
    if (t == 0) p1[blockIdx.x] = red[0];
    __syncthreads();
    red[t] = acc2; __syncthreads();
    for (int st = 128; st > 0; st >>= 1) { if (t < st) red[t] += red[t + st]; __syncthreads(); }
    if (t == 0) p2[blockIdx.x] = red[0];
}

__global__ void k_final(const float* __restrict__ p1, const float* __restrict__ p2,
                        float* __restrict__ out) {
    if (threadIdx.x == 0) {
        float s1 = 0.f, s2 = 0.f;
        for (int i = 0; i < 96; ++i) { s1 += p1[i]; s2 += p2[i]; }
        out[NEL]     = -s1 / (float)NEL;
        out[NEL + 1] =  s2 / (float)NEL;
        out[NEL + 2] =  s2 / (float)NEL;
    }
}

// ------------------------------------------------------------------------
extern "C" void kernel_launch(void* const* d_in, const int* in_sizes, int n_in,
                              void* d_out, int out_size, void* d_ws, size_t ws_size,
                              hipStream_t stream) {
    const float* x   = (const float*)d_in[0];
    const float* efb = (const float*)d_in[1];
    const float* efw = (const float*)d_in[2];
    const float* ew1 = (const float*)d_in[3];
    const float* ew2 = (const float*)d_in[4];
    const float* ew3 = (const float*)d_in[5];
    const float* ewq = (const float*)d_in[6];
    const float* ewk = (const float*)d_in[7];
    const float* ewv = (const float*)d_in[8];
    const float* ewo = (const float*)d_in[9];
    const float* ef1 = (const float*)d_in[10];
    const float* ef2 = (const float*)d_in[11];
    const float* eow = (const float*)d_in[12];
    const float* cb  = (const float*)d_in[13];
    const float* dfb = (const float*)d_in[14];
    const float* dfw = (const float*)d_in[15];
    const float* dw1 = (const float*)d_in[16];
    const float* dw2 = (const float*)d_in[17];
    const float* dw3 = (const float*)d_in[18];
    const float* dwq = (const float*)d_in[19];
    const float* dwk = (const float*)d_in[20];
    const float* dwv = (const float*)d_in[21];
    const float* dwo = (const float*)d_in[22];
    const float* df1 = (const float*)d_in[23];
    const float* df2 = (const float*)d_in[24];
    const float* dow = (const float*)d_in[25];
    float* out = (float*)d_out;

    float* ws = (float*)d_ws;
    float* qf   = ws;                           // 512
    float* h    = ws + 512;                     // 3,145,728
    float* fmid = h + 3145728;                  // 12,582,912 region (bf16 fmid + q/kk/vv aliases)
    float* t1   = fmid + 12582912;              // 3,145,728
    float* z    = t1 + 3145728;
    float* zvq  = z + NEL;
    float* zst  = zvq + NEL;
    float* z2   = zst + NEL;
    float* p1   = z2 + NEL;
    float* p2   = p1 + 128;
    float* pe   = p2 + 128;                     // 32768
    unsigned short* fmidb = (unsigned short*)fmid;                    // 12.6M ushorts
    unsigned short* q  = (unsigned short*)(fmid + 6291456);           // after fmidb
    unsigned short* kk = q + 3145728;
    unsigned short* vv = kk + 3145728;

    auto run_half = [&](const float* xin, const float* fb, const float* fw,
                        const float* w1, const float* w2, const float* w3,
                        const float* wq, const float* wk, const float* wv,
                        const float* wo, const float* f1, const float* f2) {
        k_embact<<<BSN / 4, 256, 0, stream>>>(xin, fb, fw, w1, qf, h);
        k_lin4<0, 0><<<dim3(12, 64), 256, 0, stream>>>(h, w2, nullptr, qf, nullptr, t1);
        k_act<<<(BSN * 64 + 255) / 256, 256, 0, stream>>>(t1, qf);
        k_lin4<0, 1><<<dim3(12, 64), 256, 0, stream>>>(t1, w3, nullptr, qf, pe, h);
        for (int l = 0; l < LLAY; ++l) {
            size_t off  = (size_t)l * 7 * 64 * 64;
            size_t offf = (size_t)l * 7 * 256 * 64;
            k_linqkv<<<dim3(12, 64), 256, 0, stream>>>(h, wq + off, wk + off, wv + off, q, kk, vv);
            k_attn5<<<BB * HHEAD * 8, 256, 0, stream>>>(q, kk, vv, t1);
            k_lin4<1, 0><<<dim3(12, 64), 256, 0, stream>>>(t1, wo + off, h, qf, nullptr, h);
            k_f1act<<<dim3(256, 4), 256, 0, stream>>>(h, f1 + offf, qf, fmidb);
            k_linf2<<<dim3(12, 64), 256, 0, stream>>>(fmidb, f2 + offf, h, h);
        }
    };

    k_init_qf<<<1, 256, 0, stream>>>(qf);
    k_init_pe<<<512, 64, 0, stream>>>(pe);
    run_half(x, efb, efw, ew1, ew2, ew3, ewq, ewk, ewv, ewo, ef1, ef2);
    k_fcvq<<<BSN, 256, 0, stream>>>(h, eow, qf, cb, z, zvq, zst);
    run_half(zst, dfb, dfw, dw1, dw2, dw3, dwq, dwk, dwv, dwo, df1, df2);
    k_fcout<<<BSN, 64, 0, stream>>>(h, dow, qf, z2);
    k_loss<<<96, 256, 0, stream>>>(x, z2, z, zvq, out, p1, p2);
    k_final<<<1, 64, 0, stream>>>(p1, p2, out);
}